// Round 3
// baseline (6570.674 us; speedup 1.0000x reference)
//
#include <hip/hip_runtime.h>
#include <math.h>

typedef float f32x4 __attribute__((ext_vector_type(4)));
typedef short bf16x8 __attribute__((ext_vector_type(8)));

#define D 64
#define TT 8
#define RR 8

// ---------------- scalar helpers ----------------
__device__ __forceinline__ float bf2f(unsigned short u) {
    union { unsigned int i; float f; } x;
    x.i = ((unsigned int)u) << 16;
    return x.f;
}
__device__ __forceinline__ unsigned short f2bf(float f) {
    union { float f; unsigned int i; } x;
    x.f = f;
    unsigned int i = x.i;
    unsigned int r = (i + 0x7FFFu + ((i >> 16) & 1u)) >> 16;   // RNE
    return (unsigned short)r;
}
struct BfPair { short hi; short lo; };
// split fp32 into bf16 hi + bf16 lo (x ~= hi + lo, error ~2^-17 |x|)
__device__ __forceinline__ BfPair split2(float x) {
    BfPair p;
    unsigned short h = f2bf(x);
    p.hi = (short)h;
    p.lo = (short)f2bf(x - bf2f(h));
    return p;
}
__device__ __forceinline__ void load_A_split(const float* __restrict__ p, bf16x8& ah, bf16x8& al) {
#pragma unroll
    for (int i = 0; i < 8; ++i) {
        BfPair s = split2(p[i]);
        ah[i] = s.hi; al[i] = s.lo;
    }
}
// B fragment (B[k][n] = W[k][n], row-major 64x64 fp32), split into hi/lo
__device__ __forceinline__ void load_B_split(const float* __restrict__ W, int ks, int c, int lane,
                                             bf16x8& bh, bf16x8& bl) {
    int n = lane & 15, q = lane >> 4;
#pragma unroll
    for (int i = 0; i < 8; ++i) {
        BfPair s = split2(W[(ks * 32 + q * 8 + i) * 64 + c * 16 + n]);
        bh[i] = s.hi; bl[i] = s.lo;
    }
}
// plain bf16 B fragment
__device__ __forceinline__ bf16x8 load_B_frag(const float* __restrict__ W, int ks, int c, int lane) {
    int n = lane & 15, q = lane >> 4;
    bf16x8 r;
#pragma unroll
    for (int i = 0; i < 8; ++i)
        r[i] = (short)f2bf(W[(ks * 32 + q * 8 + i) * 64 + c * 16 + n]);
    return r;
}

#define MFMA16(a, b, c) __builtin_amdgcn_mfma_f32_16x16x32_bf16(a, b, c, 0, 0, 0)

// 24 MFMAs: acc[c] += (A0h+A0l)@(B0h+B0l) + (A1h+A1l)@(B1h+B1l), dropping lo*lo
#define SPLIT_MFMA_BODY(acc, A0h, A0l, A1h, A1l, Bh, Bl)          \
    _Pragma("unroll")                                             \
    for (int c = 0; c < 4; ++c) {                                 \
        acc[c] = MFMA16(A0h, Bh[0][c], acc[c]);                   \
        acc[c] = MFMA16(A0l, Bh[0][c], acc[c]);                   \
        acc[c] = MFMA16(A0h, Bl[0][c], acc[c]);                   \
        acc[c] = MFMA16(A1h, Bh[1][c], acc[c]);                   \
        acc[c] = MFMA16(A1l, Bh[1][c], acc[c]);                   \
        acc[c] = MFMA16(A1h, Bl[1][c], acc[c]);                   \
    }

// ---------------- CSR build ----------------
__global__ void hist_kernel(const int* __restrict__ dst, const int* __restrict__ et,
                            const int* __restrict__ nt,
                            int* __restrict__ deg, int* __restrict__ tcnt, int* __restrict__ rcnt,
                            int N, int E) {
    int tid = blockIdx.x * blockDim.x + threadIdx.x;
    if (tid < E) {
        atomicAdd(&deg[dst[tid]], 1);
        atomicAdd(&rcnt[et[tid]], 1);
    }
    if (tid < N) atomicAdd(&tcnt[nt[tid]], 1);
}

__global__ void scan_kernel(const int* __restrict__ deg, int* __restrict__ off,
                            int* __restrict__ cursor,
                            const int* __restrict__ tcnt, int* __restrict__ toff, int* __restrict__ tcur,
                            const int* __restrict__ rcnt, int* __restrict__ roff, int* __restrict__ rcur,
                            int N) {
    __shared__ int ps[1024];
    int tid = threadIdx.x;
    int chunk = (N + 1023) / 1024;
    int s0 = tid * chunk;
    int s1 = s0 + chunk; if (s1 > N) s1 = N;
    int sum = 0;
    for (int i = s0; i < s1; ++i) sum += deg[i];
    ps[tid] = sum;
    __syncthreads();
    for (int sh = 1; sh < 1024; sh <<= 1) {
        int v = (tid >= sh) ? ps[tid - sh] : 0;
        __syncthreads();
        ps[tid] += v;
        __syncthreads();
    }
    int run = (tid > 0) ? ps[tid - 1] : 0;
    for (int i = s0; i < s1; ++i) { off[i] = run; cursor[i] = run; run += deg[i]; }
    if (tid == 0) {
        off[N] = ps[1023];
        int a = 0;
        for (int t = 0; t < TT; ++t) { toff[t] = a; tcur[t] = a; a += tcnt[t]; }
        toff[TT] = a;
        int b = 0;
        for (int r = 0; r < RR; ++r) { roff[r] = b; rcur[r] = b; b += rcnt[r]; }
        roff[RR] = b;
    }
}

__global__ void scatter_kernel(const int* __restrict__ src, const int* __restrict__ dst,
                               const int* __restrict__ et, const int* __restrict__ nt,
                               int* __restrict__ curs, int* __restrict__ tcur, int* __restrict__ rcur,
                               int* __restrict__ einfo, int* __restrict__ rsrc, int* __restrict__ rdst,
                               int* __restrict__ rdpos, int* __restrict__ nidx, int N, int E) {
    int tid = blockIdx.x * blockDim.x + threadIdx.x;
    if (tid < E) {
        int s = src[tid], d = dst[tid], r = et[tid];
        int pos = atomicAdd(&curs[d], 1);
        einfo[pos] = (s << 3) | r;            // V2 row id, directly
        int rp = atomicAdd(&rcur[r], 1);
        rsrc[rp] = s; rdst[rp] = d; rdpos[rp] = pos;
    }
    if (tid < N) {
        int t = nt[tid];
        nidx[atomicAdd(&tcur[t], 1)] = tid;
    }
}

// ---------------- node projections ----------------
// grid (SX, 3, T), one wave/block. a=0: k (split hi/lo bf16 out), a=1: q (fp32 out), a=2: v (bf16 out)
__global__ void proj_kernel(const float* __restrict__ h,
                            const float* __restrict__ Wk, const float* __restrict__ Wq,
                            const float* __restrict__ Wv,
                            const int* __restrict__ toff, const int* __restrict__ nidx,
                            unsigned short* __restrict__ khi, unsigned short* __restrict__ klo,
                            float* __restrict__ qout, unsigned short* __restrict__ vout) {
    const int t = blockIdx.z, a = blockIdx.y, lane = threadIdx.x;
    const int beg = toff[t], end = toff[t + 1], cnt = end - beg;
    if (cnt <= 0) return;
    const int nstrips = (cnt + 15) >> 4;
    const float* W = (a == 0 ? Wk : (a == 1 ? Wq : Wv)) + (size_t)t * 4096;
    const int m = lane & 15, quad = lane >> 4;

    bf16x8 Bh[2][4], Bl[2][4];
#pragma unroll
    for (int ks = 0; ks < 2; ++ks)
#pragma unroll
        for (int c = 0; c < 4; ++c) load_B_split(W, ks, c, lane, Bh[ks][c], Bl[ks][c]);

    for (int s = blockIdx.x; s < nstrips; s += gridDim.x) {
        int base = beg + s * 16;
        int rA = base + m; if (rA > end - 1) rA = end - 1;
        const float* hp = h + (size_t)nidx[rA] * D;
        bf16x8 A0h, A0l, A1h, A1l;
        load_A_split(hp + quad * 8, A0h, A0l);
        load_A_split(hp + 32 + quad * 8, A1h, A1l);
        f32x4 acc[4];
#pragma unroll
        for (int c = 0; c < 4; ++c) acc[c] = (f32x4){0.f, 0.f, 0.f, 0.f};
        SPLIT_MFMA_BODY(acc, A0h, A0l, A1h, A1l, Bh, Bl)
#pragma unroll
        for (int reg = 0; reg < 4; ++reg) {
            int rr = base + quad * 4 + reg;
            if (rr < end) {
                size_t nb = (size_t)nidx[rr] * D;
#pragma unroll
                for (int c = 0; c < 4; ++c) {
                    float val = acc[c][reg];
                    size_t idx = nb + c * 16 + m;
                    if (a == 0) {
                        unsigned short hh = f2bf(val);
                        khi[idx] = hh;
                        klo[idx] = f2bf(val - bf2f(hh));
                    } else if (a == 1) {
                        qout[idx] = val;
                    } else {
                        vout[idx] = f2bf(val);
                    }
                }
            }
        }
    }
}

// ---------------- V2[n][r] = v_node[n] @ M[r]  (bf16, tolerance path) ----------------
// grid (SX, R), one wave/block
__global__ void v2_kernel(const unsigned short* __restrict__ vn, const float* __restrict__ Amsg,
                          unsigned short* __restrict__ V2, int N) {
    const int r = blockIdx.y, lane = threadIdx.x;
    const int m = lane & 15, quad = lane >> 4;
    const int nstrips = (N + 15) >> 4;
    const float* W = Amsg + (size_t)r * 4096;
    bf16x8 B[2][4];
#pragma unroll
    for (int ks = 0; ks < 2; ++ks)
#pragma unroll
        for (int c = 0; c < 4; ++c) B[ks][c] = load_B_frag(W, ks, c, lane);

    for (int s = blockIdx.x; s < nstrips; s += gridDim.x) {
        int base = s * 16;
        int rA = base + m; if (rA > N - 1) rA = N - 1;
        bf16x8 A0 = *(const bf16x8*)(vn + (size_t)rA * D + quad * 8);
        bf16x8 A1 = *(const bf16x8*)(vn + (size_t)rA * D + 32 + quad * 8);
        f32x4 acc[4];
#pragma unroll
        for (int c = 0; c < 4; ++c) acc[c] = (f32x4){0.f, 0.f, 0.f, 0.f};
#pragma unroll
        for (int c = 0; c < 4; ++c) {
            acc[c] = MFMA16(A0, B[0][c], acc[c]);
            acc[c] = MFMA16(A1, B[1][c], acc[c]);
        }
#pragma unroll
        for (int reg = 0; reg < 4; ++reg) {
            int rr = base + quad * 4 + reg;
            if (rr < N) {
#pragma unroll
                for (int c = 0; c < 4; ++c)
                    V2[((size_t)rr * RR + r) * D + c * 16 + m] = f2bf(acc[c][reg]);
            }
        }
    }
}

// ---------------- per-edge scores (fp32-accurate): sc = (k_node[src] @ A[r]) . q_node[dst] * pri/8 ----------------
// grid (SX, R), one wave/block; 16 edges per strip, relation-sorted
__global__ void score_kernel(const int* __restrict__ rsrc, const int* __restrict__ rdst,
                             const int* __restrict__ rdpos, const int* __restrict__ roff,
                             const unsigned short* __restrict__ khi, const unsigned short* __restrict__ klo,
                             const float* __restrict__ qn, const float* __restrict__ Aatt,
                             const float* __restrict__ pri, float* __restrict__ sc_d) {
    const int r = blockIdx.y, lane = threadIdx.x;
    const int beg = roff[r], end = roff[r + 1], cnt = end - beg;
    if (cnt <= 0) return;
    const int nstrips = (cnt + 15) >> 4;
    const int m = lane & 15, quad = lane >> 4;
    const float scale = pri[r] * 0.125f;
    const float* W = Aatt + (size_t)r * 4096;

    bf16x8 Bh[2][4], Bl[2][4];
#pragma unroll
    for (int ks = 0; ks < 2; ++ks)
#pragma unroll
        for (int c = 0; c < 4; ++c) load_B_split(W, ks, c, lane, Bh[ks][c], Bl[ks][c]);

    for (int st = blockIdx.x; st < nstrips; st += gridDim.x) {
        int base = st * 16;
        int ia = base + m; if (ia > cnt - 1) ia = cnt - 1;
        int s = rsrc[beg + ia];
        const unsigned short* kh = khi + (size_t)s * D;
        const unsigned short* kl = klo + (size_t)s * D;
        bf16x8 A0h = *(const bf16x8*)(kh + quad * 8);
        bf16x8 A1h = *(const bf16x8*)(kh + 32 + quad * 8);
        bf16x8 A0l = *(const bf16x8*)(kl + quad * 8);
        bf16x8 A1l = *(const bf16x8*)(kl + 32 + quad * 8);
        f32x4 acc[4];
#pragma unroll
        for (int c = 0; c < 4; ++c) acc[c] = (f32x4){0.f, 0.f, 0.f, 0.f};
        SPLIT_MFMA_BODY(acc, A0h, A0l, A1h, A1l, Bh, Bl)

        // rows: edge idx = quad*4+reg ; cols: c*16+m spread over quad's 16 lanes
        float p4[4];
#pragma unroll
        for (int reg = 0; reg < 4; ++reg) {
            int ie = base + quad * 4 + reg; if (ie > cnt - 1) ie = cnt - 1;
            const float* qp = qn + (size_t)rdst[beg + ie] * D + m;
            float pr = acc[0][reg] * qp[0] + acc[1][reg] * qp[16]
                     + acc[2][reg] * qp[32] + acc[3][reg] * qp[48];
#pragma unroll
            for (int d = 8; d; d >>= 1) pr += __shfl_xor(pr, d, 64);
            p4[reg] = pr;
        }
        if (m < 4) {
            int idx = base + quad * 4 + m;
            if (idx < cnt) {
                float v = (m == 0) ? p4[0] : (m == 1) ? p4[1] : (m == 2) ? p4[2] : p4[3];
                sc_d[rdpos[beg + idx]] = v * scale;
            }
        }
    }
}

// ---------------- per-dst online softmax + aggregation ----------------
__global__ void agg_kernel(const int* __restrict__ offs, const int* __restrict__ einfo,
                           const float* __restrict__ sc_d, const unsigned short* __restrict__ V2,
                           float* __restrict__ agg, int N) {
    const int w = threadIdx.x >> 6, lane = threadIdx.x & 63;
    const int i = blockIdx.x * 4 + w;
    if (i >= N) return;
    const int beg = offs[i], end = offs[i + 1];
    float mmax = -INFINITY, lsum = 0.f, acc = 0.f;
    for (int p = beg; p < end; ++p) {
        int info = einfo[p];
        float sc = sc_d[p];
        float vv = bf2f(V2[(size_t)info * D + lane]);
        float mn = fmaxf(mmax, sc);
        float cf = __expf(mmax - mn);      // 0 on first iteration
        float p1 = __expf(sc - mn);
        lsum = lsum * cf + p1;
        acc = acc * cf + p1 * vv;
        mmax = mn;
    }
    agg[(size_t)i * D + lane] = acc / (lsum + 1e-16f);
}

// ---------------- output transform (split-MFMA, in place on d_out) ----------------
// grid (SX, T), one wave/block
__global__ void out_kernel(float* __restrict__ io, const float* __restrict__ Wa,
                           const float* __restrict__ skip,
                           const int* __restrict__ toff, const int* __restrict__ nidx) {
    const int t = blockIdx.y, lane = threadIdx.x;
    const int beg = toff[t], end = toff[t + 1], cnt = end - beg;
    if (cnt <= 0) return;
    const int nstrips = (cnt + 15) >> 4;
    const float* W = Wa + (size_t)t * 4096;
    const float sg = 1.f / (1.f + __expf(-skip[t]));
    const int m = lane & 15, quad = lane >> 4;

    bf16x8 Bh[2][4], Bl[2][4];
#pragma unroll
    for (int ks = 0; ks < 2; ++ks)
#pragma unroll
        for (int c = 0; c < 4; ++c) load_B_split(W, ks, c, lane, Bh[ks][c], Bl[ks][c]);

    for (int s = blockIdx.x; s < nstrips; s += gridDim.x) {
        int base = beg + s * 16;
        int rA = base + m; if (rA > end - 1) rA = end - 1;
        const float* ap = io + (size_t)nidx[rA] * D;
        bf16x8 A0h, A0l, A1h, A1l;
        load_A_split(ap + quad * 8, A0h, A0l);
        load_A_split(ap + 32 + quad * 8, A1h, A1l);
        f32x4 acc[4];
#pragma unroll
        for (int c = 0; c < 4; ++c) acc[c] = (f32x4){0.f, 0.f, 0.f, 0.f};
        SPLIT_MFMA_BODY(acc, A0h, A0l, A1h, A1l, Bh, Bl)
#pragma unroll
        for (int reg = 0; reg < 4; ++reg) {
            int rr = base + quad * 4 + reg;
            if (rr < end) {
                size_t nb = (size_t)nidx[rr] * D;
#pragma unroll
                for (int c = 0; c < 4; ++c)
                    io[nb + c * 16 + m] = acc[c][reg] * sg;
            }
        }
    }
}

// ---------------- launch ----------------
extern "C" void kernel_launch(void* const* d_in, const int* in_sizes, int n_in,
                              void* d_out, int out_size, void* d_ws, size_t ws_size,
                              hipStream_t stream) {
    const float* h     = (const float*)d_in[0];
    const int*   adj   = (const int*)d_in[1];     // [2,E]: src row then dst row
    const int*   etype = (const int*)d_in[2];
    const int*   ntype = (const int*)d_in[3];
    const float* Wk    = (const float*)d_in[6];
    const float* Wq    = (const float*)d_in[7];
    const float* Wv    = (const float*)d_in[8];
    const float* Wa    = (const float*)d_in[9];
    const float* pri   = (const float*)d_in[10];
    const float* Aatt  = (const float*)d_in[11];
    const float* Amsg  = (const float*)d_in[12];
    const float* skp   = (const float*)d_in[13];
    const int N = in_sizes[3];
    const int E = in_sizes[2];
    float* out = (float*)d_out;

    char* w = (char*)d_ws;
    auto alloc = [&](size_t b) { char* p = w; w += (b + 255) & ~(size_t)255; return p; };
    unsigned short* khi = (unsigned short*)alloc((size_t)N * D * 2);
    unsigned short* klo = (unsigned short*)alloc((size_t)N * D * 2);
    float*          qn  = (float*)alloc((size_t)N * D * 4);
    unsigned short* vn  = (unsigned short*)alloc((size_t)N * D * 2);
    unsigned short* V2  = (unsigned short*)alloc((size_t)N * RR * D * 2);
    int* deg  = (int*)alloc((size_t)(N + 16) * 4);
    int* tcnt = deg + N;
    int* rcnt = deg + N + 8;
    int* offs = (int*)alloc((size_t)(N + 1) * 4);
    int* curs = (int*)alloc((size_t)N * 4);
    int* toff = (int*)alloc(64);
    int* tcur = (int*)alloc(64);
    int* roff = (int*)alloc(64);
    int* rcur = (int*)alloc(64);
    int* einfo = (int*)alloc((size_t)E * 4);
    float* sc_d = (float*)alloc((size_t)E * 4);
    int* rsrc  = (int*)alloc((size_t)E * 4);
    int* rdst  = (int*)alloc((size_t)E * 4);
    int* rdpos = (int*)alloc((size_t)E * 4);
    int* nidx  = (int*)alloc((size_t)N * 4);

    (void)hipMemsetAsync(deg, 0, (size_t)(N + 16) * 4, stream);

    const int mx = (E > N ? E : N);
    hist_kernel<<<(mx + 255) / 256, 256, 0, stream>>>(adj + E, etype, ntype, deg, tcnt, rcnt, N, E);
    scan_kernel<<<1, 1024, 0, stream>>>(deg, offs, curs, tcnt, toff, tcur, rcnt, roff, rcur, N);
    scatter_kernel<<<(mx + 255) / 256, 256, 0, stream>>>(adj, adj + E, etype, ntype,
                                                         curs, tcur, rcur,
                                                         einfo, rsrc, rdst, rdpos, nidx, N, E);
    proj_kernel<<<dim3(128, 3, TT), 64, 0, stream>>>(h, Wk, Wq, Wv, toff, nidx, khi, klo, qn, vn);
    v2_kernel<<<dim3(256, RR), 64, 0, stream>>>(vn, Amsg, V2, N);
    score_kernel<<<dim3(256, RR), 64, 0, stream>>>(rsrc, rdst, rdpos, roff, khi, klo, qn, Aatt, pri, sc_d);
    agg_kernel<<<(N + 3) / 4, 256, 0, stream>>>(offs, einfo, sc_d, V2, out, N);
    out_kernel<<<dim3(128, TT), 64, 0, stream>>>(out, Wa, skp, toff, nidx);
}

// Round 4
// 521.609 us; speedup vs baseline: 12.5969x; 12.5969x over previous
//
#include <hip/hip_runtime.h>
#include <math.h>

typedef float f32x4 __attribute__((ext_vector_type(4)));
typedef short bf16x8 __attribute__((ext_vector_type(8)));

#define D 64
#define TT 8
#define RR 8

// ---------------- scalar helpers ----------------
__device__ __forceinline__ float bf2f(unsigned short u) {
    union { unsigned int i; float f; } x;
    x.i = ((unsigned int)u) << 16;
    return x.f;
}
__device__ __forceinline__ unsigned short f2bf(float f) {
    union { float f; unsigned int i; } x;
    x.f = f;
    unsigned int i = x.i;
    unsigned int r = (i + 0x7FFFu + ((i >> 16) & 1u)) >> 16;   // RNE
    return (unsigned short)r;
}
struct BfPair { short hi; short lo; };
// split fp32 into bf16 hi + bf16 lo (x ~= hi + lo, error ~2^-17 |x|)
__device__ __forceinline__ BfPair split2(float x) {
    BfPair p;
    unsigned short h = f2bf(x);
    p.hi = (short)h;
    p.lo = (short)f2bf(x - bf2f(h));
    return p;
}
__device__ __forceinline__ void load_A_split(const float* __restrict__ p, bf16x8& ah, bf16x8& al) {
#pragma unroll
    for (int i = 0; i < 8; ++i) {
        BfPair s = split2(p[i]);
        ah[i] = s.hi; al[i] = s.lo;
    }
}
// B fragment (B[k][n] = W[k][n], row-major 64x64 fp32), split into hi/lo
__device__ __forceinline__ void load_B_split(const float* __restrict__ W, int ks, int c, int lane,
                                             bf16x8& bh, bf16x8& bl) {
    int n = lane & 15, q = lane >> 4;
#pragma unroll
    for (int i = 0; i < 8; ++i) {
        BfPair s = split2(W[(ks * 32 + q * 8 + i) * 64 + c * 16 + n]);
        bh[i] = s.hi; bl[i] = s.lo;
    }
}
// plain bf16 B fragment
__device__ __forceinline__ bf16x8 load_B_frag(const float* __restrict__ W, int ks, int c, int lane) {
    int n = lane & 15, q = lane >> 4;
    bf16x8 r;
#pragma unroll
    for (int i = 0; i < 8; ++i)
        r[i] = (short)f2bf(W[(ks * 32 + q * 8 + i) * 64 + c * 16 + n]);
    return r;
}

#define MFMA16(a, b, c) __builtin_amdgcn_mfma_f32_16x16x32_bf16(a, b, c, 0, 0, 0)

// 24 MFMAs: acc[c] += (A0h+A0l)@(B0h+B0l) + (A1h+A1l)@(B1h+B1l), dropping lo*lo
#define SPLIT_MFMA_BODY(acc, A0h, A0l, A1h, A1l, Bh, Bl)          \
    _Pragma("unroll")                                             \
    for (int c = 0; c < 4; ++c) {                                 \
        acc[c] = MFMA16(A0h, Bh[0][c], acc[c]);                   \
        acc[c] = MFMA16(A0l, Bh[0][c], acc[c]);                   \
        acc[c] = MFMA16(A0h, Bl[0][c], acc[c]);                   \
        acc[c] = MFMA16(A1h, Bh[1][c], acc[c]);                   \
        acc[c] = MFMA16(A1l, Bh[1][c], acc[c]);                   \
        acc[c] = MFMA16(A1h, Bl[1][c], acc[c]);                   \
    }

// ---------------- CSR build ----------------
// deg/curs atomics go to 50k distinct addresses (parallel across L2 channels, cheap).
// tcnt/rcnt/tcur/rcur have only 8 addresses -> hierarchical: LDS per-block histogram,
// one global atomic per bucket per block (25k atomics instead of 800k).
__global__ void hist_kernel(const int* __restrict__ dst, const int* __restrict__ et,
                            const int* __restrict__ nt,
                            int* __restrict__ deg, int* __restrict__ tcnt, int* __restrict__ rcnt,
                            int N, int E) {
    __shared__ int l_r[RR], l_t[TT];
    if (threadIdx.x < RR) l_r[threadIdx.x] = 0;
    if (threadIdx.x < TT) l_t[threadIdx.x] = 0;
    __syncthreads();
    int tid = blockIdx.x * blockDim.x + threadIdx.x;
    if (tid < E) {
        atomicAdd(&deg[dst[tid]], 1);
        atomicAdd(&l_r[et[tid]], 1);
    }
    if (tid < N) atomicAdd(&l_t[nt[tid]], 1);
    __syncthreads();
    if (threadIdx.x < RR && l_r[threadIdx.x]) atomicAdd(&rcnt[threadIdx.x], l_r[threadIdx.x]);
    if (threadIdx.x < TT && l_t[threadIdx.x]) atomicAdd(&tcnt[threadIdx.x], l_t[threadIdx.x]);
}

__global__ void scan_kernel(const int* __restrict__ deg, int* __restrict__ off,
                            int* __restrict__ cursor,
                            const int* __restrict__ tcnt, int* __restrict__ toff, int* __restrict__ tcur,
                            const int* __restrict__ rcnt, int* __restrict__ roff, int* __restrict__ rcur,
                            int N) {
    __shared__ int ps[1024];
    int tid = threadIdx.x;
    int chunk = (N + 1023) / 1024;
    int s0 = tid * chunk;
    int s1 = s0 + chunk; if (s1 > N) s1 = N;
    int sum = 0;
    for (int i = s0; i < s1; ++i) sum += deg[i];
    ps[tid] = sum;
    __syncthreads();
    for (int sh = 1; sh < 1024; sh <<= 1) {
        int v = (tid >= sh) ? ps[tid - sh] : 0;
        __syncthreads();
        ps[tid] += v;
        __syncthreads();
    }
    int run = (tid > 0) ? ps[tid - 1] : 0;
    for (int i = s0; i < s1; ++i) { off[i] = run; cursor[i] = run; run += deg[i]; }
    if (tid == 0) {
        off[N] = ps[1023];
        int a = 0;
        for (int t = 0; t < TT; ++t) { toff[t] = a; tcur[t] = a; a += tcnt[t]; }
        toff[TT] = a;
        int b = 0;
        for (int r = 0; r < RR; ++r) { roff[r] = b; rcur[r] = b; b += rcnt[r]; }
        roff[RR] = b;
    }
}

__global__ void scatter_kernel(const int* __restrict__ src, const int* __restrict__ dst,
                               const int* __restrict__ et, const int* __restrict__ nt,
                               int* __restrict__ curs, int* __restrict__ tcur, int* __restrict__ rcur,
                               int* __restrict__ einfo, int* __restrict__ rsrc, int* __restrict__ rdst,
                               int* __restrict__ rdpos, int* __restrict__ nidx, int N, int E) {
    __shared__ int l_r[RR], l_t[TT], base_r[RR], base_t[TT];
    if (threadIdx.x < RR) l_r[threadIdx.x] = 0;
    if (threadIdx.x < TT) l_t[threadIdx.x] = 0;
    __syncthreads();
    int tid = blockIdx.x * blockDim.x + threadIdx.x;
    int s = 0, d = 0, r = 0, t = 0, rrank = 0, trank = 0;
    if (tid < E) {
        s = src[tid]; d = dst[tid]; r = et[tid];
        rrank = atomicAdd(&l_r[r], 1);            // rank within block
    }
    if (tid < N) {
        t = nt[tid];
        trank = atomicAdd(&l_t[t], 1);
    }
    __syncthreads();
    if (threadIdx.x < RR)
        base_r[threadIdx.x] = l_r[threadIdx.x] ? atomicAdd(&rcur[threadIdx.x], l_r[threadIdx.x]) : 0;
    if (threadIdx.x < TT)
        base_t[threadIdx.x] = l_t[threadIdx.x] ? atomicAdd(&tcur[threadIdx.x], l_t[threadIdx.x]) : 0;
    __syncthreads();
    if (tid < E) {
        int pos = atomicAdd(&curs[d], 1);          // 50k addresses: cheap
        einfo[pos] = (s << 3) | r;                 // V2 row id, directly
        int rp = base_r[r] + rrank;
        rsrc[rp] = s; rdst[rp] = d; rdpos[rp] = pos;
    }
    if (tid < N) {
        nidx[base_t[t] + trank] = tid;
    }
}

// ---------------- node projections ----------------
// grid (SX, 3, T), one wave/block. a=0: k (split hi/lo bf16 out), a=1: q (fp32 out), a=2: v (bf16 out)
__global__ void proj_kernel(const float* __restrict__ h,
                            const float* __restrict__ Wk, const float* __restrict__ Wq,
                            const float* __restrict__ Wv,
                            const int* __restrict__ toff, const int* __restrict__ nidx,
                            unsigned short* __restrict__ khi, unsigned short* __restrict__ klo,
                            float* __restrict__ qout, unsigned short* __restrict__ vout) {
    const int t = blockIdx.z, a = blockIdx.y, lane = threadIdx.x;
    const int beg = toff[t], end = toff[t + 1], cnt = end - beg;
    if (cnt <= 0) return;
    const int nstrips = (cnt + 15) >> 4;
    const float* W = (a == 0 ? Wk : (a == 1 ? Wq : Wv)) + (size_t)t * 4096;
    const int m = lane & 15, quad = lane >> 4;

    bf16x8 Bh[2][4], Bl[2][4];
#pragma unroll
    for (int ks = 0; ks < 2; ++ks)
#pragma unroll
        for (int c = 0; c < 4; ++c) load_B_split(W, ks, c, lane, Bh[ks][c], Bl[ks][c]);

    for (int s = blockIdx.x; s < nstrips; s += gridDim.x) {
        int base = beg + s * 16;
        int rA = base + m; if (rA > end - 1) rA = end - 1;
        const float* hp = h + (size_t)nidx[rA] * D;
        bf16x8 A0h, A0l, A1h, A1l;
        load_A_split(hp + quad * 8, A0h, A0l);
        load_A_split(hp + 32 + quad * 8, A1h, A1l);
        f32x4 acc[4];
#pragma unroll
        for (int c = 0; c < 4; ++c) acc[c] = (f32x4){0.f, 0.f, 0.f, 0.f};
        SPLIT_MFMA_BODY(acc, A0h, A0l, A1h, A1l, Bh, Bl)
#pragma unroll
        for (int reg = 0; reg < 4; ++reg) {
            int rr = base + quad * 4 + reg;
            if (rr < end) {
                size_t nb = (size_t)nidx[rr] * D;
#pragma unroll
                for (int c = 0; c < 4; ++c) {
                    float val = acc[c][reg];
                    size_t idx = nb + c * 16 + m;
                    if (a == 0) {
                        unsigned short hh = f2bf(val);
                        khi[idx] = hh;
                        klo[idx] = f2bf(val - bf2f(hh));
                    } else if (a == 1) {
                        qout[idx] = val;
                    } else {
                        vout[idx] = f2bf(val);
                    }
                }
            }
        }
    }
}

// ---------------- V2[n][r] = v_node[n] @ M[r]  (bf16, tolerance path) ----------------
// grid (SX, R), one wave/block
__global__ void v2_kernel(const unsigned short* __restrict__ vn, const float* __restrict__ Amsg,
                          unsigned short* __restrict__ V2, int N) {
    const int r = blockIdx.y, lane = threadIdx.x;
    const int m = lane & 15, quad = lane >> 4;
    const int nstrips = (N + 15) >> 4;
    const float* W = Amsg + (size_t)r * 4096;
    bf16x8 B[2][4];
#pragma unroll
    for (int ks = 0; ks < 2; ++ks)
#pragma unroll
        for (int c = 0; c < 4; ++c) B[ks][c] = load_B_frag(W, ks, c, lane);

    for (int s = blockIdx.x; s < nstrips; s += gridDim.x) {
        int base = s * 16;
        int rA = base + m; if (rA > N - 1) rA = N - 1;
        bf16x8 A0 = *(const bf16x8*)(vn + (size_t)rA * D + quad * 8);
        bf16x8 A1 = *(const bf16x8*)(vn + (size_t)rA * D + 32 + quad * 8);
        f32x4 acc[4];
#pragma unroll
        for (int c = 0; c < 4; ++c) acc[c] = (f32x4){0.f, 0.f, 0.f, 0.f};
#pragma unroll
        for (int c = 0; c < 4; ++c) {
            acc[c] = MFMA16(A0, B[0][c], acc[c]);
            acc[c] = MFMA16(A1, B[1][c], acc[c]);
        }
#pragma unroll
        for (int reg = 0; reg < 4; ++reg) {
            int rr = base + quad * 4 + reg;
            if (rr < N) {
#pragma unroll
                for (int c = 0; c < 4; ++c)
                    V2[((size_t)rr * RR + r) * D + c * 16 + m] = f2bf(acc[c][reg]);
            }
        }
    }
}

// ---------------- per-edge scores (fp32-accurate): sc = (k_node[src] @ A[r]) . q_node[dst] * pri/8 ----------------
// grid (SX, R), one wave/block; 16 edges per strip, relation-sorted
__global__ void score_kernel(const int* __restrict__ rsrc, const int* __restrict__ rdst,
                             const int* __restrict__ rdpos, const int* __restrict__ roff,
                             const unsigned short* __restrict__ khi, const unsigned short* __restrict__ klo,
                             const float* __restrict__ qn, const float* __restrict__ Aatt,
                             const float* __restrict__ pri, float* __restrict__ sc_d) {
    const int r = blockIdx.y, lane = threadIdx.x;
    const int beg = roff[r], end = roff[r + 1], cnt = end - beg;
    if (cnt <= 0) return;
    const int nstrips = (cnt + 15) >> 4;
    const int m = lane & 15, quad = lane >> 4;
    const float scale = pri[r] * 0.125f;
    const float* W = Aatt + (size_t)r * 4096;

    bf16x8 Bh[2][4], Bl[2][4];
#pragma unroll
    for (int ks = 0; ks < 2; ++ks)
#pragma unroll
        for (int c = 0; c < 4; ++c) load_B_split(W, ks, c, lane, Bh[ks][c], Bl[ks][c]);

    for (int st = blockIdx.x; st < nstrips; st += gridDim.x) {
        int base = st * 16;
        int ia = base + m; if (ia > cnt - 1) ia = cnt - 1;
        int s = rsrc[beg + ia];
        const unsigned short* kh = khi + (size_t)s * D;
        const unsigned short* kl = klo + (size_t)s * D;
        bf16x8 A0h = *(const bf16x8*)(kh + quad * 8);
        bf16x8 A1h = *(const bf16x8*)(kh + 32 + quad * 8);
        bf16x8 A0l = *(const bf16x8*)(kl + quad * 8);
        bf16x8 A1l = *(const bf16x8*)(kl + 32 + quad * 8);
        f32x4 acc[4];
#pragma unroll
        for (int c = 0; c < 4; ++c) acc[c] = (f32x4){0.f, 0.f, 0.f, 0.f};
        SPLIT_MFMA_BODY(acc, A0h, A0l, A1h, A1l, Bh, Bl)

        // rows: edge idx = quad*4+reg ; cols: c*16+m spread over quad's 16 lanes
        float p4[4];
#pragma unroll
        for (int reg = 0; reg < 4; ++reg) {
            int ie = base + quad * 4 + reg; if (ie > cnt - 1) ie = cnt - 1;
            const float* qp = qn + (size_t)rdst[beg + ie] * D + m;
            float pr = acc[0][reg] * qp[0] + acc[1][reg] * qp[16]
                     + acc[2][reg] * qp[32] + acc[3][reg] * qp[48];
#pragma unroll
            for (int d = 8; d; d >>= 1) pr += __shfl_xor(pr, d, 64);
            p4[reg] = pr;
        }
        if (m < 4) {
            int idx = base + quad * 4 + m;
            if (idx < cnt) {
                float v = (m == 0) ? p4[0] : (m == 1) ? p4[1] : (m == 2) ? p4[2] : p4[3];
                sc_d[rdpos[beg + idx]] = v * scale;
            }
        }
    }
}

// ---------------- per-dst online softmax + aggregation ----------------
__global__ void agg_kernel(const int* __restrict__ offs, const int* __restrict__ einfo,
                           const float* __restrict__ sc_d, const unsigned short* __restrict__ V2,
                           float* __restrict__ agg, int N) {
    const int w = threadIdx.x >> 6, lane = threadIdx.x & 63;
    const int i = blockIdx.x * 4 + w;
    if (i >= N) return;
    const int beg = offs[i], end = offs[i + 1];
    float mmax = -INFINITY, lsum = 0.f, acc = 0.f;
    for (int p = beg; p < end; ++p) {
        int info = einfo[p];
        float sc = sc_d[p];
        float vv = bf2f(V2[(size_t)info * D + lane]);
        float mn = fmaxf(mmax, sc);
        float cf = __expf(mmax - mn);      // 0 on first iteration
        float p1 = __expf(sc - mn);
        lsum = lsum * cf + p1;
        acc = acc * cf + p1 * vv;
        mmax = mn;
    }
    agg[(size_t)i * D + lane] = acc / (lsum + 1e-16f);
}

// ---------------- output transform (split-MFMA, in place on d_out) ----------------
// grid (SX, T), one wave/block
__global__ void out_kernel(float* __restrict__ io, const float* __restrict__ Wa,
                           const float* __restrict__ skip,
                           const int* __restrict__ toff, const int* __restrict__ nidx) {
    const int t = blockIdx.y, lane = threadIdx.x;
    const int beg = toff[t], end = toff[t + 1], cnt = end - beg;
    if (cnt <= 0) return;
    const int nstrips = (cnt + 15) >> 4;
    const float* W = Wa + (size_t)t * 4096;
    const float sg = 1.f / (1.f + __expf(-skip[t]));
    const int m = lane & 15, quad = lane >> 4;

    bf16x8 Bh[2][4], Bl[2][4];
#pragma unroll
    for (int ks = 0; ks < 2; ++ks)
#pragma unroll
        for (int c = 0; c < 4; ++c) load_B_split(W, ks, c, lane, Bh[ks][c], Bl[ks][c]);

    for (int s = blockIdx.x; s < nstrips; s += gridDim.x) {
        int base = beg + s * 16;
        int rA = base + m; if (rA > end - 1) rA = end - 1;
        const float* ap = io + (size_t)nidx[rA] * D;
        bf16x8 A0h, A0l, A1h, A1l;
        load_A_split(ap + quad * 8, A0h, A0l);
        load_A_split(ap + 32 + quad * 8, A1h, A1l);
        f32x4 acc[4];
#pragma unroll
        for (int c = 0; c < 4; ++c) acc[c] = (f32x4){0.f, 0.f, 0.f, 0.f};
        SPLIT_MFMA_BODY(acc, A0h, A0l, A1h, A1l, Bh, Bl)
#pragma unroll
        for (int reg = 0; reg < 4; ++reg) {
            int rr = base + quad * 4 + reg;
            if (rr < end) {
                size_t nb = (size_t)nidx[rr] * D;
#pragma unroll
                for (int c = 0; c < 4; ++c)
                    io[nb + c * 16 + m] = acc[c][reg] * sg;
            }
        }
    }
}

// ---------------- launch ----------------
extern "C" void kernel_launch(void* const* d_in, const int* in_sizes, int n_in,
                              void* d_out, int out_size, void* d_ws, size_t ws_size,
                              hipStream_t stream) {
    const float* h     = (const float*)d_in[0];
    const int*   adj   = (const int*)d_in[1];     // [2,E]: src row then dst row
    const int*   etype = (const int*)d_in[2];
    const int*   ntype = (const int*)d_in[3];
    const float* Wk    = (const float*)d_in[6];
    const float* Wq    = (const float*)d_in[7];
    const float* Wv    = (const float*)d_in[8];
    const float* Wa    = (const float*)d_in[9];
    const float* pri   = (const float*)d_in[10];
    const float* Aatt  = (const float*)d_in[11];
    const float* Amsg  = (const float*)d_in[12];
    const float* skp   = (const float*)d_in[13];
    const int N = in_sizes[3];
    const int E = in_sizes[2];
    float* out = (float*)d_out;

    char* w = (char*)d_ws;
    auto alloc = [&](size_t b) { char* p = w; w += (b + 255) & ~(size_t)255; return p; };
    unsigned short* khi = (unsigned short*)alloc((size_t)N * D * 2);
    unsigned short* klo = (unsigned short*)alloc((size_t)N * D * 2);
    float*          qn  = (float*)alloc((size_t)N * D * 4);
    unsigned short* vn  = (unsigned short*)alloc((size_t)N * D * 2);
    unsigned short* V2  = (unsigned short*)alloc((size_t)N * RR * D * 2);
    int* deg  = (int*)alloc((size_t)(N + 16) * 4);
    int* tcnt = deg + N;
    int* rcnt = deg + N + 8;
    int* offs = (int*)alloc((size_t)(N + 1) * 4);
    int* curs = (int*)alloc((size_t)N * 4);
    int* toff = (int*)alloc(64);
    int* tcur = (int*)alloc(64);
    int* roff = (int*)alloc(64);
    int* rcur = (int*)alloc(64);
    int* einfo = (int*)alloc((size_t)E * 4);
    float* sc_d = (float*)alloc((size_t)E * 4);
    int* rsrc  = (int*)alloc((size_t)E * 4);
    int* rdst  = (int*)alloc((size_t)E * 4);
    int* rdpos = (int*)alloc((size_t)E * 4);
    int* nidx  = (int*)alloc((size_t)N * 4);

    (void)hipMemsetAsync(deg, 0, (size_t)(N + 16) * 4, stream);

    const int mx = (E > N ? E : N);
    hist_kernel<<<(mx + 255) / 256, 256, 0, stream>>>(adj + E, etype, ntype, deg, tcnt, rcnt, N, E);
    scan_kernel<<<1, 1024, 0, stream>>>(deg, offs, curs, tcnt, toff, tcur, rcnt, roff, rcur, N);
    scatter_kernel<<<(mx + 255) / 256, 256, 0, stream>>>(adj, adj + E, etype, ntype,
                                                         curs, tcur, rcur,
                                                         einfo, rsrc, rdst, rdpos, nidx, N, E);
    proj_kernel<<<dim3(128, 3, TT), 64, 0, stream>>>(h, Wk, Wq, Wv, toff, nidx, khi, klo, qn, vn);
    v2_kernel<<<dim3(256, RR), 64, 0, stream>>>(vn, Amsg, V2, N);
    score_kernel<<<dim3(256, RR), 64, 0, stream>>>(rsrc, rdst, rdpos, roff, khi, klo, qn, Aatt, pri, sc_d);
    agg_kernel<<<(N + 3) / 4, 256, 0, stream>>>(offs, einfo, sc_d, V2, out, N);
    out_kernel<<<dim3(128, TT), 64, 0, stream>>>(out, Wa, skp, toff, nidx);
}

// Round 5
// 437.085 us; speedup vs baseline: 15.0330x; 1.1934x over previous
//
#include <hip/hip_runtime.h>
#include <math.h>

typedef float f32x4 __attribute__((ext_vector_type(4)));
typedef short bf16x8 __attribute__((ext_vector_type(8)));

#define D 64
#define TT 8
#define RR 8

#define SCAN_TPB 256
#define SCAN_CH 4
#define SCAN_ELEMS (SCAN_TPB * SCAN_CH)   // 1024 elements per block

// ---------------- scalar helpers ----------------
__device__ __forceinline__ float bf2f(unsigned short u) {
    union { unsigned int i; float f; } x;
    x.i = ((unsigned int)u) << 16;
    return x.f;
}
__device__ __forceinline__ unsigned short f2bf(float f) {
    union { float f; unsigned int i; } x;
    x.f = f;
    unsigned int i = x.i;
    unsigned int r = (i + 0x7FFFu + ((i >> 16) & 1u)) >> 16;   // RNE
    return (unsigned short)r;
}
struct BfPair { short hi; short lo; };
// split fp32 into bf16 hi + bf16 lo (x ~= hi + lo, error ~2^-17 |x|)
__device__ __forceinline__ BfPair split2(float x) {
    BfPair p;
    unsigned short h = f2bf(x);
    p.hi = (short)h;
    p.lo = (short)f2bf(x - bf2f(h));
    return p;
}
__device__ __forceinline__ void load_A_split(const float* __restrict__ p, bf16x8& ah, bf16x8& al) {
#pragma unroll
    for (int i = 0; i < 8; ++i) {
        BfPair s = split2(p[i]);
        ah[i] = s.hi; al[i] = s.lo;
    }
}
// B fragment (B[k][n] = W[k][n], row-major 64x64 fp32), split into hi/lo
__device__ __forceinline__ void load_B_split(const float* __restrict__ W, int ks, int c, int lane,
                                             bf16x8& bh, bf16x8& bl) {
    int n = lane & 15, q = lane >> 4;
#pragma unroll
    for (int i = 0; i < 8; ++i) {
        BfPair s = split2(W[(ks * 32 + q * 8 + i) * 64 + c * 16 + n]);
        bh[i] = s.hi; bl[i] = s.lo;
    }
}
// plain bf16 B fragment
__device__ __forceinline__ bf16x8 load_B_frag(const float* __restrict__ W, int ks, int c, int lane) {
    int n = lane & 15, q = lane >> 4;
    bf16x8 r;
#pragma unroll
    for (int i = 0; i < 8; ++i)
        r[i] = (short)f2bf(W[(ks * 32 + q * 8 + i) * 64 + c * 16 + n]);
    return r;
}

#define MFMA16(a, b, c) __builtin_amdgcn_mfma_f32_16x16x32_bf16(a, b, c, 0, 0, 0)

// 24 MFMAs: acc[c] += (A0h+A0l)@(B0h+B0l) + (A1h+A1l)@(B1h+B1l), dropping lo*lo
#define SPLIT_MFMA_BODY(acc, A0h, A0l, A1h, A1l, Bh, Bl)          \
    _Pragma("unroll")                                             \
    for (int c = 0; c < 4; ++c) {                                 \
        acc[c] = MFMA16(A0h, Bh[0][c], acc[c]);                   \
        acc[c] = MFMA16(A0l, Bh[0][c], acc[c]);                   \
        acc[c] = MFMA16(A0h, Bl[0][c], acc[c]);                   \
        acc[c] = MFMA16(A1h, Bh[1][c], acc[c]);                   \
        acc[c] = MFMA16(A1l, Bh[1][c], acc[c]);                   \
        acc[c] = MFMA16(A1h, Bl[1][c], acc[c]);                   \
    }

// ---------------- CSR build ----------------
// deg/curs atomics go to 50k distinct addresses (parallel across L2 channels, cheap).
// tcnt/rcnt/tcur/rcur have only 8 addresses -> hierarchical: LDS per-block histogram,
// one global atomic per bucket per block.
__global__ void hist_kernel(const int* __restrict__ dst, const int* __restrict__ et,
                            const int* __restrict__ nt,
                            int* __restrict__ deg, int* __restrict__ tcnt, int* __restrict__ rcnt,
                            int N, int E) {
    __shared__ int l_r[RR], l_t[TT];
    if (threadIdx.x < RR) l_r[threadIdx.x] = 0;
    if (threadIdx.x < TT) l_t[threadIdx.x] = 0;
    __syncthreads();
    int tid = blockIdx.x * blockDim.x + threadIdx.x;
    if (tid < E) {
        atomicAdd(&deg[dst[tid]], 1);
        atomicAdd(&l_r[et[tid]], 1);
    }
    if (tid < N) atomicAdd(&l_t[nt[tid]], 1);
    __syncthreads();
    if (threadIdx.x < RR && l_r[threadIdx.x]) atomicAdd(&rcnt[threadIdx.x], l_r[threadIdx.x]);
    if (threadIdx.x < TT && l_t[threadIdx.x]) atomicAdd(&tcnt[threadIdx.x], l_t[threadIdx.x]);
}

// ---- 3-phase device-wide exclusive scan of deg[0..N) ----
// phase 1: per-block partial sums
__global__ void scan_sum_kernel(const int* __restrict__ deg, int* __restrict__ bsum, int N) {
    __shared__ int ws[SCAN_TPB / 64];
    int tid = threadIdx.x;
    int base = blockIdx.x * SCAN_ELEMS + tid * SCAN_CH;
    int s = 0;
#pragma unroll
    for (int i = 0; i < SCAN_CH; ++i) {
        int idx = base + i;
        if (idx < N) s += deg[idx];
    }
#pragma unroll
    for (int d = 32; d; d >>= 1) s += __shfl_xor(s, d, 64);
    if ((tid & 63) == 0) ws[tid >> 6] = s;
    __syncthreads();
    if (tid == 0) {
        int t = 0;
#pragma unroll
        for (int i = 0; i < SCAN_TPB / 64; ++i) t += ws[i];
        bsum[blockIdx.x] = t;
    }
}
// phase 2: serial scan of ~49 block sums + type/relation offsets (single tiny block)
__global__ void scan_mid_kernel(const int* __restrict__ bsum, int* __restrict__ bbase, int nsb,
                                const int* __restrict__ tcnt, int* __restrict__ toff, int* __restrict__ tcur,
                                const int* __restrict__ rcnt, int* __restrict__ roff, int* __restrict__ rcur) {
    if (threadIdx.x == 0) {
        int run = 0;
        for (int b = 0; b < nsb; ++b) { bbase[b] = run; run += bsum[b]; }
        int a = 0;
        for (int t = 0; t < TT; ++t) { toff[t] = a; tcur[t] = a; a += tcnt[t]; }
        toff[TT] = a;
        int bb = 0;
        for (int r = 0; r < RR; ++r) { roff[r] = bb; rcur[r] = bb; bb += rcnt[r]; }
        roff[RR] = bb;
    }
}
// phase 3: block-local scan + global base -> off/cursor
__global__ void scan_out_kernel(const int* __restrict__ deg, const int* __restrict__ bbase,
                                int* __restrict__ off, int* __restrict__ cursor, int N, int Etot) {
    __shared__ int ts[SCAN_TPB];
    int tid = threadIdx.x;
    int base = blockIdx.x * SCAN_ELEMS + tid * SCAN_CH;
    int loc[SCAN_CH];
    int s = 0;
#pragma unroll
    for (int i = 0; i < SCAN_CH; ++i) {
        int idx = base + i;
        int v = (idx < N) ? deg[idx] : 0;
        loc[i] = v; s += v;
    }
    ts[tid] = s;
    __syncthreads();
    for (int sh = 1; sh < SCAN_TPB; sh <<= 1) {
        int v = (tid >= sh) ? ts[tid - sh] : 0;
        __syncthreads();
        ts[tid] += v;
        __syncthreads();
    }
    int run = bbase[blockIdx.x] + ((tid > 0) ? ts[tid - 1] : 0);
#pragma unroll
    for (int i = 0; i < SCAN_CH; ++i) {
        int idx = base + i;
        if (idx < N) { off[idx] = run; cursor[idx] = run; run += loc[i]; }
    }
    if (blockIdx.x == 0 && tid == 0) off[N] = Etot;
}

__global__ void scatter_kernel(const int* __restrict__ src, const int* __restrict__ dst,
                               const int* __restrict__ et, const int* __restrict__ nt,
                               int* __restrict__ curs, int* __restrict__ tcur, int* __restrict__ rcur,
                               int* __restrict__ einfo, int* __restrict__ rsrc, int* __restrict__ rdst,
                               int* __restrict__ rdpos, int* __restrict__ nidx, int N, int E) {
    __shared__ int l_r[RR], l_t[TT], base_r[RR], base_t[TT];
    if (threadIdx.x < RR) l_r[threadIdx.x] = 0;
    if (threadIdx.x < TT) l_t[threadIdx.x] = 0;
    __syncthreads();
    int tid = blockIdx.x * blockDim.x + threadIdx.x;
    int s = 0, d = 0, r = 0, t = 0, rrank = 0, trank = 0;
    if (tid < E) {
        s = src[tid]; d = dst[tid]; r = et[tid];
        rrank = atomicAdd(&l_r[r], 1);            // rank within block
    }
    if (tid < N) {
        t = nt[tid];
        trank = atomicAdd(&l_t[t], 1);
    }
    __syncthreads();
    if (threadIdx.x < RR)
        base_r[threadIdx.x] = l_r[threadIdx.x] ? atomicAdd(&rcur[threadIdx.x], l_r[threadIdx.x]) : 0;
    if (threadIdx.x < TT)
        base_t[threadIdx.x] = l_t[threadIdx.x] ? atomicAdd(&tcur[threadIdx.x], l_t[threadIdx.x]) : 0;
    __syncthreads();
    if (tid < E) {
        int pos = atomicAdd(&curs[d], 1);          // 50k addresses: cheap
        einfo[pos] = (s << 3) | r;                 // V2 row id, directly
        int rp = base_r[r] + rrank;
        rsrc[rp] = s; rdst[rp] = d; rdpos[rp] = pos;
    }
    if (tid < N) {
        nidx[base_t[t] + trank] = tid;
    }
}

// ---------------- node projections ----------------
// grid (SX, 3, T), one wave/block. a=0: k (split hi/lo bf16 out), a=1: q (fp32 out), a=2: v (bf16 out)
__global__ void proj_kernel(const float* __restrict__ h,
                            const float* __restrict__ Wk, const float* __restrict__ Wq,
                            const float* __restrict__ Wv,
                            const int* __restrict__ toff, const int* __restrict__ nidx,
                            unsigned short* __restrict__ khi, unsigned short* __restrict__ klo,
                            float* __restrict__ qout, unsigned short* __restrict__ vout) {
    const int t = blockIdx.z, a = blockIdx.y, lane = threadIdx.x;
    const int beg = toff[t], end = toff[t + 1], cnt = end - beg;
    if (cnt <= 0) return;
    const int nstrips = (cnt + 15) >> 4;
    const float* W = (a == 0 ? Wk : (a == 1 ? Wq : Wv)) + (size_t)t * 4096;
    const int m = lane & 15, quad = lane >> 4;

    bf16x8 Bh[2][4], Bl[2][4];
#pragma unroll
    for (int ks = 0; ks < 2; ++ks)
#pragma unroll
        for (int c = 0; c < 4; ++c) load_B_split(W, ks, c, lane, Bh[ks][c], Bl[ks][c]);

    for (int s = blockIdx.x; s < nstrips; s += gridDim.x) {
        int base = beg + s * 16;
        int rA = base + m; if (rA > end - 1) rA = end - 1;
        const float* hp = h + (size_t)nidx[rA] * D;
        bf16x8 A0h, A0l, A1h, A1l;
        load_A_split(hp + quad * 8, A0h, A0l);
        load_A_split(hp + 32 + quad * 8, A1h, A1l);
        f32x4 acc[4];
#pragma unroll
        for (int c = 0; c < 4; ++c) acc[c] = (f32x4){0.f, 0.f, 0.f, 0.f};
        SPLIT_MFMA_BODY(acc, A0h, A0l, A1h, A1l, Bh, Bl)
#pragma unroll
        for (int reg = 0; reg < 4; ++reg) {
            int rr = base + quad * 4 + reg;
            if (rr < end) {
                size_t nb = (size_t)nidx[rr] * D;
#pragma unroll
                for (int c = 0; c < 4; ++c) {
                    float val = acc[c][reg];
                    size_t idx = nb + c * 16 + m;
                    if (a == 0) {
                        unsigned short hh = f2bf(val);
                        khi[idx] = hh;
                        klo[idx] = f2bf(val - bf2f(hh));
                    } else if (a == 1) {
                        qout[idx] = val;
                    } else {
                        vout[idx] = f2bf(val);
                    }
                }
            }
        }
    }
}

// ---------------- V2[n][r] = v_node[n] @ M[r]  (bf16, tolerance path) ----------------
// grid (SX, R), one wave/block
__global__ void v2_kernel(const unsigned short* __restrict__ vn, const float* __restrict__ Amsg,
                          unsigned short* __restrict__ V2, int N) {
    const int r = blockIdx.y, lane = threadIdx.x;
    const int m = lane & 15, quad = lane >> 4;
    const int nstrips = (N + 15) >> 4;
    const float* W = Amsg + (size_t)r * 4096;
    bf16x8 B[2][4];
#pragma unroll
    for (int ks = 0; ks < 2; ++ks)
#pragma unroll
        for (int c = 0; c < 4; ++c) B[ks][c] = load_B_frag(W, ks, c, lane);

    for (int s = blockIdx.x; s < nstrips; s += gridDim.x) {
        int base = s * 16;
        int rA = base + m; if (rA > N - 1) rA = N - 1;
        bf16x8 A0 = *(const bf16x8*)(vn + (size_t)rA * D + quad * 8);
        bf16x8 A1 = *(const bf16x8*)(vn + (size_t)rA * D + 32 + quad * 8);
        f32x4 acc[4];
#pragma unroll
        for (int c = 0; c < 4; ++c) acc[c] = (f32x4){0.f, 0.f, 0.f, 0.f};
#pragma unroll
        for (int c = 0; c < 4; ++c) {
            acc[c] = MFMA16(A0, B[0][c], acc[c]);
            acc[c] = MFMA16(A1, B[1][c], acc[c]);
        }
#pragma unroll
        for (int reg = 0; reg < 4; ++reg) {
            int rr = base + quad * 4 + reg;
            if (rr < N) {
#pragma unroll
                for (int c = 0; c < 4; ++c)
                    V2[((size_t)rr * RR + r) * D + c * 16 + m] = f2bf(acc[c][reg]);
            }
        }
    }
}

// ---------------- per-edge scores (fp32-accurate): sc = (k_node[src] @ A[r]) . q_node[dst] * pri/8 ----------------
// grid (SX, R), one wave/block; 16 edges per strip, relation-sorted
__global__ void score_kernel(const int* __restrict__ rsrc, const int* __restrict__ rdst,
                             const int* __restrict__ rdpos, const int* __restrict__ roff,
                             const unsigned short* __restrict__ khi, const unsigned short* __restrict__ klo,
                             const float* __restrict__ qn, const float* __restrict__ Aatt,
                             const float* __restrict__ pri, float* __restrict__ sc_d) {
    const int r = blockIdx.y, lane = threadIdx.x;
    const int beg = roff[r], end = roff[r + 1], cnt = end - beg;
    if (cnt <= 0) return;
    const int nstrips = (cnt + 15) >> 4;
    const int m = lane & 15, quad = lane >> 4;
    const float scale = pri[r] * 0.125f;
    const float* W = Aatt + (size_t)r * 4096;

    bf16x8 Bh[2][4], Bl[2][4];
#pragma unroll
    for (int ks = 0; ks < 2; ++ks)
#pragma unroll
        for (int c = 0; c < 4; ++c) load_B_split(W, ks, c, lane, Bh[ks][c], Bl[ks][c]);

    for (int st = blockIdx.x; st < nstrips; st += gridDim.x) {
        int base = st * 16;
        int ia = base + m; if (ia > cnt - 1) ia = cnt - 1;
        int s = rsrc[beg + ia];
        const unsigned short* kh = khi + (size_t)s * D;
        const unsigned short* kl = klo + (size_t)s * D;
        bf16x8 A0h = *(const bf16x8*)(kh + quad * 8);
        bf16x8 A1h = *(const bf16x8*)(kh + 32 + quad * 8);
        bf16x8 A0l = *(const bf16x8*)(kl + quad * 8);
        bf16x8 A1l = *(const bf16x8*)(kl + 32 + quad * 8);
        f32x4 acc[4];
#pragma unroll
        for (int c = 0; c < 4; ++c) acc[c] = (f32x4){0.f, 0.f, 0.f, 0.f};
        SPLIT_MFMA_BODY(acc, A0h, A0l, A1h, A1l, Bh, Bl)

        // rows: edge idx = quad*4+reg ; cols: c*16+m spread over quad's 16 lanes
        float p4[4];
#pragma unroll
        for (int reg = 0; reg < 4; ++reg) {
            int ie = base + quad * 4 + reg; if (ie > cnt - 1) ie = cnt - 1;
            const float* qp = qn + (size_t)rdst[beg + ie] * D + m;
            float pr = acc[0][reg] * qp[0] + acc[1][reg] * qp[16]
                     + acc[2][reg] * qp[32] + acc[3][reg] * qp[48];
#pragma unroll
            for (int d = 8; d; d >>= 1) pr += __shfl_xor(pr, d, 64);
            p4[reg] = pr;
        }
        if (m < 4) {
            int idx = base + quad * 4 + m;
            if (idx < cnt) {
                float v = (m == 0) ? p4[0] : (m == 1) ? p4[1] : (m == 2) ? p4[2] : p4[3];
                sc_d[rdpos[beg + idx]] = v * scale;
            }
        }
    }
}

// ---------------- per-dst online softmax + aggregation ----------------
__global__ void agg_kernel(const int* __restrict__ offs, const int* __restrict__ einfo,
                           const float* __restrict__ sc_d, const unsigned short* __restrict__ V2,
                           float* __restrict__ agg, int N) {
    const int w = threadIdx.x >> 6, lane = threadIdx.x & 63;
    const int i = blockIdx.x * 4 + w;
    if (i >= N) return;
    const int beg = offs[i], end = offs[i + 1];
    float mmax = -INFINITY, lsum = 0.f, acc = 0.f;
    for (int p = beg; p < end; ++p) {
        int info = einfo[p];
        float sc = sc_d[p];
        float vv = bf2f(V2[(size_t)info * D + lane]);
        float mn = fmaxf(mmax, sc);
        float cf = __expf(mmax - mn);      // 0 on first iteration
        float p1 = __expf(sc - mn);
        lsum = lsum * cf + p1;
        acc = acc * cf + p1 * vv;
        mmax = mn;
    }
    agg[(size_t)i * D + lane] = acc / (lsum + 1e-16f);
}

// ---------------- output transform (split-MFMA, in place on d_out) ----------------
// grid (SX, T), one wave/block
__global__ void out_kernel(float* __restrict__ io, const float* __restrict__ Wa,
                           const float* __restrict__ skip,
                           const int* __restrict__ toff, const int* __restrict__ nidx) {
    const int t = blockIdx.y, lane = threadIdx.x;
    const int beg = toff[t], end = toff[t + 1], cnt = end - beg;
    if (cnt <= 0) return;
    const int nstrips = (cnt + 15) >> 4;
    const float* W = Wa + (size_t)t * 4096;
    const float sg = 1.f / (1.f + __expf(-skip[t]));
    const int m = lane & 15, quad = lane >> 4;

    bf16x8 Bh[2][4], Bl[2][4];
#pragma unroll
    for (int ks = 0; ks < 2; ++ks)
#pragma unroll
        for (int c = 0; c < 4; ++c) load_B_split(W, ks, c, lane, Bh[ks][c], Bl[ks][c]);

    for (int s = blockIdx.x; s < nstrips; s += gridDim.x) {
        int base = beg + s * 16;
        int rA = base + m; if (rA > end - 1) rA = end - 1;
        const float* ap = io + (size_t)nidx[rA] * D;
        bf16x8 A0h, A0l, A1h, A1l;
        load_A_split(ap + quad * 8, A0h, A0l);
        load_A_split(ap + 32 + quad * 8, A1h, A1l);
        f32x4 acc[4];
#pragma unroll
        for (int c = 0; c < 4; ++c) acc[c] = (f32x4){0.f, 0.f, 0.f, 0.f};
        SPLIT_MFMA_BODY(acc, A0h, A0l, A1h, A1l, Bh, Bl)
#pragma unroll
        for (int reg = 0; reg < 4; ++reg) {
            int rr = base + quad * 4 + reg;
            if (rr < end) {
                size_t nb = (size_t)nidx[rr] * D;
#pragma unroll
                for (int c = 0; c < 4; ++c)
                    io[nb + c * 16 + m] = acc[c][reg] * sg;
            }
        }
    }
}

// ---------------- launch ----------------
extern "C" void kernel_launch(void* const* d_in, const int* in_sizes, int n_in,
                              void* d_out, int out_size, void* d_ws, size_t ws_size,
                              hipStream_t stream) {
    const float* h     = (const float*)d_in[0];
    const int*   adj   = (const int*)d_in[1];     // [2,E]: src row then dst row
    const int*   etype = (const int*)d_in[2];
    const int*   ntype = (const int*)d_in[3];
    const float* Wk    = (const float*)d_in[6];
    const float* Wq    = (const float*)d_in[7];
    const float* Wv    = (const float*)d_in[8];
    const float* Wa    = (const float*)d_in[9];
    const float* pri   = (const float*)d_in[10];
    const float* Aatt  = (const float*)d_in[11];
    const float* Amsg  = (const float*)d_in[12];
    const float* skp   = (const float*)d_in[13];
    const int N = in_sizes[3];
    const int E = in_sizes[2];
    float* out = (float*)d_out;

    char* w = (char*)d_ws;
    auto alloc = [&](size_t b) { char* p = w; w += (b + 255) & ~(size_t)255; return p; };
    unsigned short* khi = (unsigned short*)alloc((size_t)N * D * 2);
    unsigned short* klo = (unsigned short*)alloc((size_t)N * D * 2);
    float*          qn  = (float*)alloc((size_t)N * D * 4);
    unsigned short* vn  = (unsigned short*)alloc((size_t)N * D * 2);
    unsigned short* V2  = (unsigned short*)alloc((size_t)N * RR * D * 2);
    int* deg  = (int*)alloc((size_t)(N + 16) * 4);
    int* tcnt = deg + N;
    int* rcnt = deg + N + 8;
    int* offs = (int*)alloc((size_t)(N + 1) * 4);
    int* curs = (int*)alloc((size_t)N * 4);
    int* toff = (int*)alloc(64);
    int* tcur = (int*)alloc(64);
    int* roff = (int*)alloc(64);
    int* rcur = (int*)alloc(64);
    int* einfo = (int*)alloc((size_t)E * 4);
    float* sc_d = (float*)alloc((size_t)E * 4);
    int* rsrc  = (int*)alloc((size_t)E * 4);
    int* rdst  = (int*)alloc((size_t)E * 4);
    int* rdpos = (int*)alloc((size_t)E * 4);
    int* nidx  = (int*)alloc((size_t)N * 4);
    const int nsb = (N + SCAN_ELEMS - 1) / SCAN_ELEMS;
    int* bsum  = (int*)alloc((size_t)nsb * 4);
    int* bbase = (int*)alloc((size_t)nsb * 4);

    (void)hipMemsetAsync(deg, 0, (size_t)(N + 16) * 4, stream);

    const int mx = (E > N ? E : N);
    hist_kernel<<<(mx + 255) / 256, 256, 0, stream>>>(adj + E, etype, ntype, deg, tcnt, rcnt, N, E);
    scan_sum_kernel<<<nsb, SCAN_TPB, 0, stream>>>(deg, bsum, N);
    scan_mid_kernel<<<1, 64, 0, stream>>>(bsum, bbase, nsb, tcnt, toff, tcur, rcnt, roff, rcur);
    scan_out_kernel<<<nsb, SCAN_TPB, 0, stream>>>(deg, bbase, offs, curs, N, E);
    scatter_kernel<<<(mx + 255) / 256, 256, 0, stream>>>(adj, adj + E, etype, ntype,
                                                         curs, tcur, rcur,
                                                         einfo, rsrc, rdst, rdpos, nidx, N, E);
    proj_kernel<<<dim3(128, 3, TT), 64, 0, stream>>>(h, Wk, Wq, Wv, toff, nidx, khi, klo, qn, vn);
    v2_kernel<<<dim3(256, RR), 64, 0, stream>>>(vn, Amsg, V2, N);
    score_kernel<<<dim3(256, RR), 64, 0, stream>>>(rsrc, rdst, rdpos, roff, khi, klo, qn, Aatt, pri, sc_d);
    agg_kernel<<<(N + 3) / 4, 256, 0, stream>>>(offs, einfo, sc_d, V2, out, N);
    out_kernel<<<dim3(128, TT), 64, 0, stream>>>(out, Wa, skp, toff, nidx);
}

// Round 6
// 378.008 us; speedup vs baseline: 17.3823x; 1.1563x over previous
//
#include <hip/hip_runtime.h>
#include <math.h>

typedef float f32x4 __attribute__((ext_vector_type(4)));
typedef short bf16x8 __attribute__((ext_vector_type(8)));

#define D 64
#define TT 8
#define RR 8

#define SCAN_TPB 256
#define SCAN_CH 4
#define SCAN_ELEMS (SCAN_TPB * SCAN_CH)   // 1024 elements per block

// ---------------- scalar helpers ----------------
__device__ __forceinline__ float bf2f(unsigned short u) {
    union { unsigned int i; float f; } x;
    x.i = ((unsigned int)u) << 16;
    return x.f;
}
__device__ __forceinline__ unsigned short f2bf(float f) {
    union { float f; unsigned int i; } x;
    x.f = f;
    unsigned int i = x.i;
    unsigned int r = (i + 0x7FFFu + ((i >> 16) & 1u)) >> 16;   // RNE
    return (unsigned short)r;
}
struct BfPair { short hi; short lo; };
// split fp32 into bf16 hi + bf16 lo (x ~= hi + lo, error ~2^-17 |x|)
__device__ __forceinline__ BfPair split2(float x) {
    BfPair p;
    unsigned short h = f2bf(x);
    p.hi = (short)h;
    p.lo = (short)f2bf(x - bf2f(h));
    return p;
}
__device__ __forceinline__ void load_A_split(const float* __restrict__ p, bf16x8& ah, bf16x8& al) {
#pragma unroll
    for (int i = 0; i < 8; ++i) {
        BfPair s = split2(p[i]);
        ah[i] = s.hi; al[i] = s.lo;
    }
}
// B fragment (B[k][n] = W[k][n], row-major 64x64 fp32), split into hi/lo
__device__ __forceinline__ void load_B_split(const float* __restrict__ W, int ks, int c, int lane,
                                             bf16x8& bh, bf16x8& bl) {
    int n = lane & 15, q = lane >> 4;
#pragma unroll
    for (int i = 0; i < 8; ++i) {
        BfPair s = split2(W[(ks * 32 + q * 8 + i) * 64 + c * 16 + n]);
        bh[i] = s.hi; bl[i] = s.lo;
    }
}
// plain bf16 B fragment
__device__ __forceinline__ bf16x8 load_B_frag(const float* __restrict__ W, int ks, int c, int lane) {
    int n = lane & 15, q = lane >> 4;
    bf16x8 r;
#pragma unroll
    for (int i = 0; i < 8; ++i)
        r[i] = (short)f2bf(W[(ks * 32 + q * 8 + i) * 64 + c * 16 + n]);
    return r;
}

#define MFMA16(a, b, c) __builtin_amdgcn_mfma_f32_16x16x32_bf16(a, b, c, 0, 0, 0)

// 24 MFMAs: acc[c] += (A0h+A0l)@(B0h+B0l) + (A1h+A1l)@(B1h+B1l), dropping lo*lo
#define SPLIT_MFMA_BODY(acc, A0h, A0l, A1h, A1l, Bh, Bl)          \
    _Pragma("unroll")                                             \
    for (int c = 0; c < 4; ++c) {                                 \
        acc[c] = MFMA16(A0h, Bh[0][c], acc[c]);                   \
        acc[c] = MFMA16(A0l, Bh[0][c], acc[c]);                   \
        acc[c] = MFMA16(A0h, Bl[0][c], acc[c]);                   \
        acc[c] = MFMA16(A1h, Bh[1][c], acc[c]);                   \
        acc[c] = MFMA16(A1l, Bh[1][c], acc[c]);                   \
        acc[c] = MFMA16(A1h, Bl[1][c], acc[c]);                   \
    }

// ---------------- CSR build ----------------
__global__ void hist_kernel(const int* __restrict__ dst, const int* __restrict__ et,
                            const int* __restrict__ nt,
                            int* __restrict__ deg, int* __restrict__ tcnt, int* __restrict__ rcnt,
                            int N, int E) {
    __shared__ int l_r[RR], l_t[TT];
    if (threadIdx.x < RR) l_r[threadIdx.x] = 0;
    if (threadIdx.x < TT) l_t[threadIdx.x] = 0;
    __syncthreads();
    int tid = blockIdx.x * blockDim.x + threadIdx.x;
    if (tid < E) {
        atomicAdd(&deg[dst[tid]], 1);
        atomicAdd(&l_r[et[tid]], 1);
    }
    if (tid < N) atomicAdd(&l_t[nt[tid]], 1);
    __syncthreads();
    if (threadIdx.x < RR && l_r[threadIdx.x]) atomicAdd(&rcnt[threadIdx.x], l_r[threadIdx.x]);
    if (threadIdx.x < TT && l_t[threadIdx.x]) atomicAdd(&tcnt[threadIdx.x], l_t[threadIdx.x]);
}

// ---- 3-phase device-wide exclusive scan of deg[0..N) ----
__global__ void scan_sum_kernel(const int* __restrict__ deg, int* __restrict__ bsum, int N) {
    __shared__ int ws[SCAN_TPB / 64];
    int tid = threadIdx.x;
    int base = blockIdx.x * SCAN_ELEMS + tid * SCAN_CH;
    int s = 0;
#pragma unroll
    for (int i = 0; i < SCAN_CH; ++i) {
        int idx = base + i;
        if (idx < N) s += deg[idx];
    }
#pragma unroll
    for (int d = 32; d; d >>= 1) s += __shfl_xor(s, d, 64);
    if ((tid & 63) == 0) ws[tid >> 6] = s;
    __syncthreads();
    if (tid == 0) {
        int t = 0;
#pragma unroll
        for (int i = 0; i < SCAN_TPB / 64; ++i) t += ws[i];
        bsum[blockIdx.x] = t;
    }
}
__global__ void scan_mid_kernel(const int* __restrict__ bsum, int* __restrict__ bbase, int nsb,
                                const int* __restrict__ tcnt, int* __restrict__ toff, int* __restrict__ tcur,
                                const int* __restrict__ rcnt, int* __restrict__ roff, int* __restrict__ rcur) {
    if (threadIdx.x == 0) {
        int run = 0;
        for (int b = 0; b < nsb; ++b) { bbase[b] = run; run += bsum[b]; }
        int a = 0;
        for (int t = 0; t < TT; ++t) { toff[t] = a; tcur[t] = a; a += tcnt[t]; }
        toff[TT] = a;
        int bb = 0;
        for (int r = 0; r < RR; ++r) { roff[r] = bb; rcur[r] = bb; bb += rcnt[r]; }
        roff[RR] = bb;
    }
}
__global__ void scan_out_kernel(const int* __restrict__ deg, const int* __restrict__ bbase,
                                int* __restrict__ off, int* __restrict__ cursor, int N, int Etot) {
    __shared__ int ts[SCAN_TPB];
    int tid = threadIdx.x;
    int base = blockIdx.x * SCAN_ELEMS + tid * SCAN_CH;
    int loc[SCAN_CH];
    int s = 0;
#pragma unroll
    for (int i = 0; i < SCAN_CH; ++i) {
        int idx = base + i;
        int v = (idx < N) ? deg[idx] : 0;
        loc[i] = v; s += v;
    }
    ts[tid] = s;
    __syncthreads();
    for (int sh = 1; sh < SCAN_TPB; sh <<= 1) {
        int v = (tid >= sh) ? ts[tid - sh] : 0;
        __syncthreads();
        ts[tid] += v;
        __syncthreads();
    }
    int run = bbase[blockIdx.x] + ((tid > 0) ? ts[tid - 1] : 0);
#pragma unroll
    for (int i = 0; i < SCAN_CH; ++i) {
        int idx = base + i;
        if (idx < N) { off[idx] = run; cursor[idx] = run; run += loc[i]; }
    }
    if (blockIdx.x == 0 && tid == 0) off[N] = Etot;
}

// scatter: NO einfo write (score_kernel writes the combined {score,einfo} record).
__global__ void scatter_kernel(const int* __restrict__ src, const int* __restrict__ dst,
                               const int* __restrict__ et, const int* __restrict__ nt,
                               int* __restrict__ curs, int* __restrict__ tcur, int* __restrict__ rcur,
                               int* __restrict__ rsrc, int* __restrict__ rdst,
                               int* __restrict__ rdpos, int* __restrict__ nidx, int N, int E) {
    __shared__ int l_r[RR], l_t[TT], base_r[RR], base_t[TT];
    if (threadIdx.x < RR) l_r[threadIdx.x] = 0;
    if (threadIdx.x < TT) l_t[threadIdx.x] = 0;
    __syncthreads();
    int tid = blockIdx.x * blockDim.x + threadIdx.x;
    int s = 0, d = 0, r = 0, t = 0, rrank = 0, trank = 0;
    if (tid < E) {
        s = src[tid]; d = dst[tid]; r = et[tid];
        rrank = atomicAdd(&l_r[r], 1);            // rank within block
    }
    if (tid < N) {
        t = nt[tid];
        trank = atomicAdd(&l_t[t], 1);
    }
    __syncthreads();
    if (threadIdx.x < RR)
        base_r[threadIdx.x] = l_r[threadIdx.x] ? atomicAdd(&rcur[threadIdx.x], l_r[threadIdx.x]) : 0;
    if (threadIdx.x < TT)
        base_t[threadIdx.x] = l_t[threadIdx.x] ? atomicAdd(&tcur[threadIdx.x], l_t[threadIdx.x]) : 0;
    __syncthreads();
    if (tid < E) {
        int pos = atomicAdd(&curs[d], 1);          // 50k addresses: cheap
        int rp = base_r[r] + rrank;
        rsrc[rp] = s; rdst[rp] = d; rdpos[rp] = pos;
    }
    if (tid < N) {
        nidx[base_t[t] + trank] = tid;
    }
}

// ---------------- node projections ----------------
// grid (SX, 3, T), one wave/block. a=0: k (split hi/lo bf16 out), a=1: q (fp32 out), a=2: v (bf16 out)
__global__ void proj_kernel(const float* __restrict__ h,
                            const float* __restrict__ Wk, const float* __restrict__ Wq,
                            const float* __restrict__ Wv,
                            const int* __restrict__ toff, const int* __restrict__ nidx,
                            unsigned short* __restrict__ khi, unsigned short* __restrict__ klo,
                            float* __restrict__ qout, unsigned short* __restrict__ vout) {
    const int t = blockIdx.z, a = blockIdx.y, lane = threadIdx.x;
    const int beg = toff[t], end = toff[t + 1], cnt = end - beg;
    if (cnt <= 0) return;
    const int nstrips = (cnt + 15) >> 4;
    const float* W = (a == 0 ? Wk : (a == 1 ? Wq : Wv)) + (size_t)t * 4096;
    const int m = lane & 15, quad = lane >> 4;

    bf16x8 Bh[2][4], Bl[2][4];
#pragma unroll
    for (int ks = 0; ks < 2; ++ks)
#pragma unroll
        for (int c = 0; c < 4; ++c) load_B_split(W, ks, c, lane, Bh[ks][c], Bl[ks][c]);

    for (int s = blockIdx.x; s < nstrips; s += gridDim.x) {
        int base = beg + s * 16;
        int rA = base + m; if (rA > end - 1) rA = end - 1;
        const float* hp = h + (size_t)nidx[rA] * D;
        bf16x8 A0h, A0l, A1h, A1l;
        load_A_split(hp + quad * 8, A0h, A0l);
        load_A_split(hp + 32 + quad * 8, A1h, A1l);
        f32x4 acc[4];
#pragma unroll
        for (int c = 0; c < 4; ++c) acc[c] = (f32x4){0.f, 0.f, 0.f, 0.f};
        SPLIT_MFMA_BODY(acc, A0h, A0l, A1h, A1l, Bh, Bl)
#pragma unroll
        for (int reg = 0; reg < 4; ++reg) {
            int rr = base + quad * 4 + reg;
            if (rr < end) {
                size_t nb = (size_t)nidx[rr] * D;
#pragma unroll
                for (int c = 0; c < 4; ++c) {
                    float val = acc[c][reg];
                    size_t idx = nb + c * 16 + m;
                    if (a == 0) {
                        unsigned short hh = f2bf(val);
                        khi[idx] = hh;
                        klo[idx] = f2bf(val - bf2f(hh));
                    } else if (a == 1) {
                        qout[idx] = val;
                    } else {
                        vout[idx] = f2bf(val);
                    }
                }
            }
        }
    }
}

// ---------------- V2[n][r] = v_node[n] @ M[r]  (bf16, tolerance path) ----------------
// grid (SX, R), one wave/block
__global__ void v2_kernel(const unsigned short* __restrict__ vn, const float* __restrict__ Amsg,
                          unsigned short* __restrict__ V2, int N) {
    const int r = blockIdx.y, lane = threadIdx.x;
    const int m = lane & 15, quad = lane >> 4;
    const int nstrips = (N + 15) >> 4;
    const float* W = Amsg + (size_t)r * 4096;
    bf16x8 B[2][4];
#pragma unroll
    for (int ks = 0; ks < 2; ++ks)
#pragma unroll
        for (int c = 0; c < 4; ++c) B[ks][c] = load_B_frag(W, ks, c, lane);

    for (int s = blockIdx.x; s < nstrips; s += gridDim.x) {
        int base = s * 16;
        int rA = base + m; if (rA > N - 1) rA = N - 1;
        bf16x8 A0 = *(const bf16x8*)(vn + (size_t)rA * D + quad * 8);
        bf16x8 A1 = *(const bf16x8*)(vn + (size_t)rA * D + 32 + quad * 8);
        f32x4 acc[4];
#pragma unroll
        for (int c = 0; c < 4; ++c) acc[c] = (f32x4){0.f, 0.f, 0.f, 0.f};
#pragma unroll
        for (int c = 0; c < 4; ++c) {
            acc[c] = MFMA16(A0, B[0][c], acc[c]);
            acc[c] = MFMA16(A1, B[1][c], acc[c]);
        }
#pragma unroll
        for (int reg = 0; reg < 4; ++reg) {
            int rr = base + quad * 4 + reg;
            if (rr < N) {
#pragma unroll
                for (int c = 0; c < 4; ++c)
                    V2[((size_t)rr * RR + r) * D + c * 16 + m] = f2bf(acc[c][reg]);
            }
        }
    }
}

// ---------------- per-edge scores (fp32-accurate) -> combined {score, einfo} record ----------------
// grid (SX, R), one wave/block; 16 edges per strip, relation-sorted
__global__ void score_kernel(const int* __restrict__ rsrc, const int* __restrict__ rdst,
                             const int* __restrict__ rdpos, const int* __restrict__ roff,
                             const unsigned short* __restrict__ khi, const unsigned short* __restrict__ klo,
                             const float* __restrict__ qn, const float* __restrict__ Aatt,
                             const float* __restrict__ pri, int2* __restrict__ rec) {
    const int r = blockIdx.y, lane = threadIdx.x;
    const int beg = roff[r], end = roff[r + 1], cnt = end - beg;
    if (cnt <= 0) return;
    const int nstrips = (cnt + 15) >> 4;
    const int m = lane & 15, quad = lane >> 4;
    const float scale = pri[r] * 0.125f;
    const float* W = Aatt + (size_t)r * 4096;

    bf16x8 Bh[2][4], Bl[2][4];
#pragma unroll
    for (int ks = 0; ks < 2; ++ks)
#pragma unroll
        for (int c = 0; c < 4; ++c) load_B_split(W, ks, c, lane, Bh[ks][c], Bl[ks][c]);

    for (int st = blockIdx.x; st < nstrips; st += gridDim.x) {
        int base = st * 16;
        int ia = base + m; if (ia > cnt - 1) ia = cnt - 1;
        int s = rsrc[beg + ia];
        const unsigned short* kh = khi + (size_t)s * D;
        const unsigned short* kl = klo + (size_t)s * D;
        bf16x8 A0h = *(const bf16x8*)(kh + quad * 8);
        bf16x8 A1h = *(const bf16x8*)(kh + 32 + quad * 8);
        bf16x8 A0l = *(const bf16x8*)(kl + quad * 8);
        bf16x8 A1l = *(const bf16x8*)(kl + 32 + quad * 8);
        f32x4 acc[4];
#pragma unroll
        for (int c = 0; c < 4; ++c) acc[c] = (f32x4){0.f, 0.f, 0.f, 0.f};
        SPLIT_MFMA_BODY(acc, A0h, A0l, A1h, A1l, Bh, Bl)

        // rows: edge idx = quad*4+reg ; cols: c*16+m spread over quad's 16 lanes
        float p4[4];
#pragma unroll
        for (int reg = 0; reg < 4; ++reg) {
            int ie = base + quad * 4 + reg; if (ie > cnt - 1) ie = cnt - 1;
            const float* qp = qn + (size_t)rdst[beg + ie] * D + m;
            float pr = acc[0][reg] * qp[0] + acc[1][reg] * qp[16]
                     + acc[2][reg] * qp[32] + acc[3][reg] * qp[48];
#pragma unroll
            for (int d = 8; d; d >>= 1) pr += __shfl_xor(pr, d, 64);
            p4[reg] = pr;
        }
        if (m < 4) {
            int idx = base + quad * 4 + m;
            if (idx < cnt) {
                float v = (m == 0) ? p4[0] : (m == 1) ? p4[1] : (m == 2) ? p4[2] : p4[3];
                int sagain = rsrc[beg + idx];                 // L1-hot reload
                int2 rc;
                rc.x = __float_as_int(v * scale);
                rc.y = (sagain << 3) | r;                     // V2 row id
                rec[rdpos[beg + idx]] = rc;                   // single 8B scattered store
            }
        }
    }
}

// ---------------- per-dst softmax + aggregation (chunked two-phase) ----------------
__global__ void agg_kernel(const int* __restrict__ offs, const int2* __restrict__ rec,
                           const unsigned short* __restrict__ V2,
                           float* __restrict__ agg, int N) {
    const int w = threadIdx.x >> 6, lane = threadIdx.x & 63;
    const int i = blockIdx.x * 4 + w;
    if (i >= N) return;
    const int beg = offs[i], end = offs[i + 1];
    float mmax = -INFINITY, lsum = 0.f, acc = 0.f;
    for (int cs = beg; cs < end; cs += 64) {
        int cl = end - cs; if (cl > 64) cl = 64;
        // phase 1: lanes = edges. sequential 8B record loads
        int2 rc; rc.y = 0;
        float sc = -INFINITY;
        if (lane < cl) { rc = rec[cs + lane]; sc = __int_as_float(rc.x); }
        float cm = sc;
#pragma unroll
        for (int d = 32; d; d >>= 1) cm = fmaxf(cm, __shfl_xor(cm, d, 64));
        float mn = fmaxf(mmax, cm);
        float cf = __expf(mmax - mn);              // 0 on first chunk
        float ex = (lane < cl) ? __expf(sc - mn) : 0.f;
        float csum = ex;
#pragma unroll
        for (int d = 32; d; d >>= 1) csum += __shfl_xor(csum, d, 64);
        lsum = lsum * cf + csum;
        acc *= cf;
        // phase 2: lanes = dims; weights/rows broadcast; 4-way independent gathers
        int e = 0;
        for (; e + 4 <= cl; e += 4) {
            float w0 = __shfl(ex, e, 64),     w1 = __shfl(ex, e + 1, 64);
            float w2 = __shfl(ex, e + 2, 64), w3 = __shfl(ex, e + 3, 64);
            int i0 = __shfl(rc.y, e, 64),     i1 = __shfl(rc.y, e + 1, 64);
            int i2 = __shfl(rc.y, e + 2, 64), i3 = __shfl(rc.y, e + 3, 64);
            float v0 = bf2f(V2[(size_t)i0 * D + lane]);
            float v1 = bf2f(V2[(size_t)i1 * D + lane]);
            float v2 = bf2f(V2[(size_t)i2 * D + lane]);
            float v3 = bf2f(V2[(size_t)i3 * D + lane]);
            acc += w0 * v0 + w1 * v1 + w2 * v2 + w3 * v3;
        }
        for (; e < cl; ++e) {
            float we = __shfl(ex, e, 64);
            int ie = __shfl(rc.y, e, 64);
            acc += we * bf2f(V2[(size_t)ie * D + lane]);
        }
        mmax = mn;
    }
    agg[(size_t)i * D + lane] = acc / (lsum + 1e-16f);
}

// ---------------- output transform (split-MFMA, in place on d_out) ----------------
// grid (SX, T), one wave/block
__global__ void out_kernel(float* __restrict__ io, const float* __restrict__ Wa,
                           const float* __restrict__ skip,
                           const int* __restrict__ toff, const int* __restrict__ nidx) {
    const int t = blockIdx.y, lane = threadIdx.x;
    const int beg = toff[t], end = toff[t + 1], cnt = end - beg;
    if (cnt <= 0) return;
    const int nstrips = (cnt + 15) >> 4;
    const float* W = Wa + (size_t)t * 4096;
    const float sg = 1.f / (1.f + __expf(-skip[t]));
    const int m = lane & 15, quad = lane >> 4;

    bf16x8 Bh[2][4], Bl[2][4];
#pragma unroll
    for (int ks = 0; ks < 2; ++ks)
#pragma unroll
        for (int c = 0; c < 4; ++c) load_B_split(W, ks, c, lane, Bh[ks][c], Bl[ks][c]);

    for (int s = blockIdx.x; s < nstrips; s += gridDim.x) {
        int base = beg + s * 16;
        int rA = base + m; if (rA > end - 1) rA = end - 1;
        const float* ap = io + (size_t)nidx[rA] * D;
        bf16x8 A0h, A0l, A1h, A1l;
        load_A_split(ap + quad * 8, A0h, A0l);
        load_A_split(ap + 32 + quad * 8, A1h, A1l);
        f32x4 acc[4];
#pragma unroll
        for (int c = 0; c < 4; ++c) acc[c] = (f32x4){0.f, 0.f, 0.f, 0.f};
        SPLIT_MFMA_BODY(acc, A0h, A0l, A1h, A1l, Bh, Bl)
#pragma unroll
        for (int reg = 0; reg < 4; ++reg) {
            int rr = base + quad * 4 + reg;
            if (rr < end) {
                size_t nb = (size_t)nidx[rr] * D;
#pragma unroll
                for (int c = 0; c < 4; ++c)
                    io[nb + c * 16 + m] = acc[c][reg] * sg;
            }
        }
    }
}

// ---------------- launch ----------------
extern "C" void kernel_launch(void* const* d_in, const int* in_sizes, int n_in,
                              void* d_out, int out_size, void* d_ws, size_t ws_size,
                              hipStream_t stream) {
    const float* h     = (const float*)d_in[0];
    const int*   adj   = (const int*)d_in[1];     // [2,E]: src row then dst row
    const int*   etype = (const int*)d_in[2];
    const int*   ntype = (const int*)d_in[3];
    const float* Wk    = (const float*)d_in[6];
    const float* Wq    = (const float*)d_in[7];
    const float* Wv    = (const float*)d_in[8];
    const float* Wa    = (const float*)d_in[9];
    const float* pri   = (const float*)d_in[10];
    const float* Aatt  = (const float*)d_in[11];
    const float* Amsg  = (const float*)d_in[12];
    const float* skp   = (const float*)d_in[13];
    const int N = in_sizes[3];
    const int E = in_sizes[2];
    float* out = (float*)d_out;

    char* w = (char*)d_ws;
    auto alloc = [&](size_t b) { char* p = w; w += (b + 255) & ~(size_t)255; return p; };
    unsigned short* khi = (unsigned short*)alloc((size_t)N * D * 2);
    unsigned short* klo = (unsigned short*)alloc((size_t)N * D * 2);
    float*          qn  = (float*)alloc((size_t)N * D * 4);
    unsigned short* vn  = (unsigned short*)alloc((size_t)N * D * 2);
    unsigned short* V2  = (unsigned short*)alloc((size_t)N * RR * D * 2);
    int* deg  = (int*)alloc((size_t)(N + 16) * 4);
    int* tcnt = deg + N;
    int* rcnt = deg + N + 8;
    int* offs = (int*)alloc((size_t)(N + 1) * 4);
    int* curs = (int*)alloc((size_t)N * 4);
    int* toff = (int*)alloc(64);
    int* tcur = (int*)alloc(64);
    int* roff = (int*)alloc(64);
    int* rcur = (int*)alloc(64);
    int2* rec = (int2*)alloc((size_t)E * 8);
    int* rsrc  = (int*)alloc((size_t)E * 4);
    int* rdst  = (int*)alloc((size_t)E * 4);
    int* rdpos = (int*)alloc((size_t)E * 4);
    int* nidx  = (int*)alloc((size_t)N * 4);
    const int nsb = (N + SCAN_ELEMS - 1) / SCAN_ELEMS;
    int* bsum  = (int*)alloc((size_t)nsb * 4);
    int* bbase = (int*)alloc((size_t)nsb * 4);

    (void)hipMemsetAsync(deg, 0, (size_t)(N + 16) * 4, stream);

    const int mx = (E > N ? E : N);
    hist_kernel<<<(mx + 255) / 256, 256, 0, stream>>>(adj + E, etype, ntype, deg, tcnt, rcnt, N, E);
    scan_sum_kernel<<<nsb, SCAN_TPB, 0, stream>>>(deg, bsum, N);
    scan_mid_kernel<<<1, 64, 0, stream>>>(bsum, bbase, nsb, tcnt, toff, tcur, rcnt, roff, rcur);
    scan_out_kernel<<<nsb, SCAN_TPB, 0, stream>>>(deg, bbase, offs, curs, N, E);
    scatter_kernel<<<(mx + 255) / 256, 256, 0, stream>>>(adj, adj + E, etype, ntype,
                                                         curs, tcur, rcur,
                                                         rsrc, rdst, rdpos, nidx, N, E);
    proj_kernel<<<dim3(128, 3, TT), 64, 0, stream>>>(h, Wk, Wq, Wv, toff, nidx, khi, klo, qn, vn);
    v2_kernel<<<dim3(256, RR), 64, 0, stream>>>(vn, Amsg, V2, N);
    score_kernel<<<dim3(256, RR), 64, 0, stream>>>(rsrc, rdst, rdpos, roff, khi, klo, qn, Aatt, pri, rec);
    agg_kernel<<<(N + 3) / 4, 256, 0, stream>>>(offs, rec, V2, out, N);
    out_kernel<<<dim3(128, TT), 64, 0, stream>>>(out, Wa, skp, toff, nidx);
}

// Round 7
// 350.831 us; speedup vs baseline: 18.7289x; 1.0775x over previous
//
#include <hip/hip_runtime.h>
#include <math.h>

typedef float f32x4 __attribute__((ext_vector_type(4)));
typedef short bf16x8 __attribute__((ext_vector_type(8)));

#define D 64
#define TT 8
#define RR 8

#define SCAN_TPB 256
#define SCAN_CH 4
#define SCAN_ELEMS (SCAN_TPB * SCAN_CH)   // 1024 elements per block

// ---------------- scalar helpers ----------------
__device__ __forceinline__ float bf2f(unsigned short u) {
    union { unsigned int i; float f; } x;
    x.i = ((unsigned int)u) << 16;
    return x.f;
}
__device__ __forceinline__ unsigned short f2bf(float f) {
    union { float f; unsigned int i; } x;
    x.f = f;
    unsigned int i = x.i;
    unsigned int r = (i + 0x7FFFu + ((i >> 16) & 1u)) >> 16;   // RNE
    return (unsigned short)r;
}
struct BfPair { short hi; short lo; };
// split fp32 into bf16 hi + bf16 lo (x ~= hi + lo, error ~2^-17 |x|)
__device__ __forceinline__ BfPair split2(float x) {
    BfPair p;
    unsigned short h = f2bf(x);
    p.hi = (short)h;
    p.lo = (short)f2bf(x - bf2f(h));
    return p;
}
__device__ __forceinline__ void load_A_split(const float* __restrict__ p, bf16x8& ah, bf16x8& al) {
#pragma unroll
    for (int i = 0; i < 8; ++i) {
        BfPair s = split2(p[i]);
        ah[i] = s.hi; al[i] = s.lo;
    }
}
// B fragment (B[k][n] = W[k][n], row-major 64x64 fp32), split into hi/lo
__device__ __forceinline__ void load_B_split(const float* __restrict__ W, int ks, int c, int lane,
                                             bf16x8& bh, bf16x8& bl) {
    int n = lane & 15, q = lane >> 4;
#pragma unroll
    for (int i = 0; i < 8; ++i) {
        BfPair s = split2(W[(ks * 32 + q * 8 + i) * 64 + c * 16 + n]);
        bh[i] = s.hi; bl[i] = s.lo;
    }
}
// plain bf16 B fragment
__device__ __forceinline__ bf16x8 load_B_frag(const float* __restrict__ W, int ks, int c, int lane) {
    int n = lane & 15, q = lane >> 4;
    bf16x8 r;
#pragma unroll
    for (int i = 0; i < 8; ++i)
        r[i] = (short)f2bf(W[(ks * 32 + q * 8 + i) * 64 + c * 16 + n]);
    return r;
}

#define MFMA16(a, b, c) __builtin_amdgcn_mfma_f32_16x16x32_bf16(a, b, c, 0, 0, 0)

// 24 MFMAs: acc[c] += (A0h+A0l)@(B0h+B0l) + (A1h+A1l)@(B1h+B1l), dropping lo*lo
#define SPLIT_MFMA_BODY(acc, A0h, A0l, A1h, A1l, Bh, Bl)          \
    _Pragma("unroll")                                             \
    for (int c = 0; c < 4; ++c) {                                 \
        acc[c] = MFMA16(A0h, Bh[0][c], acc[c]);                   \
        acc[c] = MFMA16(A0l, Bh[0][c], acc[c]);                   \
        acc[c] = MFMA16(A0h, Bl[0][c], acc[c]);                   \
        acc[c] = MFMA16(A1h, Bh[1][c], acc[c]);                   \
        acc[c] = MFMA16(A1l, Bh[1][c], acc[c]);                   \
        acc[c] = MFMA16(A1h, Bl[1][c], acc[c]);                   \
    }

// ---------------- CSR build ----------------
// hist: deg atomicAdd returns the per-dst rank -> stored in erank (makes scatter atomic-free
// for positions). tcnt/rcnt via LDS block histograms (8 hot addresses otherwise).
__global__ void hist_kernel(const int* __restrict__ dst, const int* __restrict__ et,
                            const int* __restrict__ nt,
                            int* __restrict__ deg, int* __restrict__ tcnt, int* __restrict__ rcnt,
                            int* __restrict__ erank, int N, int E) {
    __shared__ int l_r[RR], l_t[TT];
    if (threadIdx.x < RR) l_r[threadIdx.x] = 0;
    if (threadIdx.x < TT) l_t[threadIdx.x] = 0;
    __syncthreads();
    int tid = blockIdx.x * blockDim.x + threadIdx.x;
    if (tid < E) {
        erank[tid] = atomicAdd(&deg[dst[tid]], 1);
        atomicAdd(&l_r[et[tid]], 1);
    }
    if (tid < N) atomicAdd(&l_t[nt[tid]], 1);
    __syncthreads();
    if (threadIdx.x < RR && l_r[threadIdx.x]) atomicAdd(&rcnt[threadIdx.x], l_r[threadIdx.x]);
    if (threadIdx.x < TT && l_t[threadIdx.x]) atomicAdd(&tcnt[threadIdx.x], l_t[threadIdx.x]);
}

// ---- 3-phase device-wide exclusive scan of deg[0..N) ----
__global__ void scan_sum_kernel(const int* __restrict__ deg, int* __restrict__ bsum, int N) {
    __shared__ int ws[SCAN_TPB / 64];
    int tid = threadIdx.x;
    int base = blockIdx.x * SCAN_ELEMS + tid * SCAN_CH;
    int s = 0;
#pragma unroll
    for (int i = 0; i < SCAN_CH; ++i) {
        int idx = base + i;
        if (idx < N) s += deg[idx];
    }
#pragma unroll
    for (int d = 32; d; d >>= 1) s += __shfl_xor(s, d, 64);
    if ((tid & 63) == 0) ws[tid >> 6] = s;
    __syncthreads();
    if (tid == 0) {
        int t = 0;
#pragma unroll
        for (int i = 0; i < SCAN_TPB / 64; ++i) t += ws[i];
        bsum[blockIdx.x] = t;
    }
}
__global__ void scan_mid_kernel(const int* __restrict__ bsum, int* __restrict__ bbase, int nsb,
                                const int* __restrict__ tcnt, int* __restrict__ toff, int* __restrict__ tcur,
                                const int* __restrict__ rcnt, int* __restrict__ roff, int* __restrict__ rcur) {
    if (threadIdx.x == 0) {
        int run = 0;
        for (int b = 0; b < nsb; ++b) { bbase[b] = run; run += bsum[b]; }
        int a = 0;
        for (int t = 0; t < TT; ++t) { toff[t] = a; tcur[t] = a; a += tcnt[t]; }
        toff[TT] = a;
        int bb = 0;
        for (int r = 0; r < RR; ++r) { roff[r] = bb; rcur[r] = bb; bb += rcnt[r]; }
        roff[RR] = bb;
    }
}
__global__ void scan_out_kernel(const int* __restrict__ deg, const int* __restrict__ bbase,
                                int* __restrict__ off, int N, int Etot) {
    __shared__ int ts[SCAN_TPB];
    int tid = threadIdx.x;
    int base = blockIdx.x * SCAN_ELEMS + tid * SCAN_CH;
    int loc[SCAN_CH];
    int s = 0;
#pragma unroll
    for (int i = 0; i < SCAN_CH; ++i) {
        int idx = base + i;
        int v = (idx < N) ? deg[idx] : 0;
        loc[i] = v; s += v;
    }
    ts[tid] = s;
    __syncthreads();
    for (int sh = 1; sh < SCAN_TPB; sh <<= 1) {
        int v = (tid >= sh) ? ts[tid - sh] : 0;
        __syncthreads();
        ts[tid] += v;
        __syncthreads();
    }
    int run = bbase[blockIdx.x] + ((tid > 0) ? ts[tid - 1] : 0);
#pragma unroll
    for (int i = 0; i < SCAN_CH; ++i) {
        int idx = base + i;
        if (idx < N) { off[idx] = run; run += loc[i]; }
    }
    if (blockIdx.x == 0 && tid == 0) off[N] = Etot;
}

// scatter: pos = offs[d] + erank[e] (no per-edge atomics). Relation/type ranks via LDS.
__global__ void scatter_kernel(const int* __restrict__ src, const int* __restrict__ dst,
                               const int* __restrict__ et, const int* __restrict__ nt,
                               const int* __restrict__ offs, const int* __restrict__ erank,
                               int* __restrict__ tcur, int* __restrict__ rcur,
                               int* __restrict__ rsrc, int* __restrict__ rdst,
                               int* __restrict__ rdpos, int* __restrict__ nidx, int N, int E) {
    __shared__ int l_r[RR], l_t[TT], base_r[RR], base_t[TT];
    if (threadIdx.x < RR) l_r[threadIdx.x] = 0;
    if (threadIdx.x < TT) l_t[threadIdx.x] = 0;
    __syncthreads();
    int tid = blockIdx.x * blockDim.x + threadIdx.x;
    int s = 0, d = 0, r = 0, t = 0, rrank = 0, trank = 0;
    if (tid < E) {
        s = src[tid]; d = dst[tid]; r = et[tid];
        rrank = atomicAdd(&l_r[r], 1);            // rank within block
    }
    if (tid < N) {
        t = nt[tid];
        trank = atomicAdd(&l_t[t], 1);
    }
    __syncthreads();
    if (threadIdx.x < RR)
        base_r[threadIdx.x] = l_r[threadIdx.x] ? atomicAdd(&rcur[threadIdx.x], l_r[threadIdx.x]) : 0;
    if (threadIdx.x < TT)
        base_t[threadIdx.x] = l_t[threadIdx.x] ? atomicAdd(&tcur[threadIdx.x], l_t[threadIdx.x]) : 0;
    __syncthreads();
    if (tid < E) {
        int pos = offs[d] + erank[tid];
        int rp = base_r[r] + rrank;
        rsrc[rp] = s; rdst[rp] = d; rdpos[rp] = pos;
    }
    if (tid < N) {
        nidx[base_t[t] + trank] = tid;
    }
}

// ---------------- node projections ----------------
// grid (SX, 3, T), one wave/block. a=0: k -> kb interleaved row (hi[64] || lo[64], 256B),
// a=1: q (fp32 out), a=2: v (bf16 out)
__global__ void proj_kernel(const float* __restrict__ h,
                            const float* __restrict__ Wk, const float* __restrict__ Wq,
                            const float* __restrict__ Wv,
                            const int* __restrict__ toff, const int* __restrict__ nidx,
                            unsigned short* __restrict__ kb,
                            float* __restrict__ qout, unsigned short* __restrict__ vout) {
    const int t = blockIdx.z, a = blockIdx.y, lane = threadIdx.x;
    const int beg = toff[t], end = toff[t + 1], cnt = end - beg;
    if (cnt <= 0) return;
    const int nstrips = (cnt + 15) >> 4;
    const float* W = (a == 0 ? Wk : (a == 1 ? Wq : Wv)) + (size_t)t * 4096;
    const int m = lane & 15, quad = lane >> 4;

    bf16x8 Bh[2][4], Bl[2][4];
#pragma unroll
    for (int ks = 0; ks < 2; ++ks)
#pragma unroll
        for (int c = 0; c < 4; ++c) load_B_split(W, ks, c, lane, Bh[ks][c], Bl[ks][c]);

    for (int s = blockIdx.x; s < nstrips; s += gridDim.x) {
        int base = beg + s * 16;
        int rA = base + m; if (rA > end - 1) rA = end - 1;
        const float* hp = h + (size_t)nidx[rA] * D;
        bf16x8 A0h, A0l, A1h, A1l;
        load_A_split(hp + quad * 8, A0h, A0l);
        load_A_split(hp + 32 + quad * 8, A1h, A1l);
        f32x4 acc[4];
#pragma unroll
        for (int c = 0; c < 4; ++c) acc[c] = (f32x4){0.f, 0.f, 0.f, 0.f};
        SPLIT_MFMA_BODY(acc, A0h, A0l, A1h, A1l, Bh, Bl)
#pragma unroll
        for (int reg = 0; reg < 4; ++reg) {
            int rr = base + quad * 4 + reg;
            if (rr < end) {
                int nid = nidx[rr];
#pragma unroll
                for (int c = 0; c < 4; ++c) {
                    float val = acc[c][reg];
                    if (a == 0) {
                        unsigned short hh = f2bf(val);
                        kb[(size_t)nid * 128 + c * 16 + m] = hh;
                        kb[(size_t)nid * 128 + 64 + c * 16 + m] = f2bf(val - bf2f(hh));
                    } else if (a == 1) {
                        qout[(size_t)nid * D + c * 16 + m] = val;
                    } else {
                        vout[(size_t)nid * D + c * 16 + m] = f2bf(val);
                    }
                }
            }
        }
    }
}

// ---------------- V2[n][r] = v_node[n] @ M[r]  (bf16, tolerance path) ----------------
// grid (SX, R), one wave/block
__global__ void v2_kernel(const unsigned short* __restrict__ vn, const float* __restrict__ Amsg,
                          unsigned short* __restrict__ V2, int N) {
    const int r = blockIdx.y, lane = threadIdx.x;
    const int m = lane & 15, quad = lane >> 4;
    const int nstrips = (N + 15) >> 4;
    const float* W = Amsg + (size_t)r * 4096;
    bf16x8 B[2][4];
#pragma unroll
    for (int ks = 0; ks < 2; ++ks)
#pragma unroll
        for (int c = 0; c < 4; ++c) B[ks][c] = load_B_frag(W, ks, c, lane);

    for (int s = blockIdx.x; s < nstrips; s += gridDim.x) {
        int base = s * 16;
        int rA = base + m; if (rA > N - 1) rA = N - 1;
        bf16x8 A0 = *(const bf16x8*)(vn + (size_t)rA * D + quad * 8);
        bf16x8 A1 = *(const bf16x8*)(vn + (size_t)rA * D + 32 + quad * 8);
        f32x4 acc[4];
#pragma unroll
        for (int c = 0; c < 4; ++c) acc[c] = (f32x4){0.f, 0.f, 0.f, 0.f};
#pragma unroll
        for (int c = 0; c < 4; ++c) {
            acc[c] = MFMA16(A0, B[0][c], acc[c]);
            acc[c] = MFMA16(A1, B[1][c], acc[c]);
        }
#pragma unroll
        for (int reg = 0; reg < 4; ++reg) {
            int rr = base + quad * 4 + reg;
            if (rr < N) {
#pragma unroll
                for (int c = 0; c < 4; ++c)
                    V2[((size_t)rr * RR + r) * D + c * 16 + m] = f2bf(acc[c][reg]);
            }
        }
    }
}

// ---------------- per-edge scores (fp32-accurate) -> combined {score, einfo} record ----------------
// grid (SX, R), one wave/block; 16 edges per strip, relation-sorted
__global__ void score_kernel(const int* __restrict__ rsrc, const int* __restrict__ rdst,
                             const int* __restrict__ rdpos, const int* __restrict__ roff,
                             const unsigned short* __restrict__ kb,
                             const float* __restrict__ qn, const float* __restrict__ Aatt,
                             const float* __restrict__ pri, int2* __restrict__ rec) {
    const int r = blockIdx.y, lane = threadIdx.x;
    const int beg = roff[r], end = roff[r + 1], cnt = end - beg;
    if (cnt <= 0) return;
    const int nstrips = (cnt + 15) >> 4;
    const int m = lane & 15, quad = lane >> 4;
    const float scale = pri[r] * 0.125f;
    const float* W = Aatt + (size_t)r * 4096;

    bf16x8 Bh[2][4], Bl[2][4];
#pragma unroll
    for (int ks = 0; ks < 2; ++ks)
#pragma unroll
        for (int c = 0; c < 4; ++c) load_B_split(W, ks, c, lane, Bh[ks][c], Bl[ks][c]);

    for (int st = blockIdx.x; st < nstrips; st += gridDim.x) {
        int base = st * 16;
        int ia = base + m; if (ia > cnt - 1) ia = cnt - 1;
        int s = rsrc[beg + ia];
        const unsigned short* kr = kb + (size_t)s * 128;   // one 256B block: hi[64] || lo[64]
        bf16x8 A0h = *(const bf16x8*)(kr + quad * 8);
        bf16x8 A1h = *(const bf16x8*)(kr + 32 + quad * 8);
        bf16x8 A0l = *(const bf16x8*)(kr + 64 + quad * 8);
        bf16x8 A1l = *(const bf16x8*)(kr + 96 + quad * 8);
        f32x4 acc[4];
#pragma unroll
        for (int c = 0; c < 4; ++c) acc[c] = (f32x4){0.f, 0.f, 0.f, 0.f};
        SPLIT_MFMA_BODY(acc, A0h, A0l, A1h, A1l, Bh, Bl)

        // rows: edge idx = quad*4+reg ; cols: c*16+m spread over quad's 16 lanes
        float p4[4];
#pragma unroll
        for (int reg = 0; reg < 4; ++reg) {
            int ie = base + quad * 4 + reg; if (ie > cnt - 1) ie = cnt - 1;
            const float* qp = qn + (size_t)rdst[beg + ie] * D + m;
            float pr = acc[0][reg] * qp[0] + acc[1][reg] * qp[16]
                     + acc[2][reg] * qp[32] + acc[3][reg] * qp[48];
#pragma unroll
            for (int d = 8; d; d >>= 1) pr += __shfl_xor(pr, d, 64);
            p4[reg] = pr;
        }
        if (m < 4) {
            int idx = base + quad * 4 + m;
            if (idx < cnt) {
                float v = (m == 0) ? p4[0] : (m == 1) ? p4[1] : (m == 2) ? p4[2] : p4[3];
                int sagain = rsrc[beg + idx];                 // L1-hot reload
                int2 rc;
                rc.x = __float_as_int(v * scale);
                rc.y = (sagain << 3) | r;                     // V2 row id
                rec[rdpos[beg + idx]] = rc;                   // single 8B scattered store
            }
        }
    }
}

// ---------------- per-dst softmax + aggregation (chunked two-phase) ----------------
__global__ void agg_kernel(const int* __restrict__ offs, const int2* __restrict__ rec,
                           const unsigned short* __restrict__ V2,
                           float* __restrict__ agg, int N) {
    const int w = threadIdx.x >> 6, lane = threadIdx.x & 63;
    const int i = blockIdx.x * 4 + w;
    if (i >= N) return;
    const int beg = offs[i], end = offs[i + 1];
    float mmax = -INFINITY, lsum = 0.f, acc = 0.f;
    for (int cs = beg; cs < end; cs += 64) {
        int cl = end - cs; if (cl > 64) cl = 64;
        // phase 1: lanes = edges. sequential 8B record loads
        int2 rc; rc.y = 0;
        float sc = -INFINITY;
        if (lane < cl) { rc = rec[cs + lane]; sc = __int_as_float(rc.x); }
        float cm = sc;
#pragma unroll
        for (int d = 32; d; d >>= 1) cm = fmaxf(cm, __shfl_xor(cm, d, 64));
        float mn = fmaxf(mmax, cm);
        float cf = __expf(mmax - mn);              // 0 on first chunk
        float ex = (lane < cl) ? __expf(sc - mn) : 0.f;
        float csum = ex;
#pragma unroll
        for (int d = 32; d; d >>= 1) csum += __shfl_xor(csum, d, 64);
        lsum = lsum * cf + csum;
        acc *= cf;
        // phase 2: lanes = dims; weights/rows broadcast; 4-way independent gathers
        int e = 0;
        for (; e + 4 <= cl; e += 4) {
            float w0 = __shfl(ex, e, 64),     w1 = __shfl(ex, e + 1, 64);
            float w2 = __shfl(ex, e + 2, 64), w3 = __shfl(ex, e + 3, 64);
            int i0 = __shfl(rc.y, e, 64),     i1 = __shfl(rc.y, e + 1, 64);
            int i2 = __shfl(rc.y, e + 2, 64), i3 = __shfl(rc.y, e + 3, 64);
            float v0 = bf2f(V2[(size_t)i0 * D + lane]);
            float v1 = bf2f(V2[(size_t)i1 * D + lane]);
            float v2 = bf2f(V2[(size_t)i2 * D + lane]);
            float v3 = bf2f(V2[(size_t)i3 * D + lane]);
            acc += w0 * v0 + w1 * v1 + w2 * v2 + w3 * v3;
        }
        for (; e < cl; ++e) {
            float we = __shfl(ex, e, 64);
            int ie = __shfl(rc.y, e, 64);
            acc += we * bf2f(V2[(size_t)ie * D + lane]);
        }
        mmax = mn;
    }
    agg[(size_t)i * D + lane] = acc / (lsum + 1e-16f);
}

// ---------------- output transform (split-MFMA, in place on d_out) ----------------
// grid (SX, T), one wave/block
__global__ void out_kernel(float* __restrict__ io, const float* __restrict__ Wa,
                           const float* __restrict__ skip,
                           const int* __restrict__ toff, const int* __restrict__ nidx) {
    const int t = blockIdx.y, lane = threadIdx.x;
    const int beg = toff[t], end = toff[t + 1], cnt = end - beg;
    if (cnt <= 0) return;
    const int nstrips = (cnt + 15) >> 4;
    const float* W = Wa + (size_t)t * 4096;
    const float sg = 1.f / (1.f + __expf(-skip[t]));
    const int m = lane & 15, quad = lane >> 4;

    bf16x8 Bh[2][4], Bl[2][4];
#pragma unroll
    for (int ks = 0; ks < 2; ++ks)
#pragma unroll
        for (int c = 0; c < 4; ++c) load_B_split(W, ks, c, lane, Bh[ks][c], Bl[ks][c]);

    for (int s = blockIdx.x; s < nstrips; s += gridDim.x) {
        int base = beg + s * 16;
        int rA = base + m; if (rA > end - 1) rA = end - 1;
        const float* ap = io + (size_t)nidx[rA] * D;
        bf16x8 A0h, A0l, A1h, A1l;
        load_A_split(ap + quad * 8, A0h, A0l);
        load_A_split(ap + 32 + quad * 8, A1h, A1l);
        f32x4 acc[4];
#pragma unroll
        for (int c = 0; c < 4; ++c) acc[c] = (f32x4){0.f, 0.f, 0.f, 0.f};
        SPLIT_MFMA_BODY(acc, A0h, A0l, A1h, A1l, Bh, Bl)
#pragma unroll
        for (int reg = 0; reg < 4; ++reg) {
            int rr = base + quad * 4 + reg;
            if (rr < end) {
                size_t nb = (size_t)nidx[rr] * D;
#pragma unroll
                for (int c = 0; c < 4; ++c)
                    io[nb + c * 16 + m] = acc[c][reg] * sg;
            }
        }
    }
}

// ---------------- launch ----------------
extern "C" void kernel_launch(void* const* d_in, const int* in_sizes, int n_in,
                              void* d_out, int out_size, void* d_ws, size_t ws_size,
                              hipStream_t stream) {
    const float* h     = (const float*)d_in[0];
    const int*   adj   = (const int*)d_in[1];     // [2,E]: src row then dst row
    const int*   etype = (const int*)d_in[2];
    const int*   ntype = (const int*)d_in[3];
    const float* Wk    = (const float*)d_in[6];
    const float* Wq    = (const float*)d_in[7];
    const float* Wv    = (const float*)d_in[8];
    const float* Wa    = (const float*)d_in[9];
    const float* pri   = (const float*)d_in[10];
    const float* Aatt  = (const float*)d_in[11];
    const float* Amsg  = (const float*)d_in[12];
    const float* skp   = (const float*)d_in[13];
    const int N = in_sizes[3];
    const int E = in_sizes[2];
    float* out = (float*)d_out;

    char* w = (char*)d_ws;
    auto alloc = [&](size_t b) { char* p = w; w += (b + 255) & ~(size_t)255; return p; };
    unsigned short* kb  = (unsigned short*)alloc((size_t)N * 128 * 2);  // hi||lo interleaved
    float*          qn  = (float*)alloc((size_t)N * D * 4);
    unsigned short* vn  = (unsigned short*)alloc((size_t)N * D * 2);
    unsigned short* V2  = (unsigned short*)alloc((size_t)N * RR * D * 2);
    int* deg  = (int*)alloc((size_t)(N + 16) * 4);
    int* tcnt = deg + N;
    int* rcnt = deg + N + 8;
    int* offs = (int*)alloc((size_t)(N + 1) * 4);
    int* erank = (int*)alloc((size_t)E * 4);
    int* toff = (int*)alloc(64);
    int* tcur = (int*)alloc(64);
    int* roff = (int*)alloc(64);
    int* rcur = (int*)alloc(64);
    int2* rec = (int2*)alloc((size_t)E * 8);
    int* rsrc  = (int*)alloc((size_t)E * 4);
    int* rdst  = (int*)alloc((size_t)E * 4);
    int* rdpos = (int*)alloc((size_t)E * 4);
    int* nidx  = (int*)alloc((size_t)N * 4);
    const int nsb = (N + SCAN_ELEMS - 1) / SCAN_ELEMS;
    int* bsum  = (int*)alloc((size_t)nsb * 4);
    int* bbase = (int*)alloc((size_t)nsb * 4);

    (void)hipMemsetAsync(deg, 0, (size_t)(N + 16) * 4, stream);

    const int mx = (E > N ? E : N);
    hist_kernel<<<(mx + 255) / 256, 256, 0, stream>>>(adj + E, etype, ntype, deg, tcnt, rcnt, erank, N, E);
    scan_sum_kernel<<<nsb, SCAN_TPB, 0, stream>>>(deg, bsum, N);
    scan_mid_kernel<<<1, 64, 0, stream>>>(bsum, bbase, nsb, tcnt, toff, tcur, rcnt, roff, rcur);
    scan_out_kernel<<<nsb, SCAN_TPB, 0, stream>>>(deg, bbase, offs, N, E);
    scatter_kernel<<<(mx + 255) / 256, 256, 0, stream>>>(adj, adj + E, etype, ntype,
                                                         offs, erank, tcur, rcur,
                                                         rsrc, rdst, rdpos, nidx, N, E);
    proj_kernel<<<dim3(128, 3, TT), 64, 0, stream>>>(h, Wk, Wq, Wv, toff, nidx, kb, qn, vn);
    v2_kernel<<<dim3(256, RR), 64, 0, stream>>>(vn, Amsg, V2, N);
    score_kernel<<<dim3(512, RR), 64, 0, stream>>>(rsrc, rdst, rdpos, roff, kb, qn, Aatt, pri, rec);
    agg_kernel<<<(N + 3) / 4, 256, 0, stream>>>(offs, rec, V2, out, N);
    out_kernel<<<dim3(128, TT), 64, 0, stream>>>(out, Wa, skp, toff, nidx);
}

// Round 8
// 323.966 us; speedup vs baseline: 20.2820x; 1.0829x over previous
//
#include <hip/hip_runtime.h>
#include <math.h>

typedef float f32x4 __attribute__((ext_vector_type(4)));
typedef short bf16x8 __attribute__((ext_vector_type(8)));
typedef _Float16 f16x8 __attribute__((ext_vector_type(8)));
typedef _Float16 f16x4 __attribute__((ext_vector_type(4)));

#define D 64
#define TT 8
#define RR 8

#define SCAN_TPB 256
#define SCAN_CH 4
#define SCAN_ELEMS (SCAN_TPB * SCAN_CH)   // 1024 elements per block

// ---------------- scalar helpers ----------------
__device__ __forceinline__ float bf2f(unsigned short u) {
    union { unsigned int i; float f; } x;
    x.i = ((unsigned int)u) << 16;
    return x.f;
}
__device__ __forceinline__ unsigned short f2bf(float f) {
    union { float f; unsigned int i; } x;
    x.f = f;
    unsigned int i = x.i;
    unsigned int r = (i + 0x7FFFu + ((i >> 16) & 1u)) >> 16;   // RNE
    return (unsigned short)r;
}
struct BfPair { short hi; short lo; };
__device__ __forceinline__ BfPair split2(float x) {
    BfPair p;
    unsigned short h = f2bf(x);
    p.hi = (short)h;
    p.lo = (short)f2bf(x - bf2f(h));
    return p;
}
__device__ __forceinline__ void load_A_split(const float* __restrict__ p, bf16x8& ah, bf16x8& al) {
#pragma unroll
    for (int i = 0; i < 8; ++i) {
        BfPair s = split2(p[i]);
        ah[i] = s.hi; al[i] = s.lo;
    }
}
// bf16 split B fragment (used by proj/out split GEMMs)
__device__ __forceinline__ void load_B_split(const float* __restrict__ W, int ks, int c, int lane,
                                             bf16x8& bh, bf16x8& bl) {
    int n = lane & 15, q = lane >> 4;
#pragma unroll
    for (int i = 0; i < 8; ++i) {
        BfPair s = split2(W[(ks * 32 + q * 8 + i) * 64 + c * 16 + n]);
        bh[i] = s.hi; bl[i] = s.lo;
    }
}
// fp16 split B fragment (score: A-matrix hi+lo)
__device__ __forceinline__ void load_B_split_f16(const float* __restrict__ W, int ks, int c, int lane,
                                                 f16x8& bh, f16x8& bl) {
    int n = lane & 15, q = lane >> 4;
#pragma unroll
    for (int i = 0; i < 8; ++i) {
        float w = W[(ks * 32 + q * 8 + i) * 64 + c * 16 + n];
        _Float16 h = (_Float16)w;
        bh[i] = h;
        bl[i] = (_Float16)(w - (float)h);
    }
}
// fp16 single B fragment (V2 build)
__device__ __forceinline__ f16x8 load_B_frag_f16(const float* __restrict__ W, int ks, int c, int lane) {
    int n = lane & 15, q = lane >> 4;
    f16x8 r;
#pragma unroll
    for (int i = 0; i < 8; ++i)
        r[i] = (_Float16)W[(ks * 32 + q * 8 + i) * 64 + c * 16 + n];
    return r;
}

#define MFMA16(a, b, c) __builtin_amdgcn_mfma_f32_16x16x32_bf16(a, b, c, 0, 0, 0)
#define MFMAH(a, b, c)  __builtin_amdgcn_mfma_f32_16x16x32_f16(a, b, c, 0, 0, 0)

// 24 bf16 MFMAs: acc += (Ah+Al)@(Bh+Bl) dropping lo*lo
#define SPLIT_MFMA_BODY(acc, A0h, A0l, A1h, A1l, Bh, Bl)          \
    _Pragma("unroll")                                             \
    for (int c = 0; c < 4; ++c) {                                 \
        acc[c] = MFMA16(A0h, Bh[0][c], acc[c]);                   \
        acc[c] = MFMA16(A0l, Bh[0][c], acc[c]);                   \
        acc[c] = MFMA16(A0h, Bl[0][c], acc[c]);                   \
        acc[c] = MFMA16(A1h, Bh[1][c], acc[c]);                   \
        acc[c] = MFMA16(A1l, Bh[1][c], acc[c]);                   \
        acc[c] = MFMA16(A1h, Bl[1][c], acc[c]);                   \
    }

// ---------------- CSR build ----------------
__global__ void hist_kernel(const int* __restrict__ dst, const int* __restrict__ et,
                            const int* __restrict__ nt,
                            int* __restrict__ deg, int* __restrict__ tcnt, int* __restrict__ rcnt,
                            int* __restrict__ erank, int N, int E) {
    __shared__ int l_r[RR], l_t[TT];
    if (threadIdx.x < RR) l_r[threadIdx.x] = 0;
    if (threadIdx.x < TT) l_t[threadIdx.x] = 0;
    __syncthreads();
    int tid = blockIdx.x * blockDim.x + threadIdx.x;
    if (tid < E) {
        erank[tid] = atomicAdd(&deg[dst[tid]], 1);
        atomicAdd(&l_r[et[tid]], 1);
    }
    if (tid < N) atomicAdd(&l_t[nt[tid]], 1);
    __syncthreads();
    if (threadIdx.x < RR && l_r[threadIdx.x]) atomicAdd(&rcnt[threadIdx.x], l_r[threadIdx.x]);
    if (threadIdx.x < TT && l_t[threadIdx.x]) atomicAdd(&tcnt[threadIdx.x], l_t[threadIdx.x]);
}

__global__ void scan_sum_kernel(const int* __restrict__ deg, int* __restrict__ bsum, int N) {
    __shared__ int ws[SCAN_TPB / 64];
    int tid = threadIdx.x;
    int base = blockIdx.x * SCAN_ELEMS + tid * SCAN_CH;
    int s = 0;
#pragma unroll
    for (int i = 0; i < SCAN_CH; ++i) {
        int idx = base + i;
        if (idx < N) s += deg[idx];
    }
#pragma unroll
    for (int d = 32; d; d >>= 1) s += __shfl_xor(s, d, 64);
    if ((tid & 63) == 0) ws[tid >> 6] = s;
    __syncthreads();
    if (tid == 0) {
        int t = 0;
#pragma unroll
        for (int i = 0; i < SCAN_TPB / 64; ++i) t += ws[i];
        bsum[blockIdx.x] = t;
    }
}
__global__ void scan_mid_kernel(const int* __restrict__ bsum, int* __restrict__ bbase, int nsb,
                                const int* __restrict__ tcnt, int* __restrict__ toff, int* __restrict__ tcur,
                                const int* __restrict__ rcnt, int* __restrict__ roff, int* __restrict__ rcur) {
    if (threadIdx.x == 0) {
        int run = 0;
        for (int b = 0; b < nsb; ++b) { bbase[b] = run; run += bsum[b]; }
        int a = 0;
        for (int t = 0; t < TT; ++t) { toff[t] = a; tcur[t] = a; a += tcnt[t]; }
        toff[TT] = a;
        int bb = 0;
        for (int r = 0; r < RR; ++r) { roff[r] = bb; rcur[r] = bb; bb += rcnt[r]; }
        roff[RR] = bb;
    }
}
__global__ void scan_out_kernel(const int* __restrict__ deg, const int* __restrict__ bbase,
                                int* __restrict__ off, int N, int Etot) {
    __shared__ int ts[SCAN_TPB];
    int tid = threadIdx.x;
    int base = blockIdx.x * SCAN_ELEMS + tid * SCAN_CH;
    int loc[SCAN_CH];
    int s = 0;
#pragma unroll
    for (int i = 0; i < SCAN_CH; ++i) {
        int idx = base + i;
        int v = (idx < N) ? deg[idx] : 0;
        loc[i] = v; s += v;
    }
    ts[tid] = s;
    __syncthreads();
    for (int sh = 1; sh < SCAN_TPB; sh <<= 1) {
        int v = (tid >= sh) ? ts[tid - sh] : 0;
        __syncthreads();
        ts[tid] += v;
        __syncthreads();
    }
    int run = bbase[blockIdx.x] + ((tid > 0) ? ts[tid - 1] : 0);
#pragma unroll
    for (int i = 0; i < SCAN_CH; ++i) {
        int idx = base + i;
        if (idx < N) { off[idx] = run; run += loc[i]; }
    }
    if (blockIdx.x == 0 && tid == 0) off[N] = Etot;
}

__global__ void scatter_kernel(const int* __restrict__ src, const int* __restrict__ dst,
                               const int* __restrict__ et, const int* __restrict__ nt,
                               const int* __restrict__ offs, const int* __restrict__ erank,
                               int* __restrict__ tcur, int* __restrict__ rcur,
                               int* __restrict__ rsrc, int* __restrict__ rdst,
                               int* __restrict__ rdpos, int* __restrict__ nidx, int N, int E) {
    __shared__ int l_r[RR], l_t[TT], base_r[RR], base_t[TT];
    if (threadIdx.x < RR) l_r[threadIdx.x] = 0;
    if (threadIdx.x < TT) l_t[threadIdx.x] = 0;
    __syncthreads();
    int tid = blockIdx.x * blockDim.x + threadIdx.x;
    int s = 0, d = 0, r = 0, t = 0, rrank = 0, trank = 0;
    if (tid < E) {
        s = src[tid]; d = dst[tid]; r = et[tid];
        rrank = atomicAdd(&l_r[r], 1);
    }
    if (tid < N) {
        t = nt[tid];
        trank = atomicAdd(&l_t[t], 1);
    }
    __syncthreads();
    if (threadIdx.x < RR)
        base_r[threadIdx.x] = l_r[threadIdx.x] ? atomicAdd(&rcur[threadIdx.x], l_r[threadIdx.x]) : 0;
    if (threadIdx.x < TT)
        base_t[threadIdx.x] = l_t[threadIdx.x] ? atomicAdd(&tcur[threadIdx.x], l_t[threadIdx.x]) : 0;
    __syncthreads();
    if (tid < E) {
        int pos = offs[d] + erank[tid];
        int rp = base_r[r] + rrank;
        rsrc[rp] = s; rdst[rp] = d; rdpos[rp] = pos;
    }
    if (tid < N) {
        nidx[base_t[t] + trank] = tid;
    }
}

// ---------------- node projections ----------------
// a=0: k -> fp16 row (128B); a=1: q fp32; a=2: v fp16. GEMMs internally split-bf16 accurate.
__global__ void proj_kernel(const float* __restrict__ h,
                            const float* __restrict__ Wk, const float* __restrict__ Wq,
                            const float* __restrict__ Wv,
                            const int* __restrict__ toff, const int* __restrict__ nidx,
                            _Float16* __restrict__ kh16,
                            float* __restrict__ qout, _Float16* __restrict__ vout) {
    const int t = blockIdx.z, a = blockIdx.y, lane = threadIdx.x;
    const int beg = toff[t], end = toff[t + 1], cnt = end - beg;
    if (cnt <= 0) return;
    const int nstrips = (cnt + 15) >> 4;
    const float* W = (a == 0 ? Wk : (a == 1 ? Wq : Wv)) + (size_t)t * 4096;
    const int m = lane & 15, quad = lane >> 4;

    bf16x8 Bh[2][4], Bl[2][4];
#pragma unroll
    for (int ks = 0; ks < 2; ++ks)
#pragma unroll
        for (int c = 0; c < 4; ++c) load_B_split(W, ks, c, lane, Bh[ks][c], Bl[ks][c]);

    for (int s = blockIdx.x; s < nstrips; s += gridDim.x) {
        int base = beg + s * 16;
        int rA = base + m; if (rA > end - 1) rA = end - 1;
        const float* hp = h + (size_t)nidx[rA] * D;
        bf16x8 A0h, A0l, A1h, A1l;
        load_A_split(hp + quad * 8, A0h, A0l);
        load_A_split(hp + 32 + quad * 8, A1h, A1l);
        f32x4 acc[4];
#pragma unroll
        for (int c = 0; c < 4; ++c) acc[c] = (f32x4){0.f, 0.f, 0.f, 0.f};
        SPLIT_MFMA_BODY(acc, A0h, A0l, A1h, A1l, Bh, Bl)
#pragma unroll
        for (int reg = 0; reg < 4; ++reg) {
            int rr = base + quad * 4 + reg;
            if (rr < end) {
                int nid = nidx[rr];
#pragma unroll
                for (int c = 0; c < 4; ++c) {
                    float val = acc[c][reg];
                    if (a == 0) {
                        kh16[(size_t)nid * D + c * 16 + m] = (_Float16)val;
                    } else if (a == 1) {
                        qout[(size_t)nid * D + c * 16 + m] = val;
                    } else {
                        vout[(size_t)nid * D + c * 16 + m] = (_Float16)val;
                    }
                }
            }
        }
    }
}

// ---------------- V2[n][r] = v_node[n] @ M[r]  (fp16) ----------------
__global__ void v2_kernel(const _Float16* __restrict__ vn, const float* __restrict__ Amsg,
                          _Float16* __restrict__ V2, int N) {
    const int r = blockIdx.y, lane = threadIdx.x;
    const int m = lane & 15, quad = lane >> 4;
    const int nstrips = (N + 15) >> 4;
    const float* W = Amsg + (size_t)r * 4096;
    f16x8 B[2][4];
#pragma unroll
    for (int ks = 0; ks < 2; ++ks)
#pragma unroll
        for (int c = 0; c < 4; ++c) B[ks][c] = load_B_frag_f16(W, ks, c, lane);

    for (int s = blockIdx.x; s < nstrips; s += gridDim.x) {
        int base = s * 16;
        int rA = base + m; if (rA > N - 1) rA = N - 1;
        f16x8 A0 = *(const f16x8*)(vn + (size_t)rA * D + quad * 8);
        f16x8 A1 = *(const f16x8*)(vn + (size_t)rA * D + 32 + quad * 8);
        f32x4 acc[4];
#pragma unroll
        for (int c = 0; c < 4; ++c) acc[c] = (f32x4){0.f, 0.f, 0.f, 0.f};
#pragma unroll
        for (int c = 0; c < 4; ++c) {
            acc[c] = MFMAH(A0, B[0][c], acc[c]);
            acc[c] = MFMAH(A1, B[1][c], acc[c]);
        }
#pragma unroll
        for (int reg = 0; reg < 4; ++reg) {
            int rr = base + quad * 4 + reg;
            if (rr < N) {
#pragma unroll
                for (int c = 0; c < 4; ++c)
                    V2[((size_t)rr * RR + r) * D + c * 16 + m] = (_Float16)acc[c][reg];
            }
        }
    }
}

// ---------------- per-edge scores: k fp16 (128B gather), A split-fp16, q fp32 ----------------
__global__ void score_kernel(const int* __restrict__ rsrc, const int* __restrict__ rdst,
                             const int* __restrict__ rdpos, const int* __restrict__ roff,
                             const _Float16* __restrict__ kh16,
                             const float* __restrict__ qn, const float* __restrict__ Aatt,
                             const float* __restrict__ pri, int2* __restrict__ rec) {
    const int r = blockIdx.y, lane = threadIdx.x;
    const int beg = roff[r], end = roff[r + 1], cnt = end - beg;
    if (cnt <= 0) return;
    const int nstrips = (cnt + 15) >> 4;
    const int m = lane & 15, quad = lane >> 4;
    const float scale = pri[r] * 0.125f;
    const float* W = Aatt + (size_t)r * 4096;

    f16x8 Bh[2][4], Bl[2][4];
#pragma unroll
    for (int ks = 0; ks < 2; ++ks)
#pragma unroll
        for (int c = 0; c < 4; ++c) load_B_split_f16(W, ks, c, lane, Bh[ks][c], Bl[ks][c]);

    for (int st = blockIdx.x; st < nstrips; st += gridDim.x) {
        int base = st * 16;
        int ia = base + m; if (ia > cnt - 1) ia = cnt - 1;
        int s = rsrc[beg + ia];
        const _Float16* kr = kh16 + (size_t)s * D;   // 128B row
        f16x8 A0 = *(const f16x8*)(kr + quad * 8);
        f16x8 A1 = *(const f16x8*)(kr + 32 + quad * 8);
        f32x4 acc[4];
#pragma unroll
        for (int c = 0; c < 4; ++c) acc[c] = (f32x4){0.f, 0.f, 0.f, 0.f};
#pragma unroll
        for (int c = 0; c < 4; ++c) {
            acc[c] = MFMAH(A0, Bh[0][c], acc[c]);
            acc[c] = MFMAH(A0, Bl[0][c], acc[c]);
            acc[c] = MFMAH(A1, Bh[1][c], acc[c]);
            acc[c] = MFMAH(A1, Bl[1][c], acc[c]);
        }

        float p4[4];
#pragma unroll
        for (int reg = 0; reg < 4; ++reg) {
            int ie = base + quad * 4 + reg; if (ie > cnt - 1) ie = cnt - 1;
            const float* qp = qn + (size_t)rdst[beg + ie] * D + m;
            float pr = acc[0][reg] * qp[0] + acc[1][reg] * qp[16]
                     + acc[2][reg] * qp[32] + acc[3][reg] * qp[48];
#pragma unroll
            for (int d = 8; d; d >>= 1) pr += __shfl_xor(pr, d, 64);
            p4[reg] = pr;
        }
        if (m < 4) {
            int idx = base + quad * 4 + m;
            if (idx < cnt) {
                float v = (m == 0) ? p4[0] : (m == 1) ? p4[1] : (m == 2) ? p4[2] : p4[3];
                int sagain = rsrc[beg + idx];
                int2 rc;
                rc.x = __float_as_int(v * scale);
                rc.y = (sagain << 3) | r;                     // V2 row id
                rec[rdpos[beg + idx]] = rc;
            }
        }
    }
}

// ---------------- per-dst softmax + aggregation: one 16-lane quad per node ----------------
__global__ void agg_kernel(const int* __restrict__ offs, const int2* __restrict__ rec,
                           const _Float16* __restrict__ V2,
                           float* __restrict__ agg, int N) {
    const int lane = threadIdx.x & 63;
    const int wv = threadIdx.x >> 6;         // 4 waves/block
    const int quad = lane >> 4, ql = lane & 15;
    const int i = blockIdx.x * 16 + wv * 4 + quad;
    if (i >= N) return;
    const int beg = offs[i], end = offs[i + 1];
    const int qb = quad << 4;
    float mmax = -INFINITY, lsum = 0.f;
    float a0 = 0.f, a1 = 0.f, a2 = 0.f, a3 = 0.f;
    for (int cs = beg; cs < end; cs += 16) {
        int cl = end - cs; if (cl > 16) cl = 16;
        // phase 1: 16 lanes = 16 edges
        int2 rc; rc.y = 0;
        float sc = -INFINITY;
        if (ql < cl) { rc = rec[cs + ql]; sc = __int_as_float(rc.x); }
        float cm = sc;
#pragma unroll
        for (int d = 8; d; d >>= 1) cm = fmaxf(cm, __shfl_xor(cm, d, 64));
        float mn = fmaxf(mmax, cm);
        float cf = __expf(mmax - mn);             // 0 on first chunk
        float ex = (ql < cl) ? __expf(sc - mn) : 0.f;
        float csum = ex;
#pragma unroll
        for (int d = 8; d; d >>= 1) csum += __shfl_xor(csum, d, 64);
        lsum = lsum * cf + csum;
        a0 *= cf; a1 *= cf; a2 *= cf; a3 *= cf;
        // phase 2: 16 lanes = 64 dims (4 each); weights/rows broadcast from quad lanes
        for (int e = 0; e < cl; e += 2) {
            float w0 = __shfl(ex, qb + e, 64);
            int   i0 = __shfl(rc.y, qb + e, 64);
            float w1 = __shfl(ex, qb + e + 1, 64);   // 0-weight row if e+1>=cl (lanes init 0)
            int   i1 = __shfl(rc.y, qb + e + 1, 64);
            f16x4 v0 = *(const f16x4*)(V2 + (size_t)i0 * D + ql * 4);
            f16x4 v1 = *(const f16x4*)(V2 + (size_t)i1 * D + ql * 4);
            a0 += w0 * (float)v0[0] + w1 * (float)v1[0];
            a1 += w0 * (float)v0[1] + w1 * (float)v1[1];
            a2 += w0 * (float)v0[2] + w1 * (float)v1[2];
            a3 += w0 * (float)v0[3] + w1 * (float)v1[3];
        }
        mmax = mn;
    }
    float inv = 1.f / (lsum + 1e-16f);
    f32x4 outv = (f32x4){a0 * inv, a1 * inv, a2 * inv, a3 * inv};
    *(f32x4*)(agg + (size_t)i * D + ql * 4) = outv;
}

// ---------------- output transform (split-bf16 MFMA, in place on d_out) ----------------
__global__ void out_kernel(float* __restrict__ io, const float* __restrict__ Wa,
                           const float* __restrict__ skip,
                           const int* __restrict__ toff, const int* __restrict__ nidx) {
    const int t = blockIdx.y, lane = threadIdx.x;
    const int beg = toff[t], end = toff[t + 1], cnt = end - beg;
    if (cnt <= 0) return;
    const int nstrips = (cnt + 15) >> 4;
    const float* W = Wa + (size_t)t * 4096;
    const float sg = 1.f / (1.f + __expf(-skip[t]));
    const int m = lane & 15, quad = lane >> 4;

    bf16x8 Bh[2][4], Bl[2][4];
#pragma unroll
    for (int ks = 0; ks < 2; ++ks)
#pragma unroll
        for (int c = 0; c < 4; ++c) load_B_split(W, ks, c, lane, Bh[ks][c], Bl[ks][c]);

    for (int s = blockIdx.x; s < nstrips; s += gridDim.x) {
        int base = beg + s * 16;
        int rA = base + m; if (rA > end - 1) rA = end - 1;
        const float* ap = io + (size_t)nidx[rA] * D;
        bf16x8 A0h, A0l, A1h, A1l;
        load_A_split(ap + quad * 8, A0h, A0l);
        load_A_split(ap + 32 + quad * 8, A1h, A1l);
        f32x4 acc[4];
#pragma unroll
        for (int c = 0; c < 4; ++c) acc[c] = (f32x4){0.f, 0.f, 0.f, 0.f};
        SPLIT_MFMA_BODY(acc, A0h, A0l, A1h, A1l, Bh, Bl)
#pragma unroll
        for (int reg = 0; reg < 4; ++reg) {
            int rr = base + quad * 4 + reg;
            if (rr < end) {
                size_t nb = (size_t)nidx[rr] * D;
#pragma unroll
                for (int c = 0; c < 4; ++c)
                    io[nb + c * 16 + m] = acc[c][reg] * sg;
            }
        }
    }
}

// ---------------- launch ----------------
extern "C" void kernel_launch(void* const* d_in, const int* in_sizes, int n_in,
                              void* d_out, int out_size, void* d_ws, size_t ws_size,
                              hipStream_t stream) {
    const float* h     = (const float*)d_in[0];
    const int*   adj   = (const int*)d_in[1];     // [2,E]: src row then dst row
    const int*   etype = (const int*)d_in[2];
    const int*   ntype = (const int*)d_in[3];
    const float* Wk    = (const float*)d_in[6];
    const float* Wq    = (const float*)d_in[7];
    const float* Wv    = (const float*)d_in[8];
    const float* Wa    = (const float*)d_in[9];
    const float* pri   = (const float*)d_in[10];
    const float* Aatt  = (const float*)d_in[11];
    const float* Amsg  = (const float*)d_in[12];
    const float* skp   = (const float*)d_in[13];
    const int N = in_sizes[3];
    const int E = in_sizes[2];
    float* out = (float*)d_out;

    char* w = (char*)d_ws;
    auto alloc = [&](size_t b) { char* p = w; w += (b + 255) & ~(size_t)255; return p; };
    _Float16* kh16 = (_Float16*)alloc((size_t)N * D * 2);
    float*    qn   = (float*)alloc((size_t)N * D * 4);
    _Float16* vn   = (_Float16*)alloc((size_t)N * D * 2);
    _Float16* V2   = (_Float16*)alloc((size_t)N * RR * D * 2);
    int* deg  = (int*)alloc((size_t)(N + 16) * 4);
    int* tcnt = deg + N;
    int* rcnt = deg + N + 8;
    int* offs = (int*)alloc((size_t)(N + 1) * 4);
    int* erank = (int*)alloc((size_t)E * 4);
    int* toff = (int*)alloc(64);
    int* tcur = (int*)alloc(64);
    int* roff = (int*)alloc(64);
    int* rcur = (int*)alloc(64);
    int2* rec = (int2*)alloc((size_t)E * 8);
    int* rsrc  = (int*)alloc((size_t)E * 4);
    int* rdst  = (int*)alloc((size_t)E * 4);
    int* rdpos = (int*)alloc((size_t)E * 4);
    int* nidx  = (int*)alloc((size_t)N * 4);
    const int nsb = (N + SCAN_ELEMS - 1) / SCAN_ELEMS;
    int* bsum  = (int*)alloc((size_t)nsb * 4);
    int* bbase = (int*)alloc((size_t)nsb * 4);

    (void)hipMemsetAsync(deg, 0, (size_t)(N + 16) * 4, stream);

    const int mx = (E > N ? E : N);
    hist_kernel<<<(mx + 255) / 256, 256, 0, stream>>>(adj + E, etype, ntype, deg, tcnt, rcnt, erank, N, E);
    scan_sum_kernel<<<nsb, SCAN_TPB, 0, stream>>>(deg, bsum, N);
    scan_mid_kernel<<<1, 64, 0, stream>>>(bsum, bbase, nsb, tcnt, toff, tcur, rcnt, roff, rcur);
    scan_out_kernel<<<nsb, SCAN_TPB, 0, stream>>>(deg, bbase, offs, N, E);
    scatter_kernel<<<(mx + 255) / 256, 256, 0, stream>>>(adj, adj + E, etype, ntype,
                                                         offs, erank, tcur, rcur,
                                                         rsrc, rdst, rdpos, nidx, N, E);
    proj_kernel<<<dim3(128, 3, TT), 64, 0, stream>>>(h, Wk, Wq, Wv, toff, nidx, kh16, qn, vn);
    v2_kernel<<<dim3(256, RR), 64, 0, stream>>>(vn, Amsg, V2, N);
    score_kernel<<<dim3(512, RR), 64, 0, stream>>>(rsrc, rdst, rdpos, roff, kh16, qn, Aatt, pri, rec);
    agg_kernel<<<(N + 15) / 16, 256, 0, stream>>>(offs, rec, V2, out, N);
    out_kernel<<<dim3(128, TT), 64, 0, stream>>>(out, Wa, skp, toff, nidx);
}

// Round 9
// 307.576 us; speedup vs baseline: 21.3628x; 1.0533x over previous
//
#include <hip/hip_runtime.h>
#include <math.h>

typedef float f32x4 __attribute__((ext_vector_type(4)));
typedef short bf16x8 __attribute__((ext_vector_type(8)));
typedef _Float16 f16x8 __attribute__((ext_vector_type(8)));
typedef _Float16 f16x4 __attribute__((ext_vector_type(4)));

#define D 64
#define TT 8
#define RR 8

#define SCAN_TPB 256
#define SCAN_CH 4
#define SCAN_ELEMS (SCAN_TPB * SCAN_CH)   // 1024 elements per block

// ---------------- scalar helpers ----------------
__device__ __forceinline__ float bf2f(unsigned short u) {
    union { unsigned int i; float f; } x;
    x.i = ((unsigned int)u) << 16;
    return x.f;
}
__device__ __forceinline__ unsigned short f2bf(float f) {
    union { float f; unsigned int i; } x;
    x.f = f;
    unsigned int i = x.i;
    unsigned int r = (i + 0x7FFFu + ((i >> 16) & 1u)) >> 16;   // RNE
    return (unsigned short)r;
}
struct BfPair { short hi; short lo; };
__device__ __forceinline__ BfPair split2(float x) {
    BfPair p;
    unsigned short h = f2bf(x);
    p.hi = (short)h;
    p.lo = (short)f2bf(x - bf2f(h));
    return p;
}
__device__ __forceinline__ void load_A_split(const float* __restrict__ p, bf16x8& ah, bf16x8& al) {
#pragma unroll
    for (int i = 0; i < 8; ++i) {
        BfPair s = split2(p[i]);
        ah[i] = s.hi; al[i] = s.lo;
    }
}
// bf16 split B fragment (used by proj/out split GEMMs)
__device__ __forceinline__ void load_B_split(const float* __restrict__ W, int ks, int c, int lane,
                                             bf16x8& bh, bf16x8& bl) {
    int n = lane & 15, q = lane >> 4;
#pragma unroll
    for (int i = 0; i < 8; ++i) {
        BfPair s = split2(W[(ks * 32 + q * 8 + i) * 64 + c * 16 + n]);
        bh[i] = s.hi; bl[i] = s.lo;
    }
}
// fp16 split B fragment (score: A-matrix hi+lo)
__device__ __forceinline__ void load_B_split_f16(const float* __restrict__ W, int ks, int c, int lane,
                                                 f16x8& bh, f16x8& bl) {
    int n = lane & 15, q = lane >> 4;
#pragma unroll
    for (int i = 0; i < 8; ++i) {
        float w = W[(ks * 32 + q * 8 + i) * 64 + c * 16 + n];
        _Float16 h = (_Float16)w;
        bh[i] = h;
        bl[i] = (_Float16)(w - (float)h);
    }
}
// fp16 single B fragment (V2 build)
__device__ __forceinline__ f16x8 load_B_frag_f16(const float* __restrict__ W, int ks, int c, int lane) {
    int n = lane & 15, q = lane >> 4;
    f16x8 r;
#pragma unroll
    for (int i = 0; i < 8; ++i)
        r[i] = (_Float16)W[(ks * 32 + q * 8 + i) * 64 + c * 16 + n];
    return r;
}

#define MFMA16(a, b, c) __builtin_amdgcn_mfma_f32_16x16x32_bf16(a, b, c, 0, 0, 0)
#define MFMAH(a, b, c)  __builtin_amdgcn_mfma_f32_16x16x32_f16(a, b, c, 0, 0, 0)

// 24 bf16 MFMAs: acc += (Ah+Al)@(Bh+Bl) dropping lo*lo
#define SPLIT_MFMA_BODY(acc, A0h, A0l, A1h, A1l, Bh, Bl)          \
    _Pragma("unroll")                                             \
    for (int c = 0; c < 4; ++c) {                                 \
        acc[c] = MFMA16(A0h, Bh[0][c], acc[c]);                   \
        acc[c] = MFMA16(A0l, Bh[0][c], acc[c]);                   \
        acc[c] = MFMA16(A0h, Bl[0][c], acc[c]);                   \
        acc[c] = MFMA16(A1h, Bh[1][c], acc[c]);                   \
        acc[c] = MFMA16(A1l, Bh[1][c], acc[c]);                   \
        acc[c] = MFMA16(A1h, Bl[1][c], acc[c]);                   \
    }

// ---------------- CSR build ----------------
__global__ void hist_kernel(const int* __restrict__ dst, const int* __restrict__ et,
                            const int* __restrict__ nt,
                            int* __restrict__ deg, int* __restrict__ tcnt, int* __restrict__ rcnt,
                            int* __restrict__ erank, int N, int E) {
    __shared__ int l_r[RR], l_t[TT];
    if (threadIdx.x < RR) l_r[threadIdx.x] = 0;
    if (threadIdx.x < TT) l_t[threadIdx.x] = 0;
    __syncthreads();
    int tid = blockIdx.x * blockDim.x + threadIdx.x;
    if (tid < E) {
        erank[tid] = atomicAdd(&deg[dst[tid]], 1);
        atomicAdd(&l_r[et[tid]], 1);
    }
    if (tid < N) atomicAdd(&l_t[nt[tid]], 1);
    __syncthreads();
    if (threadIdx.x < RR && l_r[threadIdx.x]) atomicAdd(&rcnt[threadIdx.x], l_r[threadIdx.x]);
    if (threadIdx.x < TT && l_t[threadIdx.x]) atomicAdd(&tcnt[threadIdx.x], l_t[threadIdx.x]);
}

__global__ void scan_sum_kernel(const int* __restrict__ deg, int* __restrict__ bsum, int N) {
    __shared__ int ws[SCAN_TPB / 64];
    int tid = threadIdx.x;
    int base = blockIdx.x * SCAN_ELEMS + tid * SCAN_CH;
    int s = 0;
#pragma unroll
    for (int i = 0; i < SCAN_CH; ++i) {
        int idx = base + i;
        if (idx < N) s += deg[idx];
    }
#pragma unroll
    for (int d = 32; d; d >>= 1) s += __shfl_xor(s, d, 64);
    if ((tid & 63) == 0) ws[tid >> 6] = s;
    __syncthreads();
    if (tid == 0) {
        int t = 0;
#pragma unroll
        for (int i = 0; i < SCAN_TPB / 64; ++i) t += ws[i];
        bsum[blockIdx.x] = t;
    }
}
__global__ void scan_mid_kernel(const int* __restrict__ bsum, int* __restrict__ bbase, int nsb,
                                const int* __restrict__ tcnt, int* __restrict__ toff, int* __restrict__ tcur,
                                const int* __restrict__ rcnt, int* __restrict__ roff, int* __restrict__ rcur) {
    if (threadIdx.x == 0) {
        int run = 0;
        for (int b = 0; b < nsb; ++b) { bbase[b] = run; run += bsum[b]; }
        int a = 0;
        for (int t = 0; t < TT; ++t) { toff[t] = a; tcur[t] = a; a += tcnt[t]; }
        toff[TT] = a;
        int bb = 0;
        for (int r = 0; r < RR; ++r) { roff[r] = bb; rcur[r] = bb; bb += rcnt[r]; }
        roff[RR] = bb;
    }
}
__global__ void scan_out_kernel(const int* __restrict__ deg, const int* __restrict__ bbase,
                                int* __restrict__ off, int N, int Etot) {
    __shared__ int ts[SCAN_TPB];
    int tid = threadIdx.x;
    int base = blockIdx.x * SCAN_ELEMS + tid * SCAN_CH;
    int loc[SCAN_CH];
    int s = 0;
#pragma unroll
    for (int i = 0; i < SCAN_CH; ++i) {
        int idx = base + i;
        int v = (idx < N) ? deg[idx] : 0;
        loc[i] = v; s += v;
    }
    ts[tid] = s;
    __syncthreads();
    for (int sh = 1; sh < SCAN_TPB; sh <<= 1) {
        int v = (tid >= sh) ? ts[tid - sh] : 0;
        __syncthreads();
        ts[tid] += v;
        __syncthreads();
    }
    int run = bbase[blockIdx.x] + ((tid > 0) ? ts[tid - 1] : 0);
#pragma unroll
    for (int i = 0; i < SCAN_CH; ++i) {
        int idx = base + i;
        if (idx < N) { off[idx] = run; run += loc[i]; }
    }
    if (blockIdx.x == 0 && tid == 0) off[N] = Etot;
}

__global__ void scatter_kernel(const int* __restrict__ src, const int* __restrict__ dst,
                               const int* __restrict__ et, const int* __restrict__ nt,
                               const int* __restrict__ offs, const int* __restrict__ erank,
                               int* __restrict__ tcur, int* __restrict__ rcur,
                               int* __restrict__ rsrc, int* __restrict__ rdst,
                               int* __restrict__ rdpos, int* __restrict__ nidx, int N, int E) {
    __shared__ int l_r[RR], l_t[TT], base_r[RR], base_t[TT];
    if (threadIdx.x < RR) l_r[threadIdx.x] = 0;
    if (threadIdx.x < TT) l_t[threadIdx.x] = 0;
    __syncthreads();
    int tid = blockIdx.x * blockDim.x + threadIdx.x;
    int s = 0, d = 0, r = 0, t = 0, rrank = 0, trank = 0;
    if (tid < E) {
        s = src[tid]; d = dst[tid]; r = et[tid];
        rrank = atomicAdd(&l_r[r], 1);
    }
    if (tid < N) {
        t = nt[tid];
        trank = atomicAdd(&l_t[t], 1);
    }
    __syncthreads();
    if (threadIdx.x < RR)
        base_r[threadIdx.x] = l_r[threadIdx.x] ? atomicAdd(&rcur[threadIdx.x], l_r[threadIdx.x]) : 0;
    if (threadIdx.x < TT)
        base_t[threadIdx.x] = l_t[threadIdx.x] ? atomicAdd(&tcur[threadIdx.x], l_t[threadIdx.x]) : 0;
    __syncthreads();
    if (tid < E) {
        int pos = offs[d] + erank[tid];
        int rp = base_r[r] + rrank;
        rsrc[rp] = s; rdst[rp] = d; rdpos[rp] = pos;
    }
    if (tid < N) {
        nidx[base_t[t] + trank] = tid;
    }
}

// ---------------- node projections ----------------
// a=0: k -> fp16 row (128B); a=1: q -> fp16 row (128B); a=2: v fp16.
// GEMMs internally split-bf16 accurate; only final store rounds to fp16.
__global__ void proj_kernel(const float* __restrict__ h,
                            const float* __restrict__ Wk, const float* __restrict__ Wq,
                            const float* __restrict__ Wv,
                            const int* __restrict__ toff, const int* __restrict__ nidx,
                            _Float16* __restrict__ kh16,
                            _Float16* __restrict__ qout, _Float16* __restrict__ vout) {
    const int t = blockIdx.z, a = blockIdx.y, lane = threadIdx.x;
    const int beg = toff[t], end = toff[t + 1], cnt = end - beg;
    if (cnt <= 0) return;
    const int nstrips = (cnt + 15) >> 4;
    const float* W = (a == 0 ? Wk : (a == 1 ? Wq : Wv)) + (size_t)t * 4096;
    const int m = lane & 15, quad = lane >> 4;

    bf16x8 Bh[2][4], Bl[2][4];
#pragma unroll
    for (int ks = 0; ks < 2; ++ks)
#pragma unroll
        for (int c = 0; c < 4; ++c) load_B_split(W, ks, c, lane, Bh[ks][c], Bl[ks][c]);

    _Float16* out = (a == 0) ? kh16 : (a == 1 ? qout : vout);

    for (int s = blockIdx.x; s < nstrips; s += gridDim.x) {
        int base = beg + s * 16;
        int rA = base + m; if (rA > end - 1) rA = end - 1;
        const float* hp = h + (size_t)nidx[rA] * D;
        bf16x8 A0h, A0l, A1h, A1l;
        load_A_split(hp + quad * 8, A0h, A0l);
        load_A_split(hp + 32 + quad * 8, A1h, A1l);
        f32x4 acc[4];
#pragma unroll
        for (int c = 0; c < 4; ++c) acc[c] = (f32x4){0.f, 0.f, 0.f, 0.f};
        SPLIT_MFMA_BODY(acc, A0h, A0l, A1h, A1l, Bh, Bl)
#pragma unroll
        for (int reg = 0; reg < 4; ++reg) {
            int rr = base + quad * 4 + reg;
            if (rr < end) {
                int nid = nidx[rr];
#pragma unroll
                for (int c = 0; c < 4; ++c)
                    out[(size_t)nid * D + c * 16 + m] = (_Float16)acc[c][reg];
            }
        }
    }
}

// ---------------- V2[n][r] = v_node[n] @ M[r]  (fp16) ----------------
__global__ void v2_kernel(const _Float16* __restrict__ vn, const float* __restrict__ Amsg,
                          _Float16* __restrict__ V2, int N) {
    const int r = blockIdx.y, lane = threadIdx.x;
    const int m = lane & 15, quad = lane >> 4;
    const int nstrips = (N + 15) >> 4;
    const float* W = Amsg + (size_t)r * 4096;
    f16x8 B[2][4];
#pragma unroll
    for (int ks = 0; ks < 2; ++ks)
#pragma unroll
        for (int c = 0; c < 4; ++c) B[ks][c] = load_B_frag_f16(W, ks, c, lane);

    for (int s = blockIdx.x; s < nstrips; s += gridDim.x) {
        int base = s * 16;
        int rA = base + m; if (rA > N - 1) rA = N - 1;
        f16x8 A0 = *(const f16x8*)(vn + (size_t)rA * D + quad * 8);
        f16x8 A1 = *(const f16x8*)(vn + (size_t)rA * D + 32 + quad * 8);
        f32x4 acc[4];
#pragma unroll
        for (int c = 0; c < 4; ++c) acc[c] = (f32x4){0.f, 0.f, 0.f, 0.f};
#pragma unroll
        for (int c = 0; c < 4; ++c) {
            acc[c] = MFMAH(A0, B[0][c], acc[c]);
            acc[c] = MFMAH(A1, B[1][c], acc[c]);
        }
#pragma unroll
        for (int reg = 0; reg < 4; ++reg) {
            int rr = base + quad * 4 + reg;
            if (rr < N) {
#pragma unroll
                for (int c = 0; c < 4; ++c)
                    V2[((size_t)rr * RR + r) * D + c * 16 + m] = (_Float16)acc[c][reg];
            }
        }
    }
}

// ---------------- per-edge scores: k fp16 (128B), A split-fp16, q fp16 (128B) ----------------
__global__ void score_kernel(const int* __restrict__ rsrc, const int* __restrict__ rdst,
                             const int* __restrict__ rdpos, const int* __restrict__ roff,
                             const _Float16* __restrict__ kh16,
                             const _Float16* __restrict__ qn, const float* __restrict__ Aatt,
                             const float* __restrict__ pri, int2* __restrict__ rec) {
    const int r = blockIdx.y, lane = threadIdx.x;
    const int beg = roff[r], end = roff[r + 1], cnt = end - beg;
    if (cnt <= 0) return;
    const int nstrips = (cnt + 15) >> 4;
    const int m = lane & 15, quad = lane >> 4;
    const float scale = pri[r] * 0.125f;
    const float* W = Aatt + (size_t)r * 4096;

    f16x8 Bh[2][4], Bl[2][4];
#pragma unroll
    for (int ks = 0; ks < 2; ++ks)
#pragma unroll
        for (int c = 0; c < 4; ++c) load_B_split_f16(W, ks, c, lane, Bh[ks][c], Bl[ks][c]);

    for (int st = blockIdx.x; st < nstrips; st += gridDim.x) {
        int base = st * 16;
        int ia = base + m; if (ia > cnt - 1) ia = cnt - 1;
        int s = rsrc[beg + ia];
        const _Float16* kr = kh16 + (size_t)s * D;   // 128B row
        f16x8 A0 = *(const f16x8*)(kr + quad * 8);
        f16x8 A1 = *(const f16x8*)(kr + 32 + quad * 8);
        f32x4 acc[4];
#pragma unroll
        for (int c = 0; c < 4; ++c) acc[c] = (f32x4){0.f, 0.f, 0.f, 0.f};
#pragma unroll
        for (int c = 0; c < 4; ++c) {
            acc[c] = MFMAH(A0, Bh[0][c], acc[c]);
            acc[c] = MFMAH(A0, Bl[0][c], acc[c]);
            acc[c] = MFMAH(A1, Bh[1][c], acc[c]);
            acc[c] = MFMAH(A1, Bl[1][c], acc[c]);
        }

        float p4[4];
#pragma unroll
        for (int reg = 0; reg < 4; ++reg) {
            int ie = base + quad * 4 + reg; if (ie > cnt - 1) ie = cnt - 1;
            const _Float16* qp = qn + (size_t)rdst[beg + ie] * D + m;
            float pr = acc[0][reg] * (float)qp[0] + acc[1][reg] * (float)qp[16]
                     + acc[2][reg] * (float)qp[32] + acc[3][reg] * (float)qp[48];
#pragma unroll
            for (int d = 8; d; d >>= 1) pr += __shfl_xor(pr, d, 64);
            p4[reg] = pr;
        }
        if (m < 4) {
            int idx = base + quad * 4 + m;
            if (idx < cnt) {
                float v = (m == 0) ? p4[0] : (m == 1) ? p4[1] : (m == 2) ? p4[2] : p4[3];
                int sagain = rsrc[beg + idx];
                int2 rc;
                rc.x = __float_as_int(v * scale);
                rc.y = (sagain << 3) | r;                     // V2 row id
                rec[rdpos[beg + idx]] = rc;
            }
        }
    }
}

// ---------------- per-dst softmax + aggregation: one 16-lane quad per node ----------------
__global__ void agg_kernel(const int* __restrict__ offs, const int2* __restrict__ rec,
                           const _Float16* __restrict__ V2,
                           float* __restrict__ agg, int N) {
    const int lane = threadIdx.x & 63;
    const int wv = threadIdx.x >> 6;         // 4 waves/block
    const int quad = lane >> 4, ql = lane & 15;
    const int i = blockIdx.x * 16 + wv * 4 + quad;
    if (i >= N) return;
    const int beg = offs[i], end = offs[i + 1];
    const int qb = quad << 4;
    float mmax = -INFINITY, lsum = 0.f;
    float a0 = 0.f, a1 = 0.f, a2 = 0.f, a3 = 0.f;
    for (int cs = beg; cs < end; cs += 16) {
        int cl = end - cs; if (cl > 16) cl = 16;
        // phase 1: 16 lanes = 16 edges
        int2 rc; rc.y = 0;
        float sc = -INFINITY;
        if (ql < cl) { rc = rec[cs + ql]; sc = __int_as_float(rc.x); }
        float cm = sc;
#pragma unroll
        for (int d = 8; d; d >>= 1) cm = fmaxf(cm, __shfl_xor(cm, d, 64));
        float mn = fmaxf(mmax, cm);
        float cf = __expf(mmax - mn);             // 0 on first chunk
        float ex = (ql < cl) ? __expf(sc - mn) : 0.f;
        float csum = ex;
#pragma unroll
        for (int d = 8; d; d >>= 1) csum += __shfl_xor(csum, d, 64);
        lsum = lsum * cf + csum;
        a0 *= cf; a1 *= cf; a2 *= cf; a3 *= cf;
        // phase 2: 16 lanes = 64 dims (4 each); weights/rows broadcast from quad lanes
        for (int e = 0; e < cl; e += 2) {
            float w0 = __shfl(ex, qb + e, 64);
            int   i0 = __shfl(rc.y, qb + e, 64);
            float w1 = __shfl(ex, qb + e + 1, 64);   // 0-weight row if e+1>=cl (lanes init 0)
            int   i1 = __shfl(rc.y, qb + e + 1, 64);
            f16x4 v0 = *(const f16x4*)(V2 + (size_t)i0 * D + ql * 4);
            f16x4 v1 = *(const f16x4*)(V2 + (size_t)i1 * D + ql * 4);
            a0 += w0 * (float)v0[0] + w1 * (float)v1[0];
            a1 += w0 * (float)v0[1] + w1 * (float)v1[1];
            a2 += w0 * (float)v0[2] + w1 * (float)v1[2];
            a3 += w0 * (float)v0[3] + w1 * (float)v1[3];
        }
        mmax = mn;
    }
    float inv = 1.f / (lsum + 1e-16f);
    f32x4 outv = (f32x4){a0 * inv, a1 * inv, a2 * inv, a3 * inv};
    *(f32x4*)(agg + (size_t)i * D + ql * 4) = outv;
}

// ---------------- output transform (split-bf16 MFMA, in place on d_out) ----------------
__global__ void out_kernel(float* __restrict__ io, const float* __restrict__ Wa,
                           const float* __restrict__ skip,
                           const int* __restrict__ toff, const int* __restrict__ nidx) {
    const int t = blockIdx.y, lane = threadIdx.x;
    const int beg = toff[t], end = toff[t + 1], cnt = end - beg;
    if (cnt <= 0) return;
    const int nstrips = (cnt + 15) >> 4;
    const float* W = Wa + (size_t)t * 4096;
    const float sg = 1.f / (1.f + __expf(-skip[t]));
    const int m = lane & 15, quad = lane >> 4;

    bf16x8 Bh[2][4], Bl[2][4];
#pragma unroll
    for (int ks = 0; ks < 2; ++ks)
#pragma unroll
        for (int c = 0; c < 4; ++c) load_B_split(W, ks, c, lane, Bh[ks][c], Bl[ks][c]);

    for (int s = blockIdx.x; s < nstrips; s += gridDim.x) {
        int base = beg + s * 16;
        int rA = base + m; if (rA > end - 1) rA = end - 1;
        const float* ap = io + (size_t)nidx[rA] * D;
        bf16x8 A0h, A0l, A1h, A1l;
        load_A_split(ap + quad * 8, A0h, A0l);
        load_A_split(ap + 32 + quad * 8, A1h, A1l);
        f32x4 acc[4];
#pragma unroll
        for (int c = 0; c < 4; ++c) acc[c] = (f32x4){0.f, 0.f, 0.f, 0.f};
        SPLIT_MFMA_BODY(acc, A0h, A0l, A1h, A1l, Bh, Bl)
#pragma unroll
        for (int reg = 0; reg < 4; ++reg) {
            int rr = base + quad * 4 + reg;
            if (rr < end) {
                size_t nb = (size_t)nidx[rr] * D;
#pragma unroll
                for (int c = 0; c < 4; ++c)
                    io[nb + c * 16 + m] = acc[c][reg] * sg;
            }
        }
    }
}

// ---------------- launch ----------------
extern "C" void kernel_launch(void* const* d_in, const int* in_sizes, int n_in,
                              void* d_out, int out_size, void* d_ws, size_t ws_size,
                              hipStream_t stream) {
    const float* h     = (const float*)d_in[0];
    const int*   adj   = (const int*)d_in[1];     // [2,E]: src row then dst row
    const int*   etype = (const int*)d_in[2];
    const int*   ntype = (const int*)d_in[3];
    const float* Wk    = (const float*)d_in[6];
    const float* Wq    = (const float*)d_in[7];
    const float* Wv    = (const float*)d_in[8];
    const float* Wa    = (const float*)d_in[9];
    const float* pri   = (const float*)d_in[10];
    const float* Aatt  = (const float*)d_in[11];
    const float* Amsg  = (const float*)d_in[12];
    const float* skp   = (const float*)d_in[13];
    const int N = in_sizes[3];
    const int E = in_sizes[2];
    float* out = (float*)d_out;

    char* w = (char*)d_ws;
    auto alloc = [&](size_t b) { char* p = w; w += (b + 255) & ~(size_t)255; return p; };
    _Float16* kh16 = (_Float16*)alloc((size_t)N * D * 2);
    _Float16* qn   = (_Float16*)alloc((size_t)N * D * 2);
    _Float16* vn   = (_Float16*)alloc((size_t)N * D * 2);
    _Float16* V2   = (_Float16*)alloc((size_t)N * RR * D * 2);
    int* deg  = (int*)alloc((size_t)(N + 16) * 4);
    int* tcnt = deg + N;
    int* rcnt = deg + N + 8;
    int* offs = (int*)alloc((size_t)(N + 1) * 4);
    int* erank = (int*)alloc((size_t)E * 4);
    int* toff = (int*)alloc(64);
    int* tcur = (int*)alloc(64);
    int* roff = (int*)alloc(64);
    int* rcur = (int*)alloc(64);
    int2* rec = (int2*)alloc((size_t)E * 8);
    int* rsrc  = (int*)alloc((size_t)E * 4);
    int* rdst  = (int*)alloc((size_t)E * 4);
    int* rdpos = (int*)alloc((size_t)E * 4);
    int* nidx  = (int*)alloc((size_t)N * 4);
    const int nsb = (N + SCAN_ELEMS - 1) / SCAN_ELEMS;
    int* bsum  = (int*)alloc((size_t)nsb * 4);
    int* bbase = (int*)alloc((size_t)nsb * 4);

    (void)hipMemsetAsync(deg, 0, (size_t)(N + 16) * 4, stream);

    const int mx = (E > N ? E : N);
    hist_kernel<<<(mx + 255) / 256, 256, 0, stream>>>(adj + E, etype, ntype, deg, tcnt, rcnt, erank, N, E);
    scan_sum_kernel<<<nsb, SCAN_TPB, 0, stream>>>(deg, bsum, N);
    scan_mid_kernel<<<1, 64, 0, stream>>>(bsum, bbase, nsb, tcnt, toff, tcur, rcnt, roff, rcur);
    scan_out_kernel<<<nsb, SCAN_TPB, 0, stream>>>(deg, bbase, offs, N, E);
    scatter_kernel<<<(mx + 255) / 256, 256, 0, stream>>>(adj, adj + E, etype, ntype,
                                                         offs, erank, tcur, rcur,
                                                         rsrc, rdst, rdpos, nidx, N, E);
    proj_kernel<<<dim3(128, 3, TT), 64, 0, stream>>>(h, Wk, Wq, Wv, toff, nidx, kh16, qn, vn);
    v2_kernel<<<dim3(256, RR), 64, 0, stream>>>(vn, Amsg, V2, N);
    score_kernel<<<dim3(512, RR), 64, 0, stream>>>(rsrc, rdst, rdpos, roff, kh16, qn, Aatt, pri, rec);
    agg_kernel<<<(N + 15) / 16, 256, 0, stream>>>(offs, rec, V2, out, N);
    out_kernel<<<dim3(128, TT), 64, 0, stream>>>(out, Wa, skp, toff, nidx);
}

// Round 10
// 295.430 us; speedup vs baseline: 22.2411x; 1.0411x over previous
//
#include <hip/hip_runtime.h>
#include <math.h>

typedef float f32x4 __attribute__((ext_vector_type(4)));
typedef short bf16x8 __attribute__((ext_vector_type(8)));
typedef _Float16 f16x8 __attribute__((ext_vector_type(8)));
typedef _Float16 f16x4 __attribute__((ext_vector_type(4)));

#define D 64
#define TT 8
#define RR 8

#define SCAN_TPB 256
#define SCAN_CH 4
#define SCAN_ELEMS (SCAN_TPB * SCAN_CH)   // 1024 elements per block

#define HIST_CH 4                          // edges per thread (outstanding atomics)

// ---------------- scalar helpers ----------------
__device__ __forceinline__ float bf2f(unsigned short u) {
    union { unsigned int i; float f; } x;
    x.i = ((unsigned int)u) << 16;
    return x.f;
}
__device__ __forceinline__ unsigned short f2bf(float f) {
    union { float f; unsigned int i; } x;
    x.f = f;
    unsigned int i = x.i;
    unsigned int r = (i + 0x7FFFu + ((i >> 16) & 1u)) >> 16;   // RNE
    return (unsigned short)r;
}
struct BfPair { short hi; short lo; };
__device__ __forceinline__ BfPair split2(float x) {
    BfPair p;
    unsigned short h = f2bf(x);
    p.hi = (short)h;
    p.lo = (short)f2bf(x - bf2f(h));
    return p;
}
__device__ __forceinline__ void load_A_split(const float* __restrict__ p, bf16x8& ah, bf16x8& al) {
#pragma unroll
    for (int i = 0; i < 8; ++i) {
        BfPair s = split2(p[i]);
        ah[i] = s.hi; al[i] = s.lo;
    }
}
// bf16 split B fragment (used by proj/out split GEMMs)
__device__ __forceinline__ void load_B_split(const float* __restrict__ W, int ks, int c, int lane,
                                             bf16x8& bh, bf16x8& bl) {
    int n = lane & 15, q = lane >> 4;
#pragma unroll
    for (int i = 0; i < 8; ++i) {
        BfPair s = split2(W[(ks * 32 + q * 8 + i) * 64 + c * 16 + n]);
        bh[i] = s.hi; bl[i] = s.lo;
    }
}
// fp16 split B fragment (score: A-matrix hi+lo)
__device__ __forceinline__ void load_B_split_f16(const float* __restrict__ W, int ks, int c, int lane,
                                                 f16x8& bh, f16x8& bl) {
    int n = lane & 15, q = lane >> 4;
#pragma unroll
    for (int i = 0; i < 8; ++i) {
        float w = W[(ks * 32 + q * 8 + i) * 64 + c * 16 + n];
        _Float16 h = (_Float16)w;
        bh[i] = h;
        bl[i] = (_Float16)(w - (float)h);
    }
}
// fp16 single B fragment (V2 build)
__device__ __forceinline__ f16x8 load_B_frag_f16(const float* __restrict__ W, int ks, int c, int lane) {
    int n = lane & 15, q = lane >> 4;
    f16x8 r;
#pragma unroll
    for (int i = 0; i < 8; ++i)
        r[i] = (_Float16)W[(ks * 32 + q * 8 + i) * 64 + c * 16 + n];
    return r;
}

#define MFMA16(a, b, c) __builtin_amdgcn_mfma_f32_16x16x32_bf16(a, b, c, 0, 0, 0)
#define MFMAH(a, b, c)  __builtin_amdgcn_mfma_f32_16x16x32_f16(a, b, c, 0, 0, 0)

// 24 bf16 MFMAs: acc += (Ah+Al)@(Bh+Bl) dropping lo*lo
#define SPLIT_MFMA_BODY(acc, A0h, A0l, A1h, A1l, Bh, Bl)          \
    _Pragma("unroll")                                             \
    for (int c = 0; c < 4; ++c) {                                 \
        acc[c] = MFMA16(A0h, Bh[0][c], acc[c]);                   \
        acc[c] = MFMA16(A0l, Bh[0][c], acc[c]);                   \
        acc[c] = MFMA16(A0h, Bl[0][c], acc[c]);                   \
        acc[c] = MFMA16(A1h, Bh[1][c], acc[c]);                   \
        acc[c] = MFMA16(A1l, Bh[1][c], acc[c]);                   \
        acc[c] = MFMA16(A1h, Bl[1][c], acc[c]);                   \
    }

// ---------------- CSR build ----------------
// 4 grid-strided edges/thread -> 4 independent returning atomics in flight per lane.
__global__ void hist_kernel(const int* __restrict__ dst, const int* __restrict__ et,
                            const int* __restrict__ nt,
                            int* __restrict__ deg, int* __restrict__ tcnt, int* __restrict__ rcnt,
                            int* __restrict__ erank, int N, int E) {
    __shared__ int l_r[RR], l_t[TT];
    if (threadIdx.x < RR) l_r[threadIdx.x] = 0;
    if (threadIdx.x < TT) l_t[threadIdx.x] = 0;
    __syncthreads();
    const int stride = gridDim.x * blockDim.x;
    const int tid = blockIdx.x * blockDim.x + threadIdx.x;
#pragma unroll
    for (int i = 0; i < HIST_CH; ++i) {
        int e = tid + i * stride;
        if (e < E) {
            erank[e] = atomicAdd(&deg[dst[e]], 1);
            atomicAdd(&l_r[et[e]], 1);
        }
    }
#pragma unroll
    for (int i = 0; i < HIST_CH; ++i) {
        int n = tid + i * stride;
        if (n < N) atomicAdd(&l_t[nt[n]], 1);
    }
    __syncthreads();
    if (threadIdx.x < RR && l_r[threadIdx.x]) atomicAdd(&rcnt[threadIdx.x], l_r[threadIdx.x]);
    if (threadIdx.x < TT && l_t[threadIdx.x]) atomicAdd(&tcnt[threadIdx.x], l_t[threadIdx.x]);
}

__global__ void scan_sum_kernel(const int* __restrict__ deg, int* __restrict__ bsum, int N) {
    __shared__ int ws[SCAN_TPB / 64];
    int tid = threadIdx.x;
    int base = blockIdx.x * SCAN_ELEMS + tid * SCAN_CH;
    int s = 0;
#pragma unroll
    for (int i = 0; i < SCAN_CH; ++i) {
        int idx = base + i;
        if (idx < N) s += deg[idx];
    }
#pragma unroll
    for (int d = 32; d; d >>= 1) s += __shfl_xor(s, d, 64);
    if ((tid & 63) == 0) ws[tid >> 6] = s;
    __syncthreads();
    if (tid == 0) {
        int t = 0;
#pragma unroll
        for (int i = 0; i < SCAN_TPB / 64; ++i) t += ws[i];
        bsum[blockIdx.x] = t;
    }
}
__global__ void scan_mid_kernel(const int* __restrict__ bsum, int* __restrict__ bbase, int nsb,
                                const int* __restrict__ tcnt, int* __restrict__ toff, int* __restrict__ tcur,
                                const int* __restrict__ rcnt, int* __restrict__ roff, int* __restrict__ rcur) {
    if (threadIdx.x == 0) {
        int run = 0;
        for (int b = 0; b < nsb; ++b) { bbase[b] = run; run += bsum[b]; }
        int a = 0;
        for (int t = 0; t < TT; ++t) { toff[t] = a; tcur[t] = a; a += tcnt[t]; }
        toff[TT] = a;
        int bb = 0;
        for (int r = 0; r < RR; ++r) { roff[r] = bb; rcur[r] = bb; bb += rcnt[r]; }
        roff[RR] = bb;
    }
}
__global__ void scan_out_kernel(const int* __restrict__ deg, const int* __restrict__ bbase,
                                int* __restrict__ off, int N, int Etot) {
    __shared__ int ts[SCAN_TPB];
    int tid = threadIdx.x;
    int base = blockIdx.x * SCAN_ELEMS + tid * SCAN_CH;
    int loc[SCAN_CH];
    int s = 0;
#pragma unroll
    for (int i = 0; i < SCAN_CH; ++i) {
        int idx = base + i;
        int v = (idx < N) ? deg[idx] : 0;
        loc[i] = v; s += v;
    }
    ts[tid] = s;
    __syncthreads();
    for (int sh = 1; sh < SCAN_TPB; sh <<= 1) {
        int v = (tid >= sh) ? ts[tid - sh] : 0;
        __syncthreads();
        ts[tid] += v;
        __syncthreads();
    }
    int run = bbase[blockIdx.x] + ((tid > 0) ? ts[tid - 1] : 0);
#pragma unroll
    for (int i = 0; i < SCAN_CH; ++i) {
        int idx = base + i;
        if (idx < N) { off[idx] = run; run += loc[i]; }
    }
    if (blockIdx.x == 0 && tid == 0) off[N] = Etot;
}

__global__ void scatter_kernel(const int* __restrict__ src, const int* __restrict__ dst,
                               const int* __restrict__ et, const int* __restrict__ nt,
                               const int* __restrict__ offs, const int* __restrict__ erank,
                               int* __restrict__ tcur, int* __restrict__ rcur,
                               int* __restrict__ rsrc, int* __restrict__ rdst,
                               int* __restrict__ rdpos, int* __restrict__ nidx, int N, int E) {
    __shared__ int l_r[RR], l_t[TT], base_r[RR], base_t[TT];
    if (threadIdx.x < RR) l_r[threadIdx.x] = 0;
    if (threadIdx.x < TT) l_t[threadIdx.x] = 0;
    __syncthreads();
    int tid = blockIdx.x * blockDim.x + threadIdx.x;
    int s = 0, d = 0, r = 0, t = 0, rrank = 0, trank = 0;
    if (tid < E) {
        s = src[tid]; d = dst[tid]; r = et[tid];
        rrank = atomicAdd(&l_r[r], 1);
    }
    if (tid < N) {
        t = nt[tid];
        trank = atomicAdd(&l_t[t], 1);
    }
    __syncthreads();
    if (threadIdx.x < RR)
        base_r[threadIdx.x] = l_r[threadIdx.x] ? atomicAdd(&rcur[threadIdx.x], l_r[threadIdx.x]) : 0;
    if (threadIdx.x < TT)
        base_t[threadIdx.x] = l_t[threadIdx.x] ? atomicAdd(&tcur[threadIdx.x], l_t[threadIdx.x]) : 0;
    __syncthreads();
    if (tid < E) {
        int pos = offs[d] + erank[tid];
        int rp = base_r[r] + rrank;
        rsrc[rp] = s; rdst[rp] = d; rdpos[rp] = pos;
    }
    if (tid < N) {
        nidx[base_t[t] + trank] = tid;
    }
}

// ---------------- node projections ----------------
// a=0: k -> fp16 row (128B); a=1: q -> fp16 row (128B); a=2: v fp16.
// GEMMs internally split-bf16 accurate; only final store rounds to fp16.
__global__ void proj_kernel(const float* __restrict__ h,
                            const float* __restrict__ Wk, const float* __restrict__ Wq,
                            const float* __restrict__ Wv,
                            const int* __restrict__ toff, const int* __restrict__ nidx,
                            _Float16* __restrict__ kh16,
                            _Float16* __restrict__ qout, _Float16* __restrict__ vout) {
    const int t = blockIdx.z, a = blockIdx.y, lane = threadIdx.x;
    const int beg = toff[t], end = toff[t + 1], cnt = end - beg;
    if (cnt <= 0) return;
    const int nstrips = (cnt + 15) >> 4;
    const float* W = (a == 0 ? Wk : (a == 1 ? Wq : Wv)) + (size_t)t * 4096;
    const int m = lane & 15, quad = lane >> 4;

    bf16x8 Bh[2][4], Bl[2][4];
#pragma unroll
    for (int ks = 0; ks < 2; ++ks)
#pragma unroll
        for (int c = 0; c < 4; ++c) load_B_split(W, ks, c, lane, Bh[ks][c], Bl[ks][c]);

    _Float16* out = (a == 0) ? kh16 : (a == 1 ? qout : vout);

    for (int s = blockIdx.x; s < nstrips; s += gridDim.x) {
        int base = beg + s * 16;
        int rA = base + m; if (rA > end - 1) rA = end - 1;
        const float* hp = h + (size_t)nidx[rA] * D;
        bf16x8 A0h, A0l, A1h, A1l;
        load_A_split(hp + quad * 8, A0h, A0l);
        load_A_split(hp + 32 + quad * 8, A1h, A1l);
        f32x4 acc[4];
#pragma unroll
        for (int c = 0; c < 4; ++c) acc[c] = (f32x4){0.f, 0.f, 0.f, 0.f};
        SPLIT_MFMA_BODY(acc, A0h, A0l, A1h, A1l, Bh, Bl)
#pragma unroll
        for (int reg = 0; reg < 4; ++reg) {
            int rr = base + quad * 4 + reg;
            if (rr < end) {
                int nid = nidx[rr];
#pragma unroll
                for (int c = 0; c < 4; ++c)
                    out[(size_t)nid * D + c * 16 + m] = (_Float16)acc[c][reg];
            }
        }
    }
}

// ---------------- V2[n][r] = v_node[n] @ M[r]  (fp16) ----------------
__global__ void v2_kernel(const _Float16* __restrict__ vn, const float* __restrict__ Amsg,
                          _Float16* __restrict__ V2, int N) {
    const int r = blockIdx.y, lane = threadIdx.x;
    const int m = lane & 15, quad = lane >> 4;
    const int nstrips = (N + 15) >> 4;
    const float* W = Amsg + (size_t)r * 4096;
    f16x8 B[2][4];
#pragma unroll
    for (int ks = 0; ks < 2; ++ks)
#pragma unroll
        for (int c = 0; c < 4; ++c) B[ks][c] = load_B_frag_f16(W, ks, c, lane);

    for (int s = blockIdx.x; s < nstrips; s += gridDim.x) {
        int base = s * 16;
        int rA = base + m; if (rA > N - 1) rA = N - 1;
        f16x8 A0 = *(const f16x8*)(vn + (size_t)rA * D + quad * 8);
        f16x8 A1 = *(const f16x8*)(vn + (size_t)rA * D + 32 + quad * 8);
        f32x4 acc[4];
#pragma unroll
        for (int c = 0; c < 4; ++c) acc[c] = (f32x4){0.f, 0.f, 0.f, 0.f};
#pragma unroll
        for (int c = 0; c < 4; ++c) {
            acc[c] = MFMAH(A0, B[0][c], acc[c]);
            acc[c] = MFMAH(A1, B[1][c], acc[c]);
        }
#pragma unroll
        for (int reg = 0; reg < 4; ++reg) {
            int rr = base + quad * 4 + reg;
            if (rr < N) {
#pragma unroll
                for (int c = 0; c < 4; ++c)
                    V2[((size_t)rr * RR + r) * D + c * 16 + m] = (_Float16)acc[c][reg];
            }
        }
    }
}

// ---------------- per-edge scores: k fp16 (128B), A split-fp16, q fp16 (128B) ----------------
__global__ void score_kernel(const int* __restrict__ rsrc, const int* __restrict__ rdst,
                             const int* __restrict__ rdpos, const int* __restrict__ roff,
                             const _Float16* __restrict__ kh16,
                             const _Float16* __restrict__ qn, const float* __restrict__ Aatt,
                             const float* __restrict__ pri, int2* __restrict__ rec) {
    const int r = blockIdx.y, lane = threadIdx.x;
    const int beg = roff[r], end = roff[r + 1], cnt = end - beg;
    if (cnt <= 0) return;
    const int nstrips = (cnt + 15) >> 4;
    const int m = lane & 15, quad = lane >> 4;
    const float scale = pri[r] * 0.125f;
    const float* W = Aatt + (size_t)r * 4096;

    f16x8 Bh[2][4], Bl[2][4];
#pragma unroll
    for (int ks = 0; ks < 2; ++ks)
#pragma unroll
        for (int c = 0; c < 4; ++c) load_B_split_f16(W, ks, c, lane, Bh[ks][c], Bl[ks][c]);

    for (int st = blockIdx.x; st < nstrips; st += gridDim.x) {
        int base = st * 16;
        int ia = base + m; if (ia > cnt - 1) ia = cnt - 1;
        int s = rsrc[beg + ia];
        const _Float16* kr = kh16 + (size_t)s * D;   // 128B row
        f16x8 A0 = *(const f16x8*)(kr + quad * 8);
        f16x8 A1 = *(const f16x8*)(kr + 32 + quad * 8);
        f32x4 acc[4];
#pragma unroll
        for (int c = 0; c < 4; ++c) acc[c] = (f32x4){0.f, 0.f, 0.f, 0.f};
#pragma unroll
        for (int c = 0; c < 4; ++c) {
            acc[c] = MFMAH(A0, Bh[0][c], acc[c]);
            acc[c] = MFMAH(A0, Bl[0][c], acc[c]);
            acc[c] = MFMAH(A1, Bh[1][c], acc[c]);
            acc[c] = MFMAH(A1, Bl[1][c], acc[c]);
        }

        float p4[4];
#pragma unroll
        for (int reg = 0; reg < 4; ++reg) {
            int ie = base + quad * 4 + reg; if (ie > cnt - 1) ie = cnt - 1;
            const _Float16* qp = qn + (size_t)rdst[beg + ie] * D + m;
            float pr = acc[0][reg] * (float)qp[0] + acc[1][reg] * (float)qp[16]
                     + acc[2][reg] * (float)qp[32] + acc[3][reg] * (float)qp[48];
#pragma unroll
            for (int d = 8; d; d >>= 1) pr += __shfl_xor(pr, d, 64);
            p4[reg] = pr;
        }
        if (m < 4) {
            int idx = base + quad * 4 + m;
            if (idx < cnt) {
                float v = (m == 0) ? p4[0] : (m == 1) ? p4[1] : (m == 2) ? p4[2] : p4[3];
                int sagain = rsrc[beg + idx];
                int2 rc;
                rc.x = __float_as_int(v * scale);
                rc.y = (sagain << 3) | r;                     // V2 row id
                rec[rdpos[beg + idx]] = rc;
            }
        }
    }
}

// ---------------- per-dst softmax + aggregation: one 16-lane quad per node ----------------
__global__ void agg_kernel(const int* __restrict__ offs, const int2* __restrict__ rec,
                           const _Float16* __restrict__ V2,
                           float* __restrict__ agg, int N) {
    const int lane = threadIdx.x & 63;
    const int wv = threadIdx.x >> 6;         // 4 waves/block
    const int quad = lane >> 4, ql = lane & 15;
    const int i = blockIdx.x * 16 + wv * 4 + quad;
    if (i >= N) return;
    const int beg = offs[i], end = offs[i + 1];
    const int qb = quad << 4;
    float mmax = -INFINITY, lsum = 0.f;
    float a0 = 0.f, a1 = 0.f, a2 = 0.f, a3 = 0.f;
    for (int cs = beg; cs < end; cs += 16) {
        int cl = end - cs; if (cl > 16) cl = 16;
        // phase 1: 16 lanes = 16 edges
        int2 rc; rc.y = 0;
        float sc = -INFINITY;
        if (ql < cl) { rc = rec[cs + ql]; sc = __int_as_float(rc.x); }
        float cm = sc;
#pragma unroll
        for (int d = 8; d; d >>= 1) cm = fmaxf(cm, __shfl_xor(cm, d, 64));
        float mn = fmaxf(mmax, cm);
        float cf = __expf(mmax - mn);             // 0 on first chunk
        float ex = (ql < cl) ? __expf(sc - mn) : 0.f;
        float csum = ex;
#pragma unroll
        for (int d = 8; d; d >>= 1) csum += __shfl_xor(csum, d, 64);
        lsum = lsum * cf + csum;
        a0 *= cf; a1 *= cf; a2 *= cf; a3 *= cf;
        // phase 2: 16 lanes = 64 dims (4 each); weights/rows broadcast from quad lanes
        for (int e = 0; e < cl; e += 2) {
            float w0 = __shfl(ex, qb + e, 64);
            int   i0 = __shfl(rc.y, qb + e, 64);
            float w1 = __shfl(ex, qb + e + 1, 64);   // 0-weight row if e+1>=cl (lanes init 0)
            int   i1 = __shfl(rc.y, qb + e + 1, 64);
            f16x4 v0 = *(const f16x4*)(V2 + (size_t)i0 * D + ql * 4);
            f16x4 v1 = *(const f16x4*)(V2 + (size_t)i1 * D + ql * 4);
            a0 += w0 * (float)v0[0] + w1 * (float)v1[0];
            a1 += w0 * (float)v0[1] + w1 * (float)v1[1];
            a2 += w0 * (float)v0[2] + w1 * (float)v1[2];
            a3 += w0 * (float)v0[3] + w1 * (float)v1[3];
        }
        mmax = mn;
    }
    float inv = 1.f / (lsum + 1e-16f);
    f32x4 outv = (f32x4){a0 * inv, a1 * inv, a2 * inv, a3 * inv};
    *(f32x4*)(agg + (size_t)i * D + ql * 4) = outv;
}

// ---------------- output transform (split-bf16 MFMA, in place on d_out) ----------------
__global__ void out_kernel(float* __restrict__ io, const float* __restrict__ Wa,
                           const float* __restrict__ skip,
                           const int* __restrict__ toff, const int* __restrict__ nidx) {
    const int t = blockIdx.y, lane = threadIdx.x;
    const int beg = toff[t], end = toff[t + 1], cnt = end - beg;
    if (cnt <= 0) return;
    const int nstrips = (cnt + 15) >> 4;
    const float* W = Wa + (size_t)t * 4096;
    const float sg = 1.f / (1.f + __expf(-skip[t]));
    const int m = lane & 15, quad = lane >> 4;

    bf16x8 Bh[2][4], Bl[2][4];
#pragma unroll
    for (int ks = 0; ks < 2; ++ks)
#pragma unroll
        for (int c = 0; c < 4; ++c) load_B_split(W, ks, c, lane, Bh[ks][c], Bl[ks][c]);

    for (int s = blockIdx.x; s < nstrips; s += gridDim.x) {
        int base = beg + s * 16;
        int rA = base + m; if (rA > end - 1) rA = end - 1;
        const float* ap = io + (size_t)nidx[rA] * D;
        bf16x8 A0h, A0l, A1h, A1l;
        load_A_split(ap + quad * 8, A0h, A0l);
        load_A_split(ap + 32 + quad * 8, A1h, A1l);
        f32x4 acc[4];
#pragma unroll
        for (int c = 0; c < 4; ++c) acc[c] = (f32x4){0.f, 0.f, 0.f, 0.f};
        SPLIT_MFMA_BODY(acc, A0h, A0l, A1h, A1l, Bh, Bl)
#pragma unroll
        for (int reg = 0; reg < 4; ++reg) {
            int rr = base + quad * 4 + reg;
            if (rr < end) {
                size_t nb = (size_t)nidx[rr] * D;
#pragma unroll
                for (int c = 0; c < 4; ++c)
                    io[nb + c * 16 + m] = acc[c][reg] * sg;
            }
        }
    }
}

// ---------------- launch ----------------
extern "C" void kernel_launch(void* const* d_in, const int* in_sizes, int n_in,
                              void* d_out, int out_size, void* d_ws, size_t ws_size,
                              hipStream_t stream) {
    const float* h     = (const float*)d_in[0];
    const int*   adj   = (const int*)d_in[1];     // [2,E]: src row then dst row
    const int*   etype = (const int*)d_in[2];
    const int*   ntype = (const int*)d_in[3];
    const float* Wk    = (const float*)d_in[6];
    const float* Wq    = (const float*)d_in[7];
    const float* Wv    = (const float*)d_in[8];
    const float* Wa    = (const float*)d_in[9];
    const float* pri   = (const float*)d_in[10];
    const float* Aatt  = (const float*)d_in[11];
    const float* Amsg  = (const float*)d_in[12];
    const float* skp   = (const float*)d_in[13];
    const int N = in_sizes[3];
    const int E = in_sizes[2];
    float* out = (float*)d_out;

    char* w = (char*)d_ws;
    auto alloc = [&](size_t b) { char* p = w; w += (b + 255) & ~(size_t)255; return p; };
    _Float16* kh16 = (_Float16*)alloc((size_t)N * D * 2);
    _Float16* qn   = (_Float16*)alloc((size_t)N * D * 2);
    _Float16* vn   = (_Float16*)alloc((size_t)N * D * 2);
    _Float16* V2   = (_Float16*)alloc((size_t)N * RR * D * 2);
    int* deg  = (int*)alloc((size_t)(N + 16) * 4);
    int* tcnt = deg + N;
    int* rcnt = deg + N + 8;
    int* offs = (int*)alloc((size_t)(N + 1) * 4);
    int* erank = (int*)alloc((size_t)E * 4);
    int* toff = (int*)alloc(64);
    int* tcur = (int*)alloc(64);
    int* roff = (int*)alloc(64);
    int* rcur = (int*)alloc(64);
    int2* rec = (int2*)alloc((size_t)E * 8);
    int* rsrc  = (int*)alloc((size_t)E * 4);
    int* rdst  = (int*)alloc((size_t)E * 4);
    int* rdpos = (int*)alloc((size_t)E * 4);
    int* nidx  = (int*)alloc((size_t)N * 4);
    const int nsb = (N + SCAN_ELEMS - 1) / SCAN_ELEMS;
    int* bsum  = (int*)alloc((size_t)nsb * 4);
    int* bbase = (int*)alloc((size_t)nsb * 4);

    (void)hipMemsetAsync(deg, 0, (size_t)(N + 16) * 4, stream);

    const int mx = (E > N ? E : N);
    const int histBlocks = (mx + 256 * HIST_CH - 1) / (256 * HIST_CH);
    hist_kernel<<<histBlocks, 256, 0, stream>>>(adj + E, etype, ntype, deg, tcnt, rcnt, erank, N, E);
    scan_sum_kernel<<<nsb, SCAN_TPB, 0, stream>>>(deg, bsum, N);
    scan_mid_kernel<<<1, 64, 0, stream>>>(bsum, bbase, nsb, tcnt, toff, tcur, rcnt, roff, rcur);
    scan_out_kernel<<<nsb, SCAN_TPB, 0, stream>>>(deg, bbase, offs, N, E);
    scatter_kernel<<<(mx + 255) / 256, 256, 0, stream>>>(adj, adj + E, etype, ntype,
                                                         offs, erank, tcur, rcur,
                                                         rsrc, rdst, rdpos, nidx, N, E);
    proj_kernel<<<dim3(128, 3, TT), 64, 0, stream>>>(h, Wk, Wq, Wv, toff, nidx, kh16, qn, vn);
    v2_kernel<<<dim3(256, RR), 64, 0, stream>>>(vn, Amsg, V2, N);
    score_kernel<<<dim3(512, RR), 64, 0, stream>>>(rsrc, rdst, rdpos, roff, kh16, qn, Aatt, pri, rec);
    agg_kernel<<<(N + 15) / 16, 256, 0, stream>>>(offs, rec, V2, out, N);
    out_kernel<<<dim3(128, TT), 64, 0, stream>>>(out, Wa, skp, toff, nidx);
}

// Round 11
// 262.747 us; speedup vs baseline: 25.0076x; 1.1244x over previous
//
#include <hip/hip_runtime.h>
#include <math.h>

typedef float f32x4 __attribute__((ext_vector_type(4)));
typedef short bf16x8 __attribute__((ext_vector_type(8)));
typedef _Float16 f16x8 __attribute__((ext_vector_type(8)));
typedef _Float16 f16x4 __attribute__((ext_vector_type(4)));

#define D 64
#define TT 8
#define RR 8

#define SCAN_TPB 256
#define SCAN_CH 4
#define SCAN_ELEMS (SCAN_TPB * SCAN_CH)   // 1024 elements per block

#define HIST_CH 8                          // edges per thread (outstanding atomics)
#define SCAT_CH 4
#define SCORE_BX 1024                      // score x-blocks; v2 rides above this

// ---------------- scalar helpers ----------------
__device__ __forceinline__ float bf2f(unsigned short u) {
    union { unsigned int i; float f; } x;
    x.i = ((unsigned int)u) << 16;
    return x.f;
}
__device__ __forceinline__ unsigned short f2bf(float f) {
    union { float f; unsigned int i; } x;
    x.f = f;
    unsigned int i = x.i;
    unsigned int r = (i + 0x7FFFu + ((i >> 16) & 1u)) >> 16;   // RNE
    return (unsigned short)r;
}
struct BfPair { short hi; short lo; };
__device__ __forceinline__ BfPair split2(float x) {
    BfPair p;
    unsigned short h = f2bf(x);
    p.hi = (short)h;
    p.lo = (short)f2bf(x - bf2f(h));
    return p;
}
__device__ __forceinline__ void load_A_split(const float* __restrict__ p, bf16x8& ah, bf16x8& al) {
#pragma unroll
    for (int i = 0; i < 8; ++i) {
        BfPair s = split2(p[i]);
        ah[i] = s.hi; al[i] = s.lo;
    }
}
// bf16 split B fragment (used by proj/out split GEMMs)
__device__ __forceinline__ void load_B_split(const float* __restrict__ W, int ks, int c, int lane,
                                             bf16x8& bh, bf16x8& bl) {
    int n = lane & 15, q = lane >> 4;
#pragma unroll
    for (int i = 0; i < 8; ++i) {
        BfPair s = split2(W[(ks * 32 + q * 8 + i) * 64 + c * 16 + n]);
        bh[i] = s.hi; bl[i] = s.lo;
    }
}
// fp16 split B fragment (score: A-matrix hi+lo)
__device__ __forceinline__ void load_B_split_f16(const float* __restrict__ W, int ks, int c, int lane,
                                                 f16x8& bh, f16x8& bl) {
    int n = lane & 15, q = lane >> 4;
#pragma unroll
    for (int i = 0; i < 8; ++i) {
        float w = W[(ks * 32 + q * 8 + i) * 64 + c * 16 + n];
        _Float16 h = (_Float16)w;
        bh[i] = h;
        bl[i] = (_Float16)(w - (float)h);
    }
}
// fp16 single B fragment (V2 build)
__device__ __forceinline__ f16x8 load_B_frag_f16(const float* __restrict__ W, int ks, int c, int lane) {
    int n = lane & 15, q = lane >> 4;
    f16x8 r;
#pragma unroll
    for (int i = 0; i < 8; ++i)
        r[i] = (_Float16)W[(ks * 32 + q * 8 + i) * 64 + c * 16 + n];
    return r;
}

#define MFMA16(a, b, c) __builtin_amdgcn_mfma_f32_16x16x32_bf16(a, b, c, 0, 0, 0)
#define MFMAH(a, b, c)  __builtin_amdgcn_mfma_f32_16x16x32_f16(a, b, c, 0, 0, 0)

// 24 bf16 MFMAs: acc += (Ah+Al)@(Bh+Bl) dropping lo*lo
#define SPLIT_MFMA_BODY(acc, A0h, A0l, A1h, A1l, Bh, Bl)          \
    _Pragma("unroll")                                             \
    for (int c = 0; c < 4; ++c) {                                 \
        acc[c] = MFMA16(A0h, Bh[0][c], acc[c]);                   \
        acc[c] = MFMA16(A0l, Bh[0][c], acc[c]);                   \
        acc[c] = MFMA16(A0h, Bl[0][c], acc[c]);                   \
        acc[c] = MFMA16(A1h, Bh[1][c], acc[c]);                   \
        acc[c] = MFMA16(A1l, Bh[1][c], acc[c]);                   \
        acc[c] = MFMA16(A1h, Bl[1][c], acc[c]);                   \
    }

// ---------------- CSR build ----------------
// 8 grid-strided edges/thread -> 8 independent returning atomics in flight per lane.
__global__ void hist_kernel(const int* __restrict__ dst, const int* __restrict__ et,
                            const int* __restrict__ nt,
                            int* __restrict__ deg, int* __restrict__ tcnt, int* __restrict__ rcnt,
                            int* __restrict__ erank, int N, int E) {
    __shared__ int l_r[RR], l_t[TT];
    if (threadIdx.x < RR) l_r[threadIdx.x] = 0;
    if (threadIdx.x < TT) l_t[threadIdx.x] = 0;
    __syncthreads();
    const int stride = gridDim.x * blockDim.x;
    const int tid = blockIdx.x * blockDim.x + threadIdx.x;
#pragma unroll
    for (int i = 0; i < HIST_CH; ++i) {
        int e = tid + i * stride;
        if (e < E) {
            erank[e] = atomicAdd(&deg[dst[e]], 1);
            atomicAdd(&l_r[et[e]], 1);
        }
    }
#pragma unroll
    for (int i = 0; i < HIST_CH; ++i) {
        int n = tid + i * stride;
        if (n < N) atomicAdd(&l_t[nt[n]], 1);
    }
    __syncthreads();
    if (threadIdx.x < RR && l_r[threadIdx.x]) atomicAdd(&rcnt[threadIdx.x], l_r[threadIdx.x]);
    if (threadIdx.x < TT && l_t[threadIdx.x]) atomicAdd(&tcnt[threadIdx.x], l_t[threadIdx.x]);
}

// ---- 2-phase device-wide exclusive scan of deg[0..N) ----
__global__ void scan_sum_kernel(const int* __restrict__ deg, int* __restrict__ bsum, int N) {
    __shared__ int ws[SCAN_TPB / 64];
    int tid = threadIdx.x;
    int base = blockIdx.x * SCAN_ELEMS + tid * SCAN_CH;
    int s = 0;
#pragma unroll
    for (int i = 0; i < SCAN_CH; ++i) {
        int idx = base + i;
        if (idx < N) s += deg[idx];
    }
#pragma unroll
    for (int d = 32; d; d >>= 1) s += __shfl_xor(s, d, 64);
    if ((tid & 63) == 0) ws[tid >> 6] = s;
    __syncthreads();
    if (tid == 0) {
        int t = 0;
#pragma unroll
        for (int i = 0; i < SCAN_TPB / 64; ++i) t += ws[i];
        bsum[blockIdx.x] = t;
    }
}
// scan_out also does the former scan_mid work: per-block bbase via wave prefix of bsum,
// and block 0 writes toff/tcur/roff/rcur.
__global__ void scan_out_kernel(const int* __restrict__ deg, const int* __restrict__ bsum, int nsb,
                                int* __restrict__ off, int N, int Etot,
                                const int* __restrict__ tcnt, int* __restrict__ toff, int* __restrict__ tcur,
                                const int* __restrict__ rcnt, int* __restrict__ roff, int* __restrict__ rcur) {
    __shared__ int ts[SCAN_TPB];
    __shared__ int bb;
    int tid = threadIdx.x;
    if (tid < 64) {
        int v = 0;
        // nsb <= 64 expected (N <= 65536); fallback serial otherwise
        if (nsb <= 64) {
            v = (tid < nsb && tid < blockIdx.x) ? bsum[tid] : 0;
#pragma unroll
            for (int d = 32; d; d >>= 1) v += __shfl_xor(v, d, 64);
        } else if (tid == 0) {
            for (int b = 0; b < blockIdx.x; ++b) v += bsum[b];
        }
        if (tid == 0) bb = v;
    }
    if (blockIdx.x == 0 && tid == 1) {
        int a = 0;
        for (int t = 0; t < TT; ++t) { toff[t] = a; tcur[t] = a; a += tcnt[t]; }
        toff[TT] = a;
        int b2 = 0;
        for (int r = 0; r < RR; ++r) { roff[r] = b2; rcur[r] = b2; b2 += rcnt[r]; }
        roff[RR] = b2;
        off[N] = Etot;
    }
    int base = blockIdx.x * SCAN_ELEMS + tid * SCAN_CH;
    int loc[SCAN_CH];
    int s = 0;
#pragma unroll
    for (int i = 0; i < SCAN_CH; ++i) {
        int idx = base + i;
        int v = (idx < N) ? deg[idx] : 0;
        loc[i] = v; s += v;
    }
    ts[tid] = s;
    __syncthreads();
    for (int sh = 1; sh < SCAN_TPB; sh <<= 1) {
        int v = (tid >= sh) ? ts[tid - sh] : 0;
        __syncthreads();
        ts[tid] += v;
        __syncthreads();
    }
    int run = bb + ((tid > 0) ? ts[tid - 1] : 0);
#pragma unroll
    for (int i = 0; i < SCAN_CH; ++i) {
        int idx = base + i;
        if (idx < N) { off[idx] = run; run += loc[i]; }
    }
}

// scatter: pos = offs[d] + erank[e] (no per-edge global atomics); 4 grid-strided items/thread.
__global__ void scatter_kernel(const int* __restrict__ src, const int* __restrict__ dst,
                               const int* __restrict__ et, const int* __restrict__ nt,
                               const int* __restrict__ offs, const int* __restrict__ erank,
                               int* __restrict__ tcur, int* __restrict__ rcur,
                               int* __restrict__ rsrc, int* __restrict__ rdst,
                               int* __restrict__ rdpos, int* __restrict__ nidx, int N, int E) {
    __shared__ int l_r[RR], l_t[TT], base_r[RR], base_t[TT];
    if (threadIdx.x < RR) l_r[threadIdx.x] = 0;
    if (threadIdx.x < TT) l_t[threadIdx.x] = 0;
    __syncthreads();
    const int stride = gridDim.x * blockDim.x;
    const int tid = blockIdx.x * blockDim.x + threadIdx.x;
    int s[SCAT_CH], d[SCAT_CH], r[SCAT_CH], rrank[SCAT_CH];
    int t[SCAT_CH], trank[SCAT_CH];
#pragma unroll
    for (int i = 0; i < SCAT_CH; ++i) {
        int e = tid + i * stride;
        if (e < E) {
            s[i] = src[e]; d[i] = dst[e]; r[i] = et[e];
            rrank[i] = atomicAdd(&l_r[r[i]], 1);
        }
        int n = tid + i * stride;
        if (n < N) {
            t[i] = nt[n];
            trank[i] = atomicAdd(&l_t[t[i]], 1);
        }
    }
    __syncthreads();
    if (threadIdx.x < RR)
        base_r[threadIdx.x] = l_r[threadIdx.x] ? atomicAdd(&rcur[threadIdx.x], l_r[threadIdx.x]) : 0;
    if (threadIdx.x < TT)
        base_t[threadIdx.x] = l_t[threadIdx.x] ? atomicAdd(&tcur[threadIdx.x], l_t[threadIdx.x]) : 0;
    __syncthreads();
#pragma unroll
    for (int i = 0; i < SCAT_CH; ++i) {
        int e = tid + i * stride;
        if (e < E) {
            int pos = offs[d[i]] + erank[e];
            int rp = base_r[r[i]] + rrank[i];
            rsrc[rp] = s[i]; rdst[rp] = d[i]; rdpos[rp] = pos;
        }
        int n = tid + i * stride;
        if (n < N) nidx[base_t[t[i]] + trank[i]] = n;
    }
}

// ---------------- node projections ----------------
// a=0: k -> fp16 row (128B); a=1: q -> fp16 row (128B); a=2: v fp16.
// GEMMs internally split-bf16 accurate; only final store rounds to fp16.
__global__ void proj_kernel(const float* __restrict__ h,
                            const float* __restrict__ Wk, const float* __restrict__ Wq,
                            const float* __restrict__ Wv,
                            const int* __restrict__ toff, const int* __restrict__ nidx,
                            _Float16* __restrict__ kh16,
                            _Float16* __restrict__ qout, _Float16* __restrict__ vout) {
    const int t = blockIdx.z, a = blockIdx.y, lane = threadIdx.x;
    const int beg = toff[t], end = toff[t + 1], cnt = end - beg;
    if (cnt <= 0) return;
    const int nstrips = (cnt + 15) >> 4;
    const float* W = (a == 0 ? Wk : (a == 1 ? Wq : Wv)) + (size_t)t * 4096;
    const int m = lane & 15, quad = lane >> 4;

    bf16x8 Bh[2][4], Bl[2][4];
#pragma unroll
    for (int ks = 0; ks < 2; ++ks)
#pragma unroll
        for (int c = 0; c < 4; ++c) load_B_split(W, ks, c, lane, Bh[ks][c], Bl[ks][c]);

    _Float16* out = (a == 0) ? kh16 : (a == 1 ? qout : vout);

    for (int s = blockIdx.x; s < nstrips; s += gridDim.x) {
        int base = beg + s * 16;
        int rA = base + m; if (rA > end - 1) rA = end - 1;
        const float* hp = h + (size_t)nidx[rA] * D;
        bf16x8 A0h, A0l, A1h, A1l;
        load_A_split(hp + quad * 8, A0h, A0l);
        load_A_split(hp + 32 + quad * 8, A1h, A1l);
        f32x4 acc[4];
#pragma unroll
        for (int c = 0; c < 4; ++c) acc[c] = (f32x4){0.f, 0.f, 0.f, 0.f};
        SPLIT_MFMA_BODY(acc, A0h, A0l, A1h, A1l, Bh, Bl)
#pragma unroll
        for (int reg = 0; reg < 4; ++reg) {
            int rr = base + quad * 4 + reg;
            if (rr < end) {
                int nid = nidx[rr];
#pragma unroll
                for (int c = 0; c < 4; ++c)
                    out[(size_t)nid * D + c * 16 + m] = (_Float16)acc[c][reg];
            }
        }
    }
}

// ---------------- fused: per-edge scores (x < SCORE_BX) + V2 build (x >= SCORE_BX) ----------------
// score: k fp16 (128B), A split-fp16, q fp16 (128B). v2: V2[n][r] = v_node[n] @ M[r] (fp16).
__global__ void score_v2_kernel(const int* __restrict__ rsrc, const int* __restrict__ rdst,
                                const int* __restrict__ rdpos, const int* __restrict__ roff,
                                const _Float16* __restrict__ kh16,
                                const _Float16* __restrict__ qn, const float* __restrict__ Aatt,
                                const float* __restrict__ pri, int2* __restrict__ rec,
                                const _Float16* __restrict__ vn, const float* __restrict__ Amsg,
                                _Float16* __restrict__ V2, int N) {
    const int r = blockIdx.y, lane = threadIdx.x;
    const int m = lane & 15, quad = lane >> 4;

    if (blockIdx.x >= SCORE_BX) {
        // ---------------- V2 part ----------------
        const int bx = blockIdx.x - SCORE_BX;
        const int gx = gridDim.x - SCORE_BX;
        const int nstrips = (N + 15) >> 4;
        const float* W = Amsg + (size_t)r * 4096;
        f16x8 B[2][4];
#pragma unroll
        for (int ks = 0; ks < 2; ++ks)
#pragma unroll
            for (int c = 0; c < 4; ++c) B[ks][c] = load_B_frag_f16(W, ks, c, lane);

        for (int s = bx; s < nstrips; s += gx) {
            int base = s * 16;
            int rA = base + m; if (rA > N - 1) rA = N - 1;
            f16x8 A0 = *(const f16x8*)(vn + (size_t)rA * D + quad * 8);
            f16x8 A1 = *(const f16x8*)(vn + (size_t)rA * D + 32 + quad * 8);
            f32x4 acc[4];
#pragma unroll
            for (int c = 0; c < 4; ++c) acc[c] = (f32x4){0.f, 0.f, 0.f, 0.f};
#pragma unroll
            for (int c = 0; c < 4; ++c) {
                acc[c] = MFMAH(A0, B[0][c], acc[c]);
                acc[c] = MFMAH(A1, B[1][c], acc[c]);
            }
#pragma unroll
            for (int reg = 0; reg < 4; ++reg) {
                int rr = base + quad * 4 + reg;
                if (rr < N) {
#pragma unroll
                    for (int c = 0; c < 4; ++c)
                        V2[((size_t)rr * RR + r) * D + c * 16 + m] = (_Float16)acc[c][reg];
                }
            }
        }
        return;
    }

    // ---------------- score part ----------------
    const int beg = roff[r], end = roff[r + 1], cnt = end - beg;
    if (cnt <= 0) return;
    const int nstrips = (cnt + 15) >> 4;
    const float scale = pri[r] * 0.125f;
    const float* W = Aatt + (size_t)r * 4096;

    f16x8 Bh[2][4], Bl[2][4];
#pragma unroll
    for (int ks = 0; ks < 2; ++ks)
#pragma unroll
        for (int c = 0; c < 4; ++c) load_B_split_f16(W, ks, c, lane, Bh[ks][c], Bl[ks][c]);

    for (int st = blockIdx.x; st < nstrips; st += SCORE_BX) {
        int base = st * 16;
        int ia = base + m; if (ia > cnt - 1) ia = cnt - 1;
        int s = rsrc[beg + ia];
        const _Float16* kr = kh16 + (size_t)s * D;   // 128B row
        f16x8 A0 = *(const f16x8*)(kr + quad * 8);
        f16x8 A1 = *(const f16x8*)(kr + 32 + quad * 8);
        f32x4 acc[4];
#pragma unroll
        for (int c = 0; c < 4; ++c) acc[c] = (f32x4){0.f, 0.f, 0.f, 0.f};
#pragma unroll
        for (int c = 0; c < 4; ++c) {
            acc[c] = MFMAH(A0, Bh[0][c], acc[c]);
            acc[c] = MFMAH(A0, Bl[0][c], acc[c]);
            acc[c] = MFMAH(A1, Bh[1][c], acc[c]);
            acc[c] = MFMAH(A1, Bl[1][c], acc[c]);
        }

        float p4[4];
#pragma unroll
        for (int reg = 0; reg < 4; ++reg) {
            int ie = base + quad * 4 + reg; if (ie > cnt - 1) ie = cnt - 1;
            const _Float16* qp = qn + (size_t)rdst[beg + ie] * D + m;
            float pr = acc[0][reg] * (float)qp[0] + acc[1][reg] * (float)qp[16]
                     + acc[2][reg] * (float)qp[32] + acc[3][reg] * (float)qp[48];
#pragma unroll
            for (int d = 8; d; d >>= 1) pr += __shfl_xor(pr, d, 64);
            p4[reg] = pr;
        }
        if (m < 4) {
            int idx = base + quad * 4 + m;
            if (idx < cnt) {
                float v = (m == 0) ? p4[0] : (m == 1) ? p4[1] : (m == 2) ? p4[2] : p4[3];
                int sagain = rsrc[beg + idx];
                int2 rc;
                rc.x = __float_as_int(v * scale);
                rc.y = (sagain << 3) | r;                     // V2 row id
                rec[rdpos[beg + idx]] = rc;
            }
        }
    }
}

// ---------------- per-dst softmax + aggregation: one 16-lane quad per node ----------------
__global__ void agg_kernel(const int* __restrict__ offs, const int2* __restrict__ rec,
                           const _Float16* __restrict__ V2,
                           float* __restrict__ agg, int N) {
    const int lane = threadIdx.x & 63;
    const int wv = threadIdx.x >> 6;         // 4 waves/block
    const int quad = lane >> 4, ql = lane & 15;
    const int i = blockIdx.x * 16 + wv * 4 + quad;
    if (i >= N) return;
    const int beg = offs[i], end = offs[i + 1];
    const int qb = quad << 4;
    float mmax = -INFINITY, lsum = 0.f;
    float a0 = 0.f, a1 = 0.f, a2 = 0.f, a3 = 0.f;
    for (int cs = beg; cs < end; cs += 16) {
        int cl = end - cs; if (cl > 16) cl = 16;
        // phase 1: 16 lanes = 16 edges
        int2 rc; rc.y = 0;
        float sc = -INFINITY;
        if (ql < cl) { rc = rec[cs + ql]; sc = __int_as_float(rc.x); }
        float cm = sc;
#pragma unroll
        for (int d = 8; d; d >>= 1) cm = fmaxf(cm, __shfl_xor(cm, d, 64));
        float mn = fmaxf(mmax, cm);
        float cf = __expf(mmax - mn);             // 0 on first chunk
        float ex = (ql < cl) ? __expf(sc - mn) : 0.f;
        float csum = ex;
#pragma unroll
        for (int d = 8; d; d >>= 1) csum += __shfl_xor(csum, d, 64);
        lsum = lsum * cf + csum;
        a0 *= cf; a1 *= cf; a2 *= cf; a3 *= cf;
        // phase 2: 16 lanes = 64 dims (4 each); 4 independent gathers per iter.
        // lanes with e >= cl have ex==0 (w=0) and rc.y==0 (harmless row-0 load).
        for (int e = 0; e < cl; e += 4) {
            float w0 = __shfl(ex, qb + e, 64),     w1 = __shfl(ex, qb + e + 1, 64);
            float w2 = __shfl(ex, qb + e + 2, 64), w3 = __shfl(ex, qb + e + 3, 64);
            int   i0 = __shfl(rc.y, qb + e, 64),     i1 = __shfl(rc.y, qb + e + 1, 64);
            int   i2 = __shfl(rc.y, qb + e + 2, 64), i3 = __shfl(rc.y, qb + e + 3, 64);
            f16x4 v0 = *(const f16x4*)(V2 + (size_t)i0 * D + ql * 4);
            f16x4 v1 = *(const f16x4*)(V2 + (size_t)i1 * D + ql * 4);
            f16x4 v2 = *(const f16x4*)(V2 + (size_t)i2 * D + ql * 4);
            f16x4 v3 = *(const f16x4*)(V2 + (size_t)i3 * D + ql * 4);
            a0 += w0 * (float)v0[0] + w1 * (float)v1[0] + w2 * (float)v2[0] + w3 * (float)v3[0];
            a1 += w0 * (float)v0[1] + w1 * (float)v1[1] + w2 * (float)v2[1] + w3 * (float)v3[1];
            a2 += w0 * (float)v0[2] + w1 * (float)v1[2] + w2 * (float)v2[2] + w3 * (float)v3[2];
            a3 += w0 * (float)v0[3] + w1 * (float)v1[3] + w2 * (float)v2[3] + w3 * (float)v3[3];
        }
        mmax = mn;
    }
    float inv = 1.f / (lsum + 1e-16f);
    f32x4 outv = (f32x4){a0 * inv, a1 * inv, a2 * inv, a3 * inv};
    *(f32x4*)(agg + (size_t)i * D + ql * 4) = outv;
}

// ---------------- output transform (split-bf16 MFMA, in place on d_out) ----------------
__global__ void out_kernel(float* __restrict__ io, const float* __restrict__ Wa,
                           const float* __restrict__ skip,
                           const int* __restrict__ toff, const int* __restrict__ nidx) {
    const int t = blockIdx.y, lane = threadIdx.x;
    const int beg = toff[t], end = toff[t + 1], cnt = end - beg;
    if (cnt <= 0) return;
    const int nstrips = (cnt + 15) >> 4;
    const float* W = Wa + (size_t)t * 4096;
    const float sg = 1.f / (1.f + __expf(-skip[t]));
    const int m = lane & 15, quad = lane >> 4;

    bf16x8 Bh[2][4], Bl[2][4];
#pragma unroll
    for (int ks = 0; ks < 2; ++ks)
#pragma unroll
        for (int c = 0; c < 4; ++c) load_B_split(W, ks, c, lane, Bh[ks][c], Bl[ks][c]);

    for (int s = blockIdx.x; s < nstrips; s += gridDim.x) {
        int base = beg + s * 16;
        int rA = base + m; if (rA > end - 1) rA = end - 1;
        const float* ap = io + (size_t)nidx[rA] * D;
        bf16x8 A0h, A0l, A1h, A1l;
        load_A_split(ap + quad * 8, A0h, A0l);
        load_A_split(ap + 32 + quad * 8, A1h, A1l);
        f32x4 acc[4];
#pragma unroll
        for (int c = 0; c < 4; ++c) acc[c] = (f32x4){0.f, 0.f, 0.f, 0.f};
        SPLIT_MFMA_BODY(acc, A0h, A0l, A1h, A1l, Bh, Bl)
#pragma unroll
        for (int reg = 0; reg < 4; ++reg) {
            int rr = base + quad * 4 + reg;
            if (rr < end) {
                size_t nb = (size_t)nidx[rr] * D;
#pragma unroll
                for (int c = 0; c < 4; ++c)
                    io[nb + c * 16 + m] = acc[c][reg] * sg;
            }
        }
    }
}

// ---------------- launch ----------------
extern "C" void kernel_launch(void* const* d_in, const int* in_sizes, int n_in,
                              void* d_out, int out_size, void* d_ws, size_t ws_size,
                              hipStream_t stream) {
    const float* h     = (const float*)d_in[0];
    const int*   adj   = (const int*)d_in[1];     // [2,E]: src row then dst row
    const int*   etype = (const int*)d_in[2];
    const int*   ntype = (const int*)d_in[3];
    const float* Wk    = (const float*)d_in[6];
    const float* Wq    = (const float*)d_in[7];
    const float* Wv    = (const float*)d_in[8];
    const float* Wa    = (const float*)d_in[9];
    const float* pri   = (const float*)d_in[10];
    const float* Aatt  = (const float*)d_in[11];
    const float* Amsg  = (const float*)d_in[12];
    const float* skp   = (const float*)d_in[13];
    const int N = in_sizes[3];
    const int E = in_sizes[2];
    float* out = (float*)d_out;

    char* w = (char*)d_ws;
    auto alloc = [&](size_t b) { char* p = w; w += (b + 255) & ~(size_t)255; return p; };
    _Float16* kh16 = (_Float16*)alloc((size_t)N * D * 2);
    _Float16* qn   = (_Float16*)alloc((size_t)N * D * 2);
    _Float16* vn   = (_Float16*)alloc((size_t)N * D * 2);
    _Float16* V2   = (_Float16*)alloc((size_t)N * RR * D * 2);
    int* deg  = (int*)alloc((size_t)(N + 16) * 4);
    int* tcnt = deg + N;
    int* rcnt = deg + N + 8;
    int* offs = (int*)alloc((size_t)(N + 1) * 4);
    int* erank = (int*)alloc((size_t)E * 4);
    int* toff = (int*)alloc(64);
    int* tcur = (int*)alloc(64);
    int* roff = (int*)alloc(64);
    int* rcur = (int*)alloc(64);
    int2* rec = (int2*)alloc((size_t)E * 8);
    int* rsrc  = (int*)alloc((size_t)E * 4);
    int* rdst  = (int*)alloc((size_t)E * 4);
    int* rdpos = (int*)alloc((size_t)E * 4);
    int* nidx  = (int*)alloc((size_t)N * 4);
    const int nsb = (N + SCAN_ELEMS - 1) / SCAN_ELEMS;
    int* bsum  = (int*)alloc((size_t)nsb * 4);

    (void)hipMemsetAsync(deg, 0, (size_t)(N + 16) * 4, stream);

    const int mx = (E > N ? E : N);
    const int histBlocks = (mx + 256 * HIST_CH - 1) / (256 * HIST_CH);
    hist_kernel<<<histBlocks, 256, 0, stream>>>(adj + E, etype, ntype, deg, tcnt, rcnt, erank, N, E);
    scan_sum_kernel<<<nsb, SCAN_TPB, 0, stream>>>(deg, bsum, N);
    scan_out_kernel<<<nsb, SCAN_TPB, 0, stream>>>(deg, bsum, nsb, offs, N, E,
                                                  tcnt, toff, tcur, rcnt, roff, rcur);
    const int scatBlocks = (mx + 256 * SCAT_CH - 1) / (256 * SCAT_CH);
    scatter_kernel<<<scatBlocks, 256, 0, stream>>>(adj, adj + E, etype, ntype,
                                                   offs, erank, tcur, rcur,
                                                   rsrc, rdst, rdpos, nidx, N, E);
    proj_kernel<<<dim3(128, 3, TT), 64, 0, stream>>>(h, Wk, Wq, Wv, toff, nidx, kh16, qn, vn);
    score_v2_kernel<<<dim3(SCORE_BX + 256, RR), 64, 0, stream>>>(rsrc, rdst, rdpos, roff,
                                                                 kh16, qn, Aatt, pri, rec,
                                                                 vn, Amsg, V2, N);
    agg_kernel<<<(N + 15) / 16, 256, 0, stream>>>(offs, rec, V2, out, N);
    out_kernel<<<dim3(128, TT), 64, 0, stream>>>(out, Wa, skp, toff, nidx);
}

// Round 12
// 257.741 us; speedup vs baseline: 25.4934x; 1.0194x over previous
//
#include <hip/hip_runtime.h>
#include <math.h>

typedef float f32x4 __attribute__((ext_vector_type(4)));
typedef short bf16x8 __attribute__((ext_vector_type(8)));
typedef _Float16 f16x8 __attribute__((ext_vector_type(8)));
typedef _Float16 f16x4 __attribute__((ext_vector_type(4)));

#define D 64
#define TT 8
#define RR 8

#define SCAN_TPB 256
#define SCAN_CH 4
#define SCAN_ELEMS (SCAN_TPB * SCAN_CH)   // 1024 elements per block

#define HIST_CH 8                          // edges per thread (outstanding atomics)
#define SCAT_CH 4
#define SCORE_XB 256                       // score x-blocks (x4 waves = 1024 wave slots, stride 1024)
#define V2_XB 64                           // v2 x-blocks (x4 waves = 256 wave slots, stride 256)
#define AGG_XB 256                         // agg_out x-blocks per type

// ---------------- scalar helpers ----------------
__device__ __forceinline__ float bf2f(unsigned short u) {
    union { unsigned int i; float f; } x;
    x.i = ((unsigned int)u) << 16;
    return x.f;
}
__device__ __forceinline__ unsigned short f2bf(float f) {
    union { float f; unsigned int i; } x;
    x.f = f;
    unsigned int i = x.i;
    unsigned int r = (i + 0x7FFFu + ((i >> 16) & 1u)) >> 16;   // RNE
    return (unsigned short)r;
}
struct BfPair { short hi; short lo; };
__device__ __forceinline__ BfPair split2(float x) {
    BfPair p;
    unsigned short h = f2bf(x);
    p.hi = (short)h;
    p.lo = (short)f2bf(x - bf2f(h));
    return p;
}
__device__ __forceinline__ void load_A_split(const float* __restrict__ p, bf16x8& ah, bf16x8& al) {
#pragma unroll
    for (int i = 0; i < 8; ++i) {
        BfPair s = split2(p[i]);
        ah[i] = s.hi; al[i] = s.lo;
    }
}
// bf16 split B fragment (used by proj/out split GEMMs)
__device__ __forceinline__ void load_B_split(const float* __restrict__ W, int ks, int c, int lane,
                                             bf16x8& bh, bf16x8& bl) {
    int n = lane & 15, q = lane >> 4;
#pragma unroll
    for (int i = 0; i < 8; ++i) {
        BfPair s = split2(W[(ks * 32 + q * 8 + i) * 64 + c * 16 + n]);
        bh[i] = s.hi; bl[i] = s.lo;
    }
}
// fp16 split B fragment (score: A-matrix hi+lo)
__device__ __forceinline__ void load_B_split_f16(const float* __restrict__ W, int ks, int c, int lane,
                                                 f16x8& bh, f16x8& bl) {
    int n = lane & 15, q = lane >> 4;
#pragma unroll
    for (int i = 0; i < 8; ++i) {
        float w = W[(ks * 32 + q * 8 + i) * 64 + c * 16 + n];
        _Float16 h = (_Float16)w;
        bh[i] = h;
        bl[i] = (_Float16)(w - (float)h);
    }
}
// fp16 single B fragment (V2 build)
__device__ __forceinline__ f16x8 load_B_frag_f16(const float* __restrict__ W, int ks, int c, int lane) {
    int n = lane & 15, q = lane >> 4;
    f16x8 r;
#pragma unroll
    for (int i = 0; i < 8; ++i)
        r[i] = (_Float16)W[(ks * 32 + q * 8 + i) * 64 + c * 16 + n];
    return r;
}

#define MFMA16(a, b, c) __builtin_amdgcn_mfma_f32_16x16x32_bf16(a, b, c, 0, 0, 0)
#define MFMAH(a, b, c)  __builtin_amdgcn_mfma_f32_16x16x32_f16(a, b, c, 0, 0, 0)

// 24 bf16 MFMAs: acc += (Ah+Al)@(Bh+Bl) dropping lo*lo
#define SPLIT_MFMA_BODY(acc, A0h, A0l, A1h, A1l, Bh, Bl)          \
    _Pragma("unroll")                                             \
    for (int c = 0; c < 4; ++c) {                                 \
        acc[c] = MFMA16(A0h, Bh[0][c], acc[c]);                   \
        acc[c] = MFMA16(A0l, Bh[0][c], acc[c]);                   \
        acc[c] = MFMA16(A0h, Bl[0][c], acc[c]);                   \
        acc[c] = MFMA16(A1h, Bh[1][c], acc[c]);                   \
        acc[c] = MFMA16(A1l, Bh[1][c], acc[c]);                   \
        acc[c] = MFMA16(A1h, Bl[1][c], acc[c]);                   \
    }

// ---------------- CSR build ----------------
// 8 grid-strided edges/thread -> 8 independent returning atomics in flight per lane.
__global__ void hist_kernel(const int* __restrict__ dst, const int* __restrict__ et,
                            const int* __restrict__ nt,
                            int* __restrict__ deg, int* __restrict__ tcnt, int* __restrict__ rcnt,
                            int* __restrict__ erank, int N, int E) {
    __shared__ int l_r[RR], l_t[TT];
    if (threadIdx.x < RR) l_r[threadIdx.x] = 0;
    if (threadIdx.x < TT) l_t[threadIdx.x] = 0;
    __syncthreads();
    const int stride = gridDim.x * blockDim.x;
    const int tid = blockIdx.x * blockDim.x + threadIdx.x;
#pragma unroll
    for (int i = 0; i < HIST_CH; ++i) {
        int e = tid + i * stride;
        if (e < E) {
            erank[e] = atomicAdd(&deg[dst[e]], 1);
            atomicAdd(&l_r[et[e]], 1);
        }
    }
#pragma unroll
    for (int i = 0; i < HIST_CH; ++i) {
        int n = tid + i * stride;
        if (n < N) atomicAdd(&l_t[nt[n]], 1);
    }
    __syncthreads();
    if (threadIdx.x < RR && l_r[threadIdx.x]) atomicAdd(&rcnt[threadIdx.x], l_r[threadIdx.x]);
    if (threadIdx.x < TT && l_t[threadIdx.x]) atomicAdd(&tcnt[threadIdx.x], l_t[threadIdx.x]);
}

// ---- 2-phase device-wide exclusive scan of deg[0..N) ----
__global__ void scan_sum_kernel(const int* __restrict__ deg, int* __restrict__ bsum, int N) {
    __shared__ int ws[SCAN_TPB / 64];
    int tid = threadIdx.x;
    int base = blockIdx.x * SCAN_ELEMS + tid * SCAN_CH;
    int s = 0;
#pragma unroll
    for (int i = 0; i < SCAN_CH; ++i) {
        int idx = base + i;
        if (idx < N) s += deg[idx];
    }
#pragma unroll
    for (int d = 32; d; d >>= 1) s += __shfl_xor(s, d, 64);
    if ((tid & 63) == 0) ws[tid >> 6] = s;
    __syncthreads();
    if (tid == 0) {
        int t = 0;
#pragma unroll
        for (int i = 0; i < SCAN_TPB / 64; ++i) t += ws[i];
        bsum[blockIdx.x] = t;
    }
}
// scan_out: per-block base via wave prefix of bsum; block 0 writes toff/tcur/roff/rcur.
__global__ void scan_out_kernel(const int* __restrict__ deg, const int* __restrict__ bsum, int nsb,
                                int* __restrict__ off, int N, int Etot,
                                const int* __restrict__ tcnt, int* __restrict__ toff, int* __restrict__ tcur,
                                const int* __restrict__ rcnt, int* __restrict__ roff, int* __restrict__ rcur) {
    __shared__ int ts[SCAN_TPB];
    __shared__ int bb;
    int tid = threadIdx.x;
    if (tid < 64) {
        int v = 0;
        if (nsb <= 64) {
            v = (tid < nsb && tid < blockIdx.x) ? bsum[tid] : 0;
#pragma unroll
            for (int d = 32; d; d >>= 1) v += __shfl_xor(v, d, 64);
        } else if (tid == 0) {
            for (int b = 0; b < blockIdx.x; ++b) v += bsum[b];
        }
        if (tid == 0) bb = v;
    }
    if (blockIdx.x == 0 && tid == 1) {
        int a = 0;
        for (int t = 0; t < TT; ++t) { toff[t] = a; tcur[t] = a; a += tcnt[t]; }
        toff[TT] = a;
        int b2 = 0;
        for (int r = 0; r < RR; ++r) { roff[r] = b2; rcur[r] = b2; b2 += rcnt[r]; }
        roff[RR] = b2;
        off[N] = Etot;
    }
    int base = blockIdx.x * SCAN_ELEMS + tid * SCAN_CH;
    int loc[SCAN_CH];
    int s = 0;
#pragma unroll
    for (int i = 0; i < SCAN_CH; ++i) {
        int idx = base + i;
        int v = (idx < N) ? deg[idx] : 0;
        loc[i] = v; s += v;
    }
    ts[tid] = s;
    __syncthreads();
    for (int sh = 1; sh < SCAN_TPB; sh <<= 1) {
        int v = (tid >= sh) ? ts[tid - sh] : 0;
        __syncthreads();
        ts[tid] += v;
        __syncthreads();
    }
    int run = bb + ((tid > 0) ? ts[tid - 1] : 0);
#pragma unroll
    for (int i = 0; i < SCAN_CH; ++i) {
        int idx = base + i;
        if (idx < N) { off[idx] = run; run += loc[i]; }
    }
}

// scatter: pos = offs[d] + erank[e] (no per-edge global atomics); 4 grid-strided items/thread.
__global__ void scatter_kernel(const int* __restrict__ src, const int* __restrict__ dst,
                               const int* __restrict__ et, const int* __restrict__ nt,
                               const int* __restrict__ offs, const int* __restrict__ erank,
                               int* __restrict__ tcur, int* __restrict__ rcur,
                               int* __restrict__ rsrc, int* __restrict__ rdst,
                               int* __restrict__ rdpos, int* __restrict__ nidx, int N, int E) {
    __shared__ int l_r[RR], l_t[TT], base_r[RR], base_t[TT];
    if (threadIdx.x < RR) l_r[threadIdx.x] = 0;
    if (threadIdx.x < TT) l_t[threadIdx.x] = 0;
    __syncthreads();
    const int stride = gridDim.x * blockDim.x;
    const int tid = blockIdx.x * blockDim.x + threadIdx.x;
    int s[SCAT_CH], d[SCAT_CH], r[SCAT_CH], rrank[SCAT_CH];
    int t[SCAT_CH], trank[SCAT_CH];
#pragma unroll
    for (int i = 0; i < SCAT_CH; ++i) {
        int e = tid + i * stride;
        if (e < E) {
            s[i] = src[e]; d[i] = dst[e]; r[i] = et[e];
            rrank[i] = atomicAdd(&l_r[r[i]], 1);
        }
        int n = tid + i * stride;
        if (n < N) {
            t[i] = nt[n];
            trank[i] = atomicAdd(&l_t[t[i]], 1);
        }
    }
    __syncthreads();
    if (threadIdx.x < RR)
        base_r[threadIdx.x] = l_r[threadIdx.x] ? atomicAdd(&rcur[threadIdx.x], l_r[threadIdx.x]) : 0;
    if (threadIdx.x < TT)
        base_t[threadIdx.x] = l_t[threadIdx.x] ? atomicAdd(&tcur[threadIdx.x], l_t[threadIdx.x]) : 0;
    __syncthreads();
#pragma unroll
    for (int i = 0; i < SCAT_CH; ++i) {
        int e = tid + i * stride;
        if (e < E) {
            int pos = offs[d[i]] + erank[e];
            int rp = base_r[r[i]] + rrank[i];
            rsrc[rp] = s[i]; rdst[rp] = d[i]; rdpos[rp] = pos;
        }
        int n = tid + i * stride;
        if (n < N) nidx[base_t[t[i]] + trank[i]] = n;
    }
}

// ---------------- node projections ----------------
// a=0: k -> fp16 row (128B); a=1: q -> fp16 row (128B); a=2: v fp16.
__global__ void proj_kernel(const float* __restrict__ h,
                            const float* __restrict__ Wk, const float* __restrict__ Wq,
                            const float* __restrict__ Wv,
                            const int* __restrict__ toff, const int* __restrict__ nidx,
                            _Float16* __restrict__ kh16,
                            _Float16* __restrict__ qout, _Float16* __restrict__ vout) {
    const int t = blockIdx.z, a = blockIdx.y, lane = threadIdx.x;
    const int beg = toff[t], end = toff[t + 1], cnt = end - beg;
    if (cnt <= 0) return;
    const int nstrips = (cnt + 15) >> 4;
    const float* W = (a == 0 ? Wk : (a == 1 ? Wq : Wv)) + (size_t)t * 4096;
    const int m = lane & 15, quad = lane >> 4;

    bf16x8 Bh[2][4], Bl[2][4];
#pragma unroll
    for (int ks = 0; ks < 2; ++ks)
#pragma unroll
        for (int c = 0; c < 4; ++c) load_B_split(W, ks, c, lane, Bh[ks][c], Bl[ks][c]);

    _Float16* out = (a == 0) ? kh16 : (a == 1 ? qout : vout);

    for (int s = blockIdx.x; s < nstrips; s += gridDim.x) {
        int base = beg + s * 16;
        int rA = base + m; if (rA > end - 1) rA = end - 1;
        const float* hp = h + (size_t)nidx[rA] * D;
        bf16x8 A0h, A0l, A1h, A1l;
        load_A_split(hp + quad * 8, A0h, A0l);
        load_A_split(hp + 32 + quad * 8, A1h, A1l);
        f32x4 acc[4];
#pragma unroll
        for (int c = 0; c < 4; ++c) acc[c] = (f32x4){0.f, 0.f, 0.f, 0.f};
        SPLIT_MFMA_BODY(acc, A0h, A0l, A1h, A1l, Bh, Bl)
#pragma unroll
        for (int reg = 0; reg < 4; ++reg) {
            int rr = base + quad * 4 + reg;
            if (rr < end) {
                int nid = nidx[rr];
#pragma unroll
                for (int c = 0; c < 4; ++c)
                    out[(size_t)nid * D + c * 16 + m] = (_Float16)acc[c][reg];
            }
        }
    }
}

// ---------------- fused: per-edge scores (x < SCORE_XB) + V2 build (x >= SCORE_XB) ----------------
// 256-thread blocks, wave-granular strips. score: k fp16 (128B), A split-fp16, q fp16 (128B).
__global__ void score_v2_kernel(const int* __restrict__ rsrc, const int* __restrict__ rdst,
                                const int* __restrict__ rdpos, const int* __restrict__ roff,
                                const _Float16* __restrict__ kh16,
                                const _Float16* __restrict__ qn, const float* __restrict__ Aatt,
                                const float* __restrict__ pri, int2* __restrict__ rec,
                                const _Float16* __restrict__ vn, const float* __restrict__ Amsg,
                                _Float16* __restrict__ V2, int N) {
    const int r = blockIdx.y;
    const int lane = threadIdx.x & 63;
    const int wv = threadIdx.x >> 6;
    const int m = lane & 15, quad = lane >> 4;

    if (blockIdx.x >= SCORE_XB) {
        // ---------------- V2 part ----------------
        const int g = (blockIdx.x - SCORE_XB) * 4 + wv;       // 0..V2_XB*4-1
        const int nstrips = (N + 15) >> 4;
        const float* W = Amsg + (size_t)r * 4096;
        f16x8 B[2][4];
#pragma unroll
        for (int ks = 0; ks < 2; ++ks)
#pragma unroll
            for (int c = 0; c < 4; ++c) B[ks][c] = load_B_frag_f16(W, ks, c, lane);

        for (int s = g; s < nstrips; s += V2_XB * 4) {
            int base = s * 16;
            int rA = base + m; if (rA > N - 1) rA = N - 1;
            f16x8 A0 = *(const f16x8*)(vn + (size_t)rA * D + quad * 8);
            f16x8 A1 = *(const f16x8*)(vn + (size_t)rA * D + 32 + quad * 8);
            f32x4 acc[4];
#pragma unroll
            for (int c = 0; c < 4; ++c) acc[c] = (f32x4){0.f, 0.f, 0.f, 0.f};
#pragma unroll
            for (int c = 0; c < 4; ++c) {
                acc[c] = MFMAH(A0, B[0][c], acc[c]);
                acc[c] = MFMAH(A1, B[1][c], acc[c]);
            }
#pragma unroll
            for (int reg = 0; reg < 4; ++reg) {
                int rr = base + quad * 4 + reg;
                if (rr < N) {
#pragma unroll
                    for (int c = 0; c < 4; ++c)
                        V2[((size_t)rr * RR + r) * D + c * 16 + m] = (_Float16)acc[c][reg];
                }
            }
        }
        return;
    }

    // ---------------- score part ----------------
    const int beg = roff[r], end = roff[r + 1], cnt = end - beg;
    if (cnt <= 0) return;
    const int nstrips = (cnt + 15) >> 4;
    const float scale = pri[r] * 0.125f;
    const float* W = Aatt + (size_t)r * 4096;

    f16x8 Bh[2][4], Bl[2][4];
#pragma unroll
    for (int ks = 0; ks < 2; ++ks)
#pragma unroll
        for (int c = 0; c < 4; ++c) load_B_split_f16(W, ks, c, lane, Bh[ks][c], Bl[ks][c]);

    const int g = blockIdx.x * 4 + wv;                         // 0..SCORE_XB*4-1
    for (int st = g; st < nstrips; st += SCORE_XB * 4) {
        int base = st * 16;
        int ia = base + m; if (ia > cnt - 1) ia = cnt - 1;
        int s = rsrc[beg + ia];
        const _Float16* kr = kh16 + (size_t)s * D;   // 128B row
        f16x8 A0 = *(const f16x8*)(kr + quad * 8);
        f16x8 A1 = *(const f16x8*)(kr + 32 + quad * 8);
        f32x4 acc[4];
#pragma unroll
        for (int c = 0; c < 4; ++c) acc[c] = (f32x4){0.f, 0.f, 0.f, 0.f};
#pragma unroll
        for (int c = 0; c < 4; ++c) {
            acc[c] = MFMAH(A0, Bh[0][c], acc[c]);
            acc[c] = MFMAH(A0, Bl[0][c], acc[c]);
            acc[c] = MFMAH(A1, Bh[1][c], acc[c]);
            acc[c] = MFMAH(A1, Bl[1][c], acc[c]);
        }

        float p4[4];
#pragma unroll
        for (int reg = 0; reg < 4; ++reg) {
            int ie = base + quad * 4 + reg; if (ie > cnt - 1) ie = cnt - 1;
            const _Float16* qp = qn + (size_t)rdst[beg + ie] * D + m;
            float pr = acc[0][reg] * (float)qp[0] + acc[1][reg] * (float)qp[16]
                     + acc[2][reg] * (float)qp[32] + acc[3][reg] * (float)qp[48];
#pragma unroll
            for (int d = 8; d; d >>= 1) pr += __shfl_xor(pr, d, 64);
            p4[reg] = pr;
        }
        if (m < 4) {
            int idx = base + quad * 4 + m;
            if (idx < cnt) {
                float v = (m == 0) ? p4[0] : (m == 1) ? p4[1] : (m == 2) ? p4[2] : p4[3];
                int sagain = rsrc[beg + idx];
                int2 rc;
                rc.x = __float_as_int(v * scale);
                rc.y = (sagain << 3) | r;                     // V2 row id
                rec[rdpos[beg + idx]] = rc;
            }
        }
    }
}

// ---------------- fused per-dst softmax+aggregation + output transform ----------------
// grid (AGG_XB, T), 256 threads = 16 quads = 16 same-type nodes per strip.
// Quads aggregate (identical math/order to previous agg_kernel); rows staged in LDS;
// all 4 waves do the split-bf16 out-MFMA, each owning a 16-col slice (c = wave id).
__global__ void agg_out_kernel(const int* __restrict__ offs, const int2* __restrict__ rec,
                               const _Float16* __restrict__ V2,
                               const float* __restrict__ Wa, const float* __restrict__ skp,
                               const int* __restrict__ toff, const int* __restrict__ nidx,
                               float* __restrict__ out) {
    const int t = blockIdx.y;
    const int beg = toff[t], end = toff[t + 1], cnt = end - beg;
    if (cnt <= 0) return;
    const int nstrips = (cnt + 15) >> 4;
    const int lane = threadIdx.x & 63;
    const int wv = threadIdx.x >> 6;          // 4 waves
    const int quad = lane >> 4, ql = lane & 15;
    const int q16 = wv * 4 + quad;            // node slot 0..15
    const int qb = quad << 4;
    const int m = lane & 15, qd = lane >> 4;  // MFMA roles
    const float sg = 1.f / (1.f + __expf(-skp[t]));

    __shared__ float As[16][68];              // padded stride breaks LDS bank conflicts

    // per-wave B slice (c = wv): 4 fragments, prepped once
    bf16x8 Bh2[2], Bl2[2];
    const float* W = Wa + (size_t)t * 4096;
#pragma unroll
    for (int ks = 0; ks < 2; ++ks) load_B_split(W, ks, wv, lane, Bh2[ks], Bl2[ks]);

    for (int s = blockIdx.x; s < nstrips; s += gridDim.x) {
        int base = beg + s * 16;
        int rr = base + q16; if (rr > end - 1) rr = end - 1;   // tail: duplicate last node
        int i = nidx[rr];
        // ---- aggregation for node i (one quad) — identical to previous agg_kernel ----
        const int ebeg = offs[i], eend = offs[i + 1];
        float mmax = -INFINITY, lsum = 0.f;
        float a0 = 0.f, a1 = 0.f, a2 = 0.f, a3 = 0.f;
        for (int cs = ebeg; cs < eend; cs += 16) {
            int cl = eend - cs; if (cl > 16) cl = 16;
            int2 rc; rc.y = 0;
            float sc = -INFINITY;
            if (ql < cl) { rc = rec[cs + ql]; sc = __int_as_float(rc.x); }
            float cm = sc;
#pragma unroll
            for (int d = 8; d; d >>= 1) cm = fmaxf(cm, __shfl_xor(cm, d, 64));
            float mn = fmaxf(mmax, cm);
            float cf = __expf(mmax - mn);
            float ex = (ql < cl) ? __expf(sc - mn) : 0.f;
            float csum = ex;
#pragma unroll
            for (int d = 8; d; d >>= 1) csum += __shfl_xor(csum, d, 64);
            lsum = lsum * cf + csum;
            a0 *= cf; a1 *= cf; a2 *= cf; a3 *= cf;
            for (int e = 0; e < cl; e += 4) {
                float w0 = __shfl(ex, qb + e, 64),     w1 = __shfl(ex, qb + e + 1, 64);
                float w2 = __shfl(ex, qb + e + 2, 64), w3 = __shfl(ex, qb + e + 3, 64);
                int   i0 = __shfl(rc.y, qb + e, 64),     i1 = __shfl(rc.y, qb + e + 1, 64);
                int   i2 = __shfl(rc.y, qb + e + 2, 64), i3 = __shfl(rc.y, qb + e + 3, 64);
                f16x4 v0 = *(const f16x4*)(V2 + (size_t)i0 * D + ql * 4);
                f16x4 v1 = *(const f16x4*)(V2 + (size_t)i1 * D + ql * 4);
                f16x4 v2 = *(const f16x4*)(V2 + (size_t)i2 * D + ql * 4);
                f16x4 v3 = *(const f16x4*)(V2 + (size_t)i3 * D + ql * 4);
                a0 += w0 * (float)v0[0] + w1 * (float)v1[0] + w2 * (float)v2[0] + w3 * (float)v3[0];
                a1 += w0 * (float)v0[1] + w1 * (float)v1[1] + w2 * (float)v2[1] + w3 * (float)v3[1];
                a2 += w0 * (float)v0[2] + w1 * (float)v1[2] + w2 * (float)v2[2] + w3 * (float)v3[2];
                a3 += w0 * (float)v0[3] + w1 * (float)v1[3] + w2 * (float)v2[3] + w3 * (float)v3[3];
            }
            mmax = mn;
        }
        float inv = 1.f / (lsum + 1e-16f);
        As[q16][ql * 4 + 0] = a0 * inv;
        As[q16][ql * 4 + 1] = a1 * inv;
        As[q16][ql * 4 + 2] = a2 * inv;
        As[q16][ql * 4 + 3] = a3 * inv;
        __syncthreads();

        // ---- out transform: each wave computes its 16-col slice (identical MFMA seq) ----
        bf16x8 A0h, A0l, A1h, A1l;
        load_A_split(&As[m][qd * 8], A0h, A0l);
        load_A_split(&As[m][32 + qd * 8], A1h, A1l);
        f32x4 acc = (f32x4){0.f, 0.f, 0.f, 0.f};
        acc = MFMA16(A0h, Bh2[0], acc);
        acc = MFMA16(A0l, Bh2[0], acc);
        acc = MFMA16(A0h, Bl2[0], acc);
        acc = MFMA16(A1h, Bh2[1], acc);
        acc = MFMA16(A1l, Bh2[1], acc);
        acc = MFMA16(A1h, Bl2[1], acc);
#pragma unroll
        for (int reg = 0; reg < 4; ++reg) {
            int rrr = base + qd * 4 + reg;
            if (rrr < end)
                out[(size_t)nidx[rrr] * D + wv * 16 + m] = acc[reg] * sg;
        }
        __syncthreads();   // protect As before next strip
    }
}

// ---------------- launch ----------------
extern "C" void kernel_launch(void* const* d_in, const int* in_sizes, int n_in,
                              void* d_out, int out_size, void* d_ws, size_t ws_size,
                              hipStream_t stream) {
    const float* h     = (const float*)d_in[0];
    const int*   adj   = (const int*)d_in[1];     // [2,E]: src row then dst row
    const int*   etype = (const int*)d_in[2];
    const int*   ntype = (const int*)d_in[3];
    const float* Wk    = (const float*)d_in[6];
    const float* Wq    = (const float*)d_in[7];
    const float* Wv    = (const float*)d_in[8];
    const float* Wa    = (const float*)d_in[9];
    const float* pri   = (const float*)d_in[10];
    const float* Aatt  = (const float*)d_in[11];
    const float* Amsg  = (const float*)d_in[12];
    const float* skp   = (const float*)d_in[13];
    const int N = in_sizes[3];
    const int E = in_sizes[2];
    float* out = (float*)d_out;

    char* w = (char*)d_ws;
    auto alloc = [&](size_t b) { char* p = w; w += (b + 255) & ~(size_t)255; return p; };
    _Float16* kh16 = (_Float16*)alloc((size_t)N * D * 2);
    _Float16* qn   = (_Float16*)alloc((size_t)N * D * 2);
    _Float16* vn   = (_Float16*)alloc((size_t)N * D * 2);
    _Float16* V2   = (_Float16*)alloc((size_t)N * RR * D * 2);
    int* deg  = (int*)alloc((size_t)(N + 16) * 4);
    int* tcnt = deg + N;
    int* rcnt = deg + N + 8;
    int* offs = (int*)alloc((size_t)(N + 1) * 4);
    int* erank = (int*)alloc((size_t)E * 4);
    int* toff = (int*)alloc(64);
    int* tcur = (int*)alloc(64);
    int* roff = (int*)alloc(64);
    int* rcur = (int*)alloc(64);
    int2* rec = (int2*)alloc((size_t)E * 8);
    int* rsrc  = (int*)alloc((size_t)E * 4);
    int* rdst  = (int*)alloc((size_t)E * 4);
    int* rdpos = (int*)alloc((size_t)E * 4);
    int* nidx  = (int*)alloc((size_t)N * 4);
    const int nsb = (N + SCAN_ELEMS - 1) / SCAN_ELEMS;
    int* bsum  = (int*)alloc((size_t)nsb * 4);

    (void)hipMemsetAsync(deg, 0, (size_t)(N + 16) * 4, stream);

    const int mx = (E > N ? E : N);
    const int histBlocks = (mx + 256 * HIST_CH - 1) / (256 * HIST_CH);
    hist_kernel<<<histBlocks, 256, 0, stream>>>(adj + E, etype, ntype, deg, tcnt, rcnt, erank, N, E);
    scan_sum_kernel<<<nsb, SCAN_TPB, 0, stream>>>(deg, bsum, N);
    scan_out_kernel<<<nsb, SCAN_TPB, 0, stream>>>(deg, bsum, nsb, offs, N, E,
                                                  tcnt, toff, tcur, rcnt, roff, rcur);
    const int scatBlocks = (mx + 256 * SCAT_CH - 1) / (256 * SCAT_CH);
    scatter_kernel<<<scatBlocks, 256, 0, stream>>>(adj, adj + E, etype, ntype,
                                                   offs, erank, tcur, rcur,
                                                   rsrc, rdst, rdpos, nidx, N, E);
    proj_kernel<<<dim3(128, 3, TT), 64, 0, stream>>>(h, Wk, Wq, Wv, toff, nidx, kh16, qn, vn);
    score_v2_kernel<<<dim3(SCORE_XB + V2_XB, RR), 256, 0, stream>>>(rsrc, rdst, rdpos, roff,
                                                                    kh16, qn, Aatt, pri, rec,
                                                                    vn, Amsg, V2, N);
    agg_out_kernel<<<dim3(AGG_XB, TT), 256, 0, stream>>>(offs, rec, V2, Wa, skp, toff, nidx, out);
}